// Round 5
// baseline (854.515 us; speedup 1.0000x reference)
//
#include <hip/hip_runtime.h>
#include <math.h>

// DTYPE COMMITMENTS (evidence-backed): inputs f32, output f32 (rounds 4-14 PASS).
// WS BUDGET: <= ~210 MB decimal; this build ~170 MiB.

#define T_ 16
#define N_ 64
#define NN_ 32
#define D_ 512
#define H_ 8
#define DK_ 64
#define DFF_ 2048
#define L_ 2
#define NPRED_ 20

typedef unsigned short u16;
typedef unsigned int u32;
typedef __attribute__((ext_vector_type(8))) short short8;
typedef __attribute__((ext_vector_type(4))) float f32x4;

__device__ __forceinline__ u16 f2bf(float f) {
    u32 u = __float_as_uint(f);
    u32 r = u + 0x7fffu + ((u >> 16) & 1u);
    return (u16)(r >> 16);
}
__device__ __forceinline__ float bfv(u16 v) {
    return __uint_as_float(((u32)v) << 16);
}
__device__ __forceinline__ float ntn(float v) {
    if (isnan(v)) return 0.0f;
    if (isinf(v)) return v > 0.0f ? 3.4028234663852886e38f : -3.4028234663852886e38f;
    return v;
}
__device__ __forceinline__ float wave_sum(float v) {
    #pragma unroll
    for (int o = 32; o > 0; o >>= 1) v += __shfl_xor(v, o, 64);
    return v;
}
// async 16B HBM->LDS: writes ldsbase + lane*16 (wave-uniform base, per-lane gptr)
__device__ __forceinline__ void gload_lds(const u16* g, u16* l) {
    __builtin_amdgcn_global_load_lds(
        (const __attribute__((address_space(1))) u32*)g,
        (__attribute__((address_space(3))) u32*)l, 16, 0, 0);
}

// ============ batched weight convert+transpose: 14 jobs in ONE launch ===============
struct WJob { const float* src; u16* dst; int K; int N; int t0; };
struct WJobs { WJob j[14]; };
__global__ __launch_bounds__(256) void wconv_all(WJobs jobs, int ntiles) {
    int bid = blockIdx.x;
    if (bid >= ntiles) return;
    int ji = 0;
    #pragma unroll 1
    for (int i = 1; i < 14; ++i) if (bid >= jobs.j[i].t0) ji = i;
    const float* in = jobs.j[ji].src;
    u16* out = jobs.j[ji].dst;
    int K = jobs.j[ji].K, N = jobs.j[ji].N;
    int lt = bid - jobs.j[ji].t0;
    int ntx = N >> 5;
    int nb = (lt % ntx) * 32, kb = (lt / ntx) * 32;
    __shared__ float tile[32][33];
    int tx = threadIdx.x & 31, ty = threadIdx.x >> 5;
    #pragma unroll
    for (int r = ty; r < 32; r += 8)
        tile[r][tx] = in[(size_t)(kb + r) * N + nb + tx];
    __syncthreads();
    #pragma unroll
    for (int r = ty; r < 32; r += 8)
        out[(size_t)(nb + r) * K + kb + tx] = f2bf(tile[tx][r]);
}

// ============ MFMA GEMM v3 + XCD-band remap (kept for small M=1024 GEMMs) ===========
// DMA staging + 3-bit XOR chunk swizzle (r9: 0 bank conflicts); XCD remap (r10).
// EPI: 0 none, 1 relu, 2 +res f32, 3 +res bf16.
template<int TM, int TN, int EPI, int WF32, int WBF16>
__global__ __launch_bounds__(256) void gemm_bt(
    const u16* __restrict__ Ab, const u16* __restrict__ Btb,
    float* __restrict__ Cf, u16* __restrict__ Cb, const void* __restrict__ Rg,
    int K, int ldc)
{
    constexpr int WR = TM / 32, WC = TN / 32;
    constexpr int ITA = TM / 32, ITB = TN / 32;
    __shared__ __align__(16) u16 As[TM][64];
    __shared__ __align__(16) u16 Bs[TN][64];
    int tid = threadIdx.x;
    int lane = tid & 63, wave = tid >> 6;
    int quad = lane >> 4, l16 = lane & 15;
    int wm = (wave >> 1) * (TM / 2), wn = (wave & 1) * (TN / 2);

    int gx = gridDim.x, gy = gridDim.y;
    int bx, by;
    if ((gy & 7) == 0) {
        int id = blockIdx.y * gx + blockIdx.x;
        int xcd = id & 7;
        int slot = id >> 3;
        bx = slot % gx;
        by = xcd * (gy >> 3) + slot / gx;
    } else {
        bx = blockIdx.x;
        by = blockIdx.y;
    }
    size_t row0 = (size_t)by * TM;
    size_t col0 = (size_t)bx * TN;

    f32x4 acc[WR][WC];
    #pragma unroll
    for (int i = 0; i < WR; ++i)
        #pragma unroll
        for (int j = 0; j < WC; ++j)
            acc[i][j] = (f32x4){0.f, 0.f, 0.f, 0.f};

    int srow = lane >> 3;
    int c8 = (lane & 7) ^ srow;
    int h8 = l16 & 7;

    for (int k0 = 0; k0 < K; k0 += 64) {
        __syncthreads();
        #pragma unroll
        for (int it = 0; it < ITA; ++it) {
            int g = wave + it * 4;
            gload_lds(Ab + (row0 + g * 8 + srow) * (size_t)K + k0 + c8 * 8, &As[g * 8][0]);
        }
        #pragma unroll
        for (int it = 0; it < ITB; ++it) {
            int g = wave + it * 4;
            gload_lds(Btb + (col0 + g * 8 + srow) * (size_t)K + k0 + c8 * 8, &Bs[g * 8][0]);
        }
        __syncthreads();
        #pragma unroll
        for (int s = 0; s < 2; ++s) {
            int coff = ((s * 4 + quad) ^ h8) * 8;   // full 3-bit XOR (r9-verified)
            short8 af[WR], bf[WC];
            #pragma unroll
            for (int i = 0; i < WR; ++i)
                af[i] = *(short8*)&As[wm + i * 16 + l16][coff];
            #pragma unroll
            for (int j = 0; j < WC; ++j)
                bf[j] = *(short8*)&Bs[wn + j * 16 + l16][coff];
            #pragma unroll
            for (int i = 0; i < WR; ++i)
                #pragma unroll
                for (int j = 0; j < WC; ++j)
                    acc[i][j] = __builtin_amdgcn_mfma_f32_16x16x32_bf16(
                        af[i], bf[j], acc[i][j], 0, 0, 0);
        }
    }
    // C/D layout (on-target verified): col = lane&15, row = quad*4 + reg
    #pragma unroll
    for (int i = 0; i < WR; ++i)
        #pragma unroll
        for (int j = 0; j < WC; ++j)
            #pragma unroll
            for (int reg = 0; reg < 4; ++reg) {
                size_t row = row0 + wm + i * 16 + quad * 4 + reg;
                size_t col = col0 + wn + j * 16 + l16;
                float v = acc[i][j][reg];
                if (EPI == 2) v += ((const float*)Rg)[row * (size_t)ldc + col];
                if (EPI == 3) v += bfv(((const u16*)Rg)[row * (size_t)ldc + col]);
                if (EPI == 1) v = fmaxf(v, 0.f);
                if (WF32)  Cf[row * (size_t)ldc + col] = v;
                if (WBF16) Cb[row * (size_t)ldc + col] = f2bf(v);
            }
}

// ============ counted-pipeline GEMM, 8-wave big-tile (r5: LDS-ratio fix) ============
// r4 post-mortem: 128x128 FM=FN=4 has LDS-read demand (128 b128/tile/CU ~1536cyc +
// 512cyc staging writes) > MFMA (1242cyc/SIMD) -> LDS pipe caps MfmaUtil at ~60%.
// Fix: bigger per-wave frag tile flips the ratio.
//   G1' <256,256,2,4>: FM=8,FN=4 -> 24 reads/64 MFMA per wave/tile; LDS ~2816cyc
//       vs MFMA ~2483cyc/SIMD -> MFMA-bound. LDS 128KiB, 1 blk/CU.
//   G2' <256,128,4,2>: FM=FN=4, LDS 96KiB, 1 blk/CU; for N=512/1536 exact grids.
// Schedule = r4's verified counted pipeline: per tile (1) issue GA+GB gload_lds for
// t+1 into other buffer; (2) s_waitcnt vmcnt(GA+GB) counted -- only tile t's loads
// (issued one ~2600cyc tile ago >> L3 latency) must have landed; (3) one rendezvous
// barrier; (4) full MFMA block, setprio-wrapped, no intra-tile barriers; (5) one end
// barrier freeing buf for restage. vmcnt(0) only at last tile. r9 XOR swizzle.
// Requires M%TM==0, N%TN==0, K%64==0 (K>=128), gridDim.y%8==0 (XCD remap).
template<int TM, int TN, int WM, int WN, int EPI, int WF32, int WBF16>
__global__ __launch_bounds__(512, 2) void gemm_cp(
    const u16* __restrict__ Ab, const u16* __restrict__ Btb,
    float* __restrict__ Cf, u16* __restrict__ Cb, const void* __restrict__ Rg,
    int K, int ldc)
{
    constexpr int NW = WM * WN;             // 8 waves
    constexpr int FM = TM / WM / 16;
    constexpr int FN = TN / WN / 16;
    constexpr int GA = TM / 8 / NW;         // staging loads A per wave per tile
    constexpr int GB = TN / 8 / NW;         // staging loads B per wave per tile
    __shared__ __align__(16) u16 As[2][TM][64];
    __shared__ __align__(16) u16 Bs[2][TN][64];
    int tid = threadIdx.x;
    int lane = tid & 63, wave = tid >> 6;
    int quad = lane >> 4, l16 = lane & 15;
    int wm = (wave / WN) * (FM * 16);
    int wn = (wave % WN) * (FN * 16);

    int gx = gridDim.x, gy = gridDim.y;
    int id = blockIdx.y * gx + blockIdx.x;
    int xcd = id & 7, slot = id >> 3;
    int bx = slot % gx;
    int by = xcd * (gy >> 3) + slot / gx;
    size_t row0 = (size_t)by * TM;
    size_t col0 = (size_t)bx * TN;

    f32x4 acc[FM][FN];
    #pragma unroll
    for (int i = 0; i < FM; ++i)
        #pragma unroll
        for (int j = 0; j < FN; ++j)
            acc[i][j] = (f32x4){0.f, 0.f, 0.f, 0.f};

    // staging swizzle (r9-verified): physical 16B chunk p of row r holds logical
    // chunk p ^ (r&7)
    int srow = lane >> 3;
    int c8 = (lane & 7) ^ srow;
    int h8 = l16 & 7;
    size_t aoff[GA], boff[GB];
    #pragma unroll
    for (int it = 0; it < GA; ++it)
        aoff[it] = (row0 + (size_t)(wave + it * NW) * 8 + srow) * (size_t)K + c8 * 8;
    #pragma unroll
    for (int it = 0; it < GB; ++it)
        boff[it] = (col0 + (size_t)(wave + it * NW) * 8 + srow) * (size_t)K + c8 * 8;

    int nt = K >> 6;
    // prologue: stage tile 0 -> buf 0 (loads left in flight, no wait)
    #pragma unroll
    for (int it = 0; it < GA; ++it)
        gload_lds(Ab + aoff[it], &As[0][(wave + it * NW) * 8][0]);
    #pragma unroll
    for (int it = 0; it < GB; ++it)
        gload_lds(Btb + boff[it], &Bs[0][(wave + it * NW) * 8][0]);

    #pragma unroll 1
    for (int t = 0; t < nt; ++t) {
        int cur = t & 1;
        if (t + 1 < nt) {
            // stage tile t+1 into other buffer (freed by iter t-1's end barrier)
            size_t ko = (size_t)(t + 1) * 64;
            #pragma unroll
            for (int it = 0; it < GA; ++it)
                gload_lds(Ab + aoff[it] + ko, &As[cur ^ 1][(wave + it * NW) * 8][0]);
            #pragma unroll
            for (int it = 0; it < GB; ++it)
                gload_lds(Btb + boff[it] + ko, &Bs[cur ^ 1][(wave + it * NW) * 8][0]);
            __builtin_amdgcn_sched_barrier(0);
            // counted wait: just-issued GA+GB stay in flight; tile t's have landed
            if constexpr (GA + GB == 8)
                asm volatile("s_waitcnt vmcnt(8)" ::: "memory");
            else if constexpr (GA + GB == 6)
                asm volatile("s_waitcnt vmcnt(6)" ::: "memory");
            else
                asm volatile("s_waitcnt vmcnt(4)" ::: "memory");
        } else {
            __builtin_amdgcn_sched_barrier(0);
            asm volatile("s_waitcnt vmcnt(0)" ::: "memory");   // final tile only
        }
        __builtin_amdgcn_sched_barrier(0);
        __builtin_amdgcn_s_barrier();                          // rendezvous: tile t staged
        __builtin_amdgcn_sched_barrier(0);
        __builtin_amdgcn_s_setprio(1);
        #pragma unroll
        for (int kh = 0; kh < 2; ++kh) {
            int coff = ((kh * 4 + quad) ^ h8) * 8;
            short8 af[FM], bf[FN];
            #pragma unroll
            for (int j = 0; j < FN; ++j)
                bf[j] = *(short8*)&Bs[cur][wn + j * 16 + l16][coff];
            #pragma unroll
            for (int i = 0; i < FM; ++i)
                af[i] = *(short8*)&As[cur][wm + i * 16 + l16][coff];
            #pragma unroll
            for (int i = 0; i < FM; ++i)
                #pragma unroll
                for (int j = 0; j < FN; ++j)
                    acc[i][j] = __builtin_amdgcn_mfma_f32_16x16x32_bf16(
                        af[i], bf[j], acc[i][j], 0, 0, 0);
        }
        __builtin_amdgcn_s_setprio(0);
        __builtin_amdgcn_sched_barrier(0);                     // reads done before barrier
        __builtin_amdgcn_s_barrier();                          // frees buf[cur] for restage
    }

    // C/D layout (on-target verified): col = lane&15, row = quad*4 + reg
    #pragma unroll
    for (int i = 0; i < FM; ++i)
        #pragma unroll
        for (int j = 0; j < FN; ++j)
            #pragma unroll
            for (int reg = 0; reg < 4; ++reg) {
                size_t row = row0 + wm + i * 16 + quad * 4 + reg;
                size_t col = col0 + wn + j * 16 + l16;
                float v = acc[i][j][reg];
                if (EPI == 2) v += ((const float*)Rg)[row * (size_t)ldc + col];
                if (EPI == 3) v += bfv(((const u16*)Rg)[row * (size_t)ldc + col]);
                if (EPI == 1) v = fmaxf(v, 0.f);
                if (WF32)  Cf[row * (size_t)ldc + col] = v;
                if (WBF16) Cb[row * (size_t)ldc + col] = f2bf(v);
            }
}

// ============ fused attention per (b,m): all-heads phases, 3 barriers ===============
template<int CTX, int LD>
__global__ __launch_bounds__(256) void attn_fused_kernel(
    const u16* __restrict__ QKVb, const float* __restrict__ maskf, int bm0,
    float* __restrict__ att_sum, u16* __restrict__ ctxb)
{
    __shared__ __align__(16) u16 sQ[16][520];
    __shared__ __align__(16) u16 sK[16][520];
    __shared__ __align__(16) u16 sV[CTX ? 16 : 1][520];
    __shared__ float s_p[H_][16][17];
    int bm_l = blockIdx.x;
    int tid = threadIdx.x;
    int t = tid >> 4, ch = (tid & 15) * 32;
    const u16* base = QKVb + ((size_t)bm_l * T_ + t) * LD;
    #pragma unroll
    for (int c = 0; c < 4; ++c) {
        *(uint4*)&sQ[t][ch + c * 8] = *(const uint4*)(base + ch + c * 8);
        *(uint4*)&sK[t][ch + c * 8] = *(const uint4*)(base + 512 + ch + c * 8);
        if (CTX) *(uint4*)&sV[t][ch + c * 8] = *(const uint4*)(base + 1024 + ch + c * 8);
    }
    __syncthreads();

    int b = (bm0 + bm_l) >> 5;                  // bm = b*NN + m

    #pragma unroll
    for (int r = 0; r < 8; ++r) {
        int h = r;
        int q = (tid >> 4) & 15, k = tid & 15;
        const u32* qu = (const u32*)&sQ[q][0] + h * 32;
        const u32* ku = (const u32*)&sK[k][0] + h * 32;
        float acc = 0.f;
        #pragma unroll
        for (int j = 0; j < 32; ++j) {
            u32 a = qu[j], bb = ku[j];
            acc += bfv((u16)(a & 0xffff)) * bfv((u16)(bb & 0xffff));
            acc += bfv((u16)(a >> 16))    * bfv((u16)(bb >> 16));
        }
        acc *= 0.125f;
        if (maskf[(size_t)(bm0 + bm_l) * T_ + q] == 0.0f) acc = -1e9f;
        s_p[h][q][k] = acc;
    }
    __syncthreads();
    if (tid < 128) {
        int h = tid >> 4, q = tid & 15;
        float mx = -3.4e38f;
        #pragma unroll
        for (int kk = 0; kk < 16; ++kk) mx = fmaxf(mx, s_p[h][q][kk]);
        float e[16], s = 0.f;
        #pragma unroll
        for (int kk = 0; kk < 16; ++kk) { e[kk] = expf(s_p[h][q][kk] - mx); s += e[kk]; }
        float inv = 1.0f / s;
        #pragma unroll
        for (int kk = 0; kk < 16; ++kk) s_p[h][q][kk] = e[kk] * inv;
    }
    __syncthreads();
    #pragma unroll
    for (int r = 0; r < 8; ++r) {
        int h = r;
        int q = (tid >> 4) & 15, k = tid & 15;
        atomicAdd(&att_sum[(((size_t)b * H_ + h) * T_ + q) * T_ + k], s_p[h][q][k]);
    }
    if (CTX) {
        #pragma unroll
        for (int rep = 0; rep < 16; ++rep) {
            int i2 = rep * 256 + tid;           // t*256 + c2, c2 = (h*64+dk)/2
            int tt = i2 >> 8, c2 = i2 & 255;
            int h = c2 >> 5;
            const float* pr = &s_p[h][tt][0];
            float a0 = 0.f, a1 = 0.f;
            #pragma unroll
            for (int kk = 0; kk < 16; ++kk) {
                u32 vv = *((const u32*)&sV[kk][0] + c2);
                float p = pr[kk];
                a0 += p * bfv((u16)(vv & 0xffff));
                a1 += p * bfv((u16)(vv >> 16));
            }
            u32 o = (u32)f2bf(a0) | ((u32)f2bf(a1) << 16);
            *((u32*)(ctxb + ((size_t)bm_l * T_ + tt) * D_) + c2) = o;
        }
    }
}

// ============ fused self-attention + combine + si, one block per (n,h) ==============
__global__ __launch_bounds__(256) void siatt_kernel(
    const float* __restrict__ xemb, const float* __restrict__ att_sum,
    const float* __restrict__ attf, u16* __restrict__ sib)
{
    __shared__ float sX[16][516];
    __shared__ float sS[16][17];
    __shared__ float sA[16][17];
    int n = blockIdx.x >> 3, h = blockIdx.x & 7;
    int tid = threadIdx.x;
    int t = tid >> 4, ch = (tid & 15) * 32;
    const float* src = xemb + ((size_t)n * T_ + t) * D_;
    #pragma unroll
    for (int c = 0; c < 8; ++c)
        *(float4*)&sX[t][ch + c * 4] = *(const float4*)(src + ch + c * 4);
    __syncthreads();
    int q = tid >> 4, k = tid & 15;
    {
        float acc = 0.f;
        for (int d = 0; d < D_; ++d) acc += sX[q][d] * sX[k][d];
        sS[q][k] = acc * 0.04419417382415922f;
    }
    __syncthreads();
    if (tid < T_) {
        float mx = -3.4e38f;
        #pragma unroll
        for (int kk = 0; kk < 16; ++kk) mx = fmaxf(mx, sS[tid][kk]);
        float e[16], s = 0.f;
        #pragma unroll
        for (int kk = 0; kk < 16; ++kk) { e[kk] = expf(sS[tid][kk] - mx); s += e[kk]; }
        float inv = 1.0f / s;
        #pragma unroll
        for (int kk = 0; kk < 16; ++kk) sS[tid][kk] = e[kk] * inv;
    }
    __syncthreads();
    float f = attf[0] * (1.0f / 32.0f);
    sA[q][k] = sS[q][k] + f * att_sum[((size_t)n * H_ + h) * 256 + q * 16 + k];
    __syncthreads();
    #pragma unroll
    for (int rep = 0; rep < 16; ++rep) {
        int i2 = rep * 256 + tid;          // q*256 + d2
        int qq = i2 >> 8, d2 = (i2 & 255) * 2;
        const float* ar = &sA[qq][0];
        float a0 = 0.f, a1 = 0.f;
        #pragma unroll
        for (int tt = 0; tt < 16; ++tt) {
            float p = ar[tt];
            a0 += p * sX[tt][d2];
            a1 += p * sX[tt][d2 + 1];
        }
        u32 o = (u32)f2bf(a0) | ((u32)f2bf(a1) << 16);
        *((u32*)(sib + (size_t)n * T_ * 4096 + (size_t)qq * 4096 + h * 512) + (d2 >> 1)) = o;
    }
}

// ---------------- positional encoding ------------------------------------------------
__global__ void pe_kernel(float* pe) {
    int i = blockIdx.x * blockDim.x + threadIdx.x;
    if (i >= T_ * 256) return;
    int t = i >> 8, j = i & 255;
    float dv = (float)pow(10000.0, (double)j / 256.0);
    float a = (float)t * dv;
    double ad = (double)a;
    pe[t * D_ + 2 * j]     = (float)sin(ad);
    pe[t * D_ + 2 * j + 1] = (float)cos(ad);
}

// ---------------- x features + embed -------------------------------------------------
__global__ void xemb_kernel(const float* x, const float* Wx, const float* bx,
                            const float* pe, float* xemb) {
    int row = blockIdx.x;              // t*N + n
    int t = row / N_, n = row % N_;
    float x0 = x[row * 6 + 0], x1 = x[row * 6 + 1];
    float x2 = x[row * 6 + 2], x3 = x[row * 6 + 3];
    float x4 = x[row * 6 + 4], x5 = x[row * 6 + 5];
    float vel = sqrtf(x2 * x2 + x3 * x3);
    float ang = atanf(x5 / x4);
    float f0 = ntn(x0), f1 = ntn(x1), f2 = ntn(vel), f3 = ntn(ang);
    for (int d = threadIdx.x; d < D_; d += blockDim.x) {
        xemb[((size_t)n * T_ + t) * D_ + d] =
            f0 * Wx[0 * D_ + d] + f1 * Wx[1 * D_ + d]
          + f2 * Wx[2 * D_ + d] + f3 * Wx[3 * D_ + d]
          + bx[d] + pe[t * D_ + d];
    }
}

// ---------------- neighbor features + mask -------------------------------------------
__global__ void nbr_kernel(const float* x, const float* nbr, float* nf, float* maskf) {
    int idx = blockIdx.x * blockDim.x + threadIdx.x;   // t*N*NN + n*NN + m
    if (idx >= T_ * N_ * NN_) return;
    int m = idx % NN_;
    int tn = idx / NN_;
    int n = tn % N_, t = tn / N_;
    float px = x[((size_t)t * N_ + n) * 6 + 0];
    float py = x[((size_t)t * N_ + n) * 6 + 1];
    float vx, vy;
    if (t == 0) {
        vx = x[((size_t)1 * N_ + n) * 6 + 2];
        vy = x[((size_t)1 * N_ + n) * 6 + 3];
    } else {
        vx = px - x[((size_t)(t - 1) * N_ + n) * 6 + 0];
        vy = py - x[((size_t)(t - 1) * N_ + n) * 6 + 1];
    }
    float nx  = nbr[(size_t)idx * 4 + 0], ny  = nbr[(size_t)idx * 4 + 1];
    float nvx = nbr[(size_t)idx * 4 + 2], nvy = nbr[(size_t)idx * 4 + 3];
    float dpx = nx - px, dpy = ny - py;
    float dvx = nvx - vx, dvy = nvy - vy;
    float dist = sqrtf(dpx * dpx + dpy * dpy);
    maskf[((size_t)n * NN_ + m) * T_ + t] = (dist <= 2.0f) ? 1.0f : 0.0f;
    float vn = sqrtf(vx * vx + vy * vy);
    float bearing = (dpx * vx + dpy * vy) / (dist * vn);
    if (isnan(bearing)) bearing = 0.0f;
    float dvn = sqrtf(dvx * dvx + dvy * dvy);
    float tau = -(dpx * dvx + dpy * dvy) / dvn;
    if (isnan(tau)) tau = 0.0f;
    tau = fminf(fmaxf(tau, 0.0f), 7.0f);
    float mx_ = dpx + tau * dvx, my_ = dpy + tau * dvy;
    float mpd = sqrtf(mx_ * mx_ + my_ * my_);
    nf[(size_t)idx * 3 + 0] = ntn(dist);
    nf[(size_t)idx * 3 + 1] = ntn(bearing);
    nf[(size_t)idx * 3 + 2] = ntn(mpd);
}

// ---------------- neighbor embed: bf16 n_emb only ------------------------------------
__global__ void nemb_kernel(const float* nf, const float* Wn, const float* bn,
                            const float* pe, u16* Ab) {
    int row = blockIdx.x;              // (b*NN+m)*T + t
    int t = row % T_;
    int bm = row / T_;
    int m = bm % NN_, b = bm / NN_;
    size_t nfrow = (((size_t)t * N_ + b) * NN_ + m) * 3;
    float f0 = nf[nfrow], f1 = nf[nfrow + 1], f2 = nf[nfrow + 2];
    for (int d = threadIdx.x; d < D_; d += blockDim.x) {
        float v = f0 * Wn[d] + f1 * Wn[D_ + d] + f2 * Wn[2 * D_ + d]
                + bn[d] + pe[t * D_ + d];
        Ab[(size_t)row * D_ + d] = f2bf(v);
    }
}

// ---------------- LayerNorm, one wave per row; input f32 or bf16; dual out -----------
template<int INBF>
__global__ __launch_bounds__(256) void ln_kernel(
    const void* X, const float* g, const float* b, float* outF, u16* outB, int nrows) {
    int row = blockIdx.x * 4 + (threadIdx.x >> 6);
    if (row >= nrows) return;
    int lane = threadIdx.x & 63;
    float v[8];
    float s = 0.f;
    #pragma unroll
    for (int r = 0; r < 8; ++r) {
        int d = lane + r * 64;
        v[r] = INBF ? bfv(((const u16*)X)[(size_t)row * D_ + d])
                    : ((const float*)X)[(size_t)row * D_ + d];
        s += v[r];
    }
    s = wave_sum(s);
    float mean = s * (1.0f / 512.0f);
    float vs = 0.f;
    #pragma unroll
    for (int r = 0; r < 8; ++r) { float d = v[r] - mean; vs += d * d; }
    vs = wave_sum(vs);
    float rstd = rsqrtf(vs * (1.0f / 512.0f) + 1e-5f);
    #pragma unroll
    for (int r = 0; r < 8; ++r) {
        int d = lane + r * 64;
        float o = (v[r] - mean) * rstd * g[d] + b[d];
        if (outF) outF[(size_t)row * D_ + d] = o;
        if (outB) outB[(size_t)row * D_ + d] = f2bf(o);
    }
}

// ---------------- prediction head + broadcast fused (f32 out) ------------------------
__global__ void predbcast_kernel(const float* xemb, const float* Wp, const float* bp,
                                 float* out) {
    int idx = blockIdx.x * blockDim.x + threadIdx.x;   // (n*T+t)*2 + c
    if (idx >= N_ * T_ * 2) return;
    int c = idx & 1;
    int nt = idx >> 1;
    int n = nt / T_, t = nt % T_;
    float acc = bp[c];
    for (int j = 0; j < D_; ++j) acc += xemb[(size_t)nt * D_ + j] * Wp[(size_t)j * 2 + c];
    #pragma unroll
    for (int p = 0; p < NPRED_; ++p)
        out[(((size_t)p * T_ + t) * N_ + n) * 2 + c] = acc;
}

extern "C" void kernel_launch(void* const* d_in, const int* in_sizes, int n_in,
                              void* d_out, int out_size, void* d_ws, size_t ws_size,
                              hipStream_t stream) {
    (void)in_sizes; (void)n_in; (void)out_size; (void)ws_size;

    const float* x    = (const float*)d_in[0];
    const float* nbr  = (const float*)d_in[1];
    const float* attf = (const float*)d_in[2];
    const float* Wx   = (const float*)d_in[3];
    const float* bx   = (const float*)d_in[4];
    const float* Wn   = (const float*)d_in[5];
    const float* bn   = (const float*)d_in[6];
    const float* Wp   = (const float*)d_in[7];
    const float* bp   = (const float*)d_in[8];
    const float* WQ   = (const float*)d_in[9];
    const float* WK   = (const float*)d_in[10];
    const float* WV   = (const float*)d_in[11];
    const float* Wfc  = (const float*)d_in[12];
    const float* mlng = (const float*)d_in[13];
    const float* mlnb = (const float*)d_in[14];
    const float* WSI  = (const float*)d_in[15];
    const float* fsw1 = (const float*)d_in[16];
    const float* fsw2 = (const float*)d_in[17];
    const float* fsg  = (const float*)d_in[18];
    const float* fsb  = (const float*)d_in[19];
    const float* fiw1 = (const float*)d_in[20];
    const float* fiw2 = (const float*)d_in[21];
    const float* fig  = (const float*)d_in[22];
    const float* fib  = (const float*)d_in[23];

    char* w = (char*)d_ws;
    size_t off = 0;
    auto alloc = [&](size_t bytes) -> void* {
        void* p = w + off;
        off = (off + bytes + 255) & ~(size_t)255;
        return p;
    };
    const size_t MiB = 1024 * 1024;

    const int BM = N_ * NN_;          // 2048 (b,m) pairs
    const int ROWS_I = BM * T_;       // 32768 neighbor rows
    const int CB = 1024;              // bm per chunk (NCH=2, l=0 only)
    const int RC = CB * T_;           // 16384 rows per chunk
    const int NCH = ROWS_I / RC;      // 2

    float* pe      = (float*)alloc((size_t)T_ * D_ * 4);
    float* xemb    = (float*)alloc((size_t)N_ * T_ * D_ * 4);
    float* nf      = (float*)alloc((size_t)T_ * N_ * NN_ * 3 * 4);
    float* maskf   = (float*)alloc((size_t)BM * T_ * 4);
    u16*   Ab      = (u16*)alloc((size_t)ROWS_I * D_ * 2);     // n_emb bf16  32 MiB
    u16* tQKV[2], *tWSI[2], *tfs1[2], *tfs2[2];
    for (int l = 0; l < 2; ++l) {
        tQKV[l] = (u16*)alloc((size_t)1536 * 512 * 2);
        tWSI[l] = (u16*)alloc((size_t)512 * 4096 * 2);
        tfs1[l] = (u16*)alloc((size_t)2048 * 512 * 2);
        tfs2[l] = (u16*)alloc((size_t)512 * 2048 * 2);
    }
    u16* tWfc = (u16*)alloc((size_t)512 * 512 * 2);
    u16* tfi1 = (u16*)alloc((size_t)2048 * 512 * 2);
    u16* tfi2 = (u16*)alloc((size_t)512 * 2048 * 2);
    // scratch union: l0 chunk: QKVb 48 + ctxb 16 | hid 64 ; l1: QK full 64 MiB
    char* SCR  = (char*)alloc(64 * MiB);
    u16*   QKVb = (u16*)SCR;
    u16*   ctxb = (u16*)(SCR + 48 * MiB);
    u16*   hid  = (u16*)SCR;
    u16*   BbA    = (u16*)alloc((size_t)RC * D_ * 2);  // pre-LN bf16 chunk    16 MiB
    u16*   Bb_res = (u16*)alloc((size_t)RC * D_ * 2);  // res_inter bf16       16 MiB
    float* att_sum = (float*)alloc((size_t)N_ * H_ * 256 * 4);
    u16*   sib     = (u16*)alloc((size_t)N_ * T_ * 4096 * 2);  // 8 MiB
    float* xnew    = (float*)alloc((size_t)N_ * T_ * D_ * 4);
    u16*   xnb     = (u16*)alloc((size_t)N_ * T_ * D_ * 2);
    // total ~170 MiB

    // ---- batched weight conversion: 14 jobs, one launch ----
    WJobs jobs;
    int ntiles = 0;
    auto addJob = [&](int idx, const float* src, u16* dst, int K, int N) {
        jobs.j[idx] = {src, dst, K, N, ntiles};
        ntiles += (N >> 5) * (K >> 5);
    };
    addJob(0,  WQ,                            tQKV[0],              512, 512);
    addJob(1,  WK,                            tQKV[0] + 512 * 512,  512, 512);
    addJob(2,  WV,                            tQKV[0] + 1024 * 512, 512, 512);   // dead at l=1
    addJob(3,  WQ + (size_t)512 * 512,        tQKV[1],              512, 512);
    addJob(4,  WK + (size_t)512 * 512,        tQKV[1] + 512 * 512,  512, 512);
    addJob(5,  Wfc,                           tWfc,                 512, 512);
    addJob(6,  WSI,                           tWSI[0],              4096, 512);
    addJob(7,  WSI + (size_t)4096 * 512,      tWSI[1],              4096, 512);
    addJob(8,  fsw1,                          tfs1[0],              512, 2048);
    addJob(9,  fsw1 + (size_t)512 * 2048,     tfs1[1],              512, 2048);
    addJob(10, fsw2,                          tfs2[0],              2048, 512);
    addJob(11, fsw2 + (size_t)2048 * 512,     tfs2[1],              2048, 512);
    addJob(12, fiw1,                          tfi1,                 512, 2048);
    addJob(13, fiw2,                          tfi2,                 2048, 512);
    wconv_all<<<ntiles, 256, 0, stream>>>(jobs, ntiles);

    pe_kernel<<<16, 256, 0, stream>>>(pe);
    xemb_kernel<<<T_ * N_, 256, 0, stream>>>(x, Wx, bx, pe, xemb);
    nbr_kernel<<<(T_ * N_ * NN_ + 255) / 256, 256, 0, stream>>>(x, nbr, nf, maskf);
    nemb_kernel<<<BM * T_, 256, 0, stream>>>(nf, Wn, bn, pe, Ab);

    for (int l = 0; l < L_; ++l) {
        hipMemsetAsync(att_sum, 0, (size_t)N_ * H_ * 256 * 4, stream);
        if (l == 0) {
            for (int c = 0; c < NCH; ++c) {
                u16* Acb = Ab + (size_t)c * RC * D_;
                // QKV fused GEMM: N=1536, G2' 256x128 (768 blocks = 3 exact rounds)
                gemm_cp<256, 128, 4, 2, 0, 0, 1><<<dim3(12, RC / 256), 512, 0, stream>>>(
                    Acb, tQKV[0], nullptr, QKVb, nullptr, 512, 1536);
                attn_fused_kernel<1, 1536><<<CB, 256, 0, stream>>>(
                    QKVb, maskf, c * CB, att_sum, ctxb);
                // fc + residual(n_emb bf16) -> pre-LN bf16: G2' (256 blocks = 1 round)
                gemm_cp<256, 128, 4, 2, 3, 0, 1><<<dim3(4, RC / 256), 512, 0, stream>>>(
                    ctxb, tWfc, nullptr, BbA, Acb, 512, 512);
                ln_kernel<1><<<RC / 4, 256, 0, stream>>>(
                    BbA, mlng, mlnb, nullptr, Bb_res, RC);   // res_inter bf16
                // ffi1 relu: N=2048, G1' 256x256 (512 blocks = 2 exact rounds)
                gemm_cp<256, 256, 2, 4, 1, 0, 1><<<dim3(8, RC / 256), 512, 0, stream>>>(
                    Bb_res, tfi1, nullptr, hid, nullptr, 512, 2048);
                // ffi2 + residual(res_inter bf16) -> pre-LN bf16: G2' (256 blocks)
                gemm_cp<256, 128, 4, 2, 3, 0, 1><<<dim3(4, RC / 256), 512, 0, stream>>>(
                    hid, tfi2, nullptr, BbA, Bb_res, 2048, 512);
                ln_kernel<1><<<RC / 4, 256, 0, stream>>>(
                    BbA, fig, fib, nullptr, Acb, RC);        // new n_emb (bf16)
            }
        } else {
            // l=1: unchunked QK (N=1024; 64 MiB = SCR): G1' (512 blocks = 2 rounds)
            gemm_cp<256, 256, 2, 4, 0, 0, 1><<<dim3(4, ROWS_I / 256), 512, 0, stream>>>(
                Ab, tQKV[1], nullptr, QKVb, nullptr, 512, 1024);
            attn_fused_kernel<0, 1024><<<BM, 256, 0, stream>>>(
                QKVb, maskf, 0, att_sum, nullptr);
        }

        // ---- self-attention + si + ffs (updates xemb; f32 chain unchanged) ----
        siatt_kernel<<<N_ * H_, 256, 0, stream>>>(xemb, att_sum, attf, sib);
        gemm_bt<32, 64, 0, 1, 1><<<dim3(8, 32), 256, 0, stream>>>(
            sib, tWSI[l], xnew, xnb, nullptr, 4096, 512);
        gemm_bt<32, 64, 1, 0, 1><<<dim3(32, 32), 256, 0, stream>>>(
            xnb, tfs1[l], nullptr, hid, nullptr, 512, 2048);
        gemm_bt<32, 64, 2, 1, 0><<<dim3(8, 32), 256, 0, stream>>>(
            hid, tfs2[l], xemb, nullptr, xnew, 2048, 512);
        ln_kernel<0><<<(N_ * T_) / 4, 256, 0, stream>>>(
            xemb, fsg + l * D_, fsb + l * D_, xemb, nullptr, N_ * T_);
    }

    predbcast_kernel<<<(N_ * T_ * 2 + 255) / 256, 256, 0, stream>>>(
        xemb, Wp, bp, (float*)d_out);
}

// Round 6
// 790.686 us; speedup vs baseline: 1.0807x; 1.0807x over previous
//
#include <hip/hip_runtime.h>
#include <math.h>

// DTYPE COMMITMENTS (evidence-backed): inputs f32, output f32 (rounds 4-14 PASS).
// WS BUDGET: <= ~210 MB decimal; this build ~170 MiB.
// r6: GEMMs reverted to r4's gemm_ct (best measured 813us; r5 schedule regressed +
// showed 41ms profiling outliers). Tail vectorized (ln/attn/siatt) with identical
// FP accumulation order.

#define T_ 16
#define N_ 64
#define NN_ 32
#define D_ 512
#define H_ 8
#define DK_ 64
#define DFF_ 2048
#define L_ 2
#define NPRED_ 20

typedef unsigned short u16;
typedef unsigned int u32;
typedef __attribute__((ext_vector_type(8))) short short8;
typedef __attribute__((ext_vector_type(4))) float f32x4;

__device__ __forceinline__ u16 f2bf(float f) {
    u32 u = __float_as_uint(f);
    u32 r = u + 0x7fffu + ((u >> 16) & 1u);
    return (u16)(r >> 16);
}
__device__ __forceinline__ float bfv(u16 v) {
    return __uint_as_float(((u32)v) << 16);
}
__device__ __forceinline__ float ntn(float v) {
    if (isnan(v)) return 0.0f;
    if (isinf(v)) return v > 0.0f ? 3.4028234663852886e38f : -3.4028234663852886e38f;
    return v;
}
__device__ __forceinline__ float wave_sum(float v) {
    #pragma unroll
    for (int o = 32; o > 0; o >>= 1) v += __shfl_xor(v, o, 64);
    return v;
}
// async 16B HBM->LDS: writes ldsbase + lane*16 (wave-uniform base, per-lane gptr)
__device__ __forceinline__ void gload_lds(const u16* g, u16* l) {
    __builtin_amdgcn_global_load_lds(
        (const __attribute__((address_space(1))) u32*)g,
        (__attribute__((address_space(3))) u32*)l, 16, 0, 0);
}

// ============ batched weight convert+transpose: 14 jobs in ONE launch ===============
struct WJob { const float* src; u16* dst; int K; int N; int t0; };
struct WJobs { WJob j[14]; };
__global__ __launch_bounds__(256) void wconv_all(WJobs jobs, int ntiles) {
    int bid = blockIdx.x;
    if (bid >= ntiles) return;
    int ji = 0;
    #pragma unroll 1
    for (int i = 1; i < 14; ++i) if (bid >= jobs.j[i].t0) ji = i;
    const float* in = jobs.j[ji].src;
    u16* out = jobs.j[ji].dst;
    int K = jobs.j[ji].K, N = jobs.j[ji].N;
    int lt = bid - jobs.j[ji].t0;
    int ntx = N >> 5;
    int nb = (lt % ntx) * 32, kb = (lt / ntx) * 32;
    __shared__ float tile[32][33];
    int tx = threadIdx.x & 31, ty = threadIdx.x >> 5;
    #pragma unroll
    for (int r = ty; r < 32; r += 8)
        tile[r][tx] = in[(size_t)(kb + r) * N + nb + tx];
    __syncthreads();
    #pragma unroll
    for (int r = ty; r < 32; r += 8)
        out[(size_t)(nb + r) * K + kb + tx] = f2bf(tile[tx][r]);
}

// ============ MFMA GEMM v3 + XCD-band remap (kept for small M=1024 GEMMs) ===========
// DMA staging + 3-bit XOR chunk swizzle (r9: 0 bank conflicts); XCD remap (r10).
// EPI: 0 none, 1 relu, 2 +res f32, 3 +res bf16.
template<int TM, int TN, int EPI, int WF32, int WBF16>
__global__ __launch_bounds__(256) void gemm_bt(
    const u16* __restrict__ Ab, const u16* __restrict__ Btb,
    float* __restrict__ Cf, u16* __restrict__ Cb, const void* __restrict__ Rg,
    int K, int ldc)
{
    constexpr int WR = TM / 32, WC = TN / 32;
    constexpr int ITA = TM / 32, ITB = TN / 32;
    __shared__ __align__(16) u16 As[TM][64];
    __shared__ __align__(16) u16 Bs[TN][64];
    int tid = threadIdx.x;
    int lane = tid & 63, wave = tid >> 6;
    int quad = lane >> 4, l16 = lane & 15;
    int wm = (wave >> 1) * (TM / 2), wn = (wave & 1) * (TN / 2);

    int gx = gridDim.x, gy = gridDim.y;
    int bx, by;
    if ((gy & 7) == 0) {
        int id = blockIdx.y * gx + blockIdx.x;
        int xcd = id & 7;
        int slot = id >> 3;
        bx = slot % gx;
        by = xcd * (gy >> 3) + slot / gx;
    } else {
        bx = blockIdx.x;
        by = blockIdx.y;
    }
    size_t row0 = (size_t)by * TM;
    size_t col0 = (size_t)bx * TN;

    f32x4 acc[WR][WC];
    #pragma unroll
    for (int i = 0; i < WR; ++i)
        #pragma unroll
        for (int j = 0; j < WC; ++j)
            acc[i][j] = (f32x4){0.f, 0.f, 0.f, 0.f};

    int srow = lane >> 3;
    int c8 = (lane & 7) ^ srow;
    int h8 = l16 & 7;

    for (int k0 = 0; k0 < K; k0 += 64) {
        __syncthreads();
        #pragma unroll
        for (int it = 0; it < ITA; ++it) {
            int g = wave + it * 4;
            gload_lds(Ab + (row0 + g * 8 + srow) * (size_t)K + k0 + c8 * 8, &As[g * 8][0]);
        }
        #pragma unroll
        for (int it = 0; it < ITB; ++it) {
            int g = wave + it * 4;
            gload_lds(Btb + (col0 + g * 8 + srow) * (size_t)K + k0 + c8 * 8, &Bs[g * 8][0]);
        }
        __syncthreads();
        #pragma unroll
        for (int s = 0; s < 2; ++s) {
            int coff = ((s * 4 + quad) ^ h8) * 8;   // full 3-bit XOR (r9-verified)
            short8 af[WR], bf[WC];
            #pragma unroll
            for (int i = 0; i < WR; ++i)
                af[i] = *(short8*)&As[wm + i * 16 + l16][coff];
            #pragma unroll
            for (int j = 0; j < WC; ++j)
                bf[j] = *(short8*)&Bs[wn + j * 16 + l16][coff];
            #pragma unroll
            for (int i = 0; i < WR; ++i)
                #pragma unroll
                for (int j = 0; j < WC; ++j)
                    acc[i][j] = __builtin_amdgcn_mfma_f32_16x16x32_bf16(
                        af[i], bf[j], acc[i][j], 0, 0, 0);
        }
    }
    // C/D layout (on-target verified): col = lane&15, row = quad*4 + reg
    #pragma unroll
    for (int i = 0; i < WR; ++i)
        #pragma unroll
        for (int j = 0; j < WC; ++j)
            #pragma unroll
            for (int reg = 0; reg < 4; ++reg) {
                size_t row = row0 + wm + i * 16 + quad * 4 + reg;
                size_t col = col0 + wn + j * 16 + l16;
                float v = acc[i][j][reg];
                if (EPI == 2) v += ((const float*)Rg)[row * (size_t)ldc + col];
                if (EPI == 3) v += bfv(((const u16*)Rg)[row * (size_t)ldc + col]);
                if (EPI == 1) v = fmaxf(v, 0.f);
                if (WF32)  Cf[row * (size_t)ldc + col] = v;
                if (WBF16) Cb[row * (size_t)ldc + col] = f2bf(v);
            }
}

// ============ counted-pipeline GEMM: 128x128, BK=64, 2 barriers/tile (r4 best) ======
// Per K-tile: (1) issue 8 gload_lds for tile t+1 into the other LDS buffer FIRST;
// (2) s_waitcnt vmcnt(8) -- counted: the 8 just-issued loads stay IN FLIGHT, only
// tile t's loads (issued one full tile ago) must have landed; (3) one rendezvous
// s_barrier; (4) full 32-MFMA compute, setprio-wrapped, no intra-tile barriers;
// (5) one end barrier protecting the buffer restaged next iteration. vmcnt(0) only
// at the last tile. LDS 64KiB -> 2 blocks/CU. r9 XOR swizzle (0 conflicts).
// Requires M%128==0, N%128==0, K%64==0 (K>=128), gridDim.y%8==0 (XCD remap).
template<int EPI, int WF32, int WBF16>
__global__ __launch_bounds__(256, 2) void gemm_ct(
    const u16* __restrict__ Ab, const u16* __restrict__ Btb,
    float* __restrict__ Cf, u16* __restrict__ Cb, const void* __restrict__ Rg,
    int K, int ldc)
{
    __shared__ __align__(16) u16 As[2][128][64];
    __shared__ __align__(16) u16 Bs[2][128][64];
    int tid = threadIdx.x;
    int lane = tid & 63, wave = tid >> 6;       // 4 waves: 2M x 2N
    int quad = lane >> 4, l16 = lane & 15;
    int wm = (wave >> 1) * 64, wn = (wave & 1) * 64;

    int gx = gridDim.x, gy = gridDim.y;
    int id = blockIdx.y * gx + blockIdx.x;
    int xcd = id & 7, slot = id >> 3;
    int bx = slot % gx;
    int by = xcd * (gy >> 3) + slot / gx;
    size_t row0 = (size_t)by * 128;
    size_t col0 = (size_t)bx * 128;

    f32x4 acc[4][4];
    #pragma unroll
    for (int i = 0; i < 4; ++i)
        #pragma unroll
        for (int j = 0; j < 4; ++j)
            acc[i][j] = (f32x4){0.f, 0.f, 0.f, 0.f};

    // staging swizzle (r9-verified): physical 16B chunk p of row r holds logical
    // chunk p ^ (r&7)
    int srow = lane >> 3;
    int c8 = (lane & 7) ^ srow;
    int h8 = l16 & 7;
    size_t aoff[4], boff[4];
    #pragma unroll
    for (int it = 0; it < 4; ++it) {
        aoff[it] = (row0 + (size_t)(wave + it * 4) * 8 + srow) * (size_t)K + c8 * 8;
        boff[it] = (col0 + (size_t)(wave + it * 4) * 8 + srow) * (size_t)K + c8 * 8;
    }

    int nt = K >> 6;
    // prologue: stage tile 0 -> buf 0 (8 loads in flight, no wait)
    #pragma unroll
    for (int it = 0; it < 4; ++it)
        gload_lds(Ab + aoff[it], &As[0][(wave + it * 4) * 8][0]);
    #pragma unroll
    for (int it = 0; it < 4; ++it)
        gload_lds(Btb + boff[it], &Bs[0][(wave + it * 4) * 8][0]);

    #pragma unroll 1
    for (int t = 0; t < nt; ++t) {
        int cur = t & 1;
        if (t + 1 < nt) {
            // stage tile t+1 into other buffer (freed by iter t-1's end barrier)
            size_t ko = (size_t)(t + 1) * 64;
            #pragma unroll
            for (int it = 0; it < 4; ++it)
                gload_lds(Ab + aoff[it] + ko, &As[cur ^ 1][(wave + it * 4) * 8][0]);
            #pragma unroll
            for (int it = 0; it < 4; ++it)
                gload_lds(Btb + boff[it] + ko, &Bs[cur ^ 1][(wave + it * 4) * 8][0]);
            __builtin_amdgcn_sched_barrier(0);
            asm volatile("s_waitcnt vmcnt(8)" ::: "memory");   // tile t landed; t+1 in flight
        } else {
            __builtin_amdgcn_sched_barrier(0);
            asm volatile("s_waitcnt vmcnt(0)" ::: "memory");   // final tile only
        }
        __builtin_amdgcn_sched_barrier(0);
        __builtin_amdgcn_s_barrier();                          // rendezvous: tile t staged
        __builtin_amdgcn_sched_barrier(0);
        __builtin_amdgcn_s_setprio(1);
        #pragma unroll
        for (int kh = 0; kh < 2; ++kh) {
            int coff = ((kh * 4 + quad) ^ h8) * 8;
            short8 af[4], bf[4];
            #pragma unroll
            for (int j = 0; j < 4; ++j)
                bf[j] = *(short8*)&Bs[cur][wn + j * 16 + l16][coff];
            #pragma unroll
            for (int i = 0; i < 4; ++i)
                af[i] = *(short8*)&As[cur][wm + i * 16 + l16][coff];
            #pragma unroll
            for (int i = 0; i < 4; ++i)
                #pragma unroll
                for (int j = 0; j < 4; ++j)
                    acc[i][j] = __builtin_amdgcn_mfma_f32_16x16x32_bf16(
                        af[i], bf[j], acc[i][j], 0, 0, 0);
        }
        __builtin_amdgcn_s_setprio(0);
        __builtin_amdgcn_sched_barrier(0);                     // reads done before barrier
        __builtin_amdgcn_s_barrier();                          // frees buf[cur] for restage
    }

    // C/D layout (on-target verified): col = lane&15, row = quad*4 + reg
    #pragma unroll
    for (int i = 0; i < 4; ++i)
        #pragma unroll
        for (int j = 0; j < 4; ++j)
            #pragma unroll
            for (int reg = 0; reg < 4; ++reg) {
                size_t row = row0 + wm + i * 16 + quad * 4 + reg;
                size_t col = col0 + wn + j * 16 + l16;
                float v = acc[i][j][reg];
                if (EPI == 2) v += ((const float*)Rg)[row * (size_t)ldc + col];
                if (EPI == 3) v += bfv(((const u16*)Rg)[row * (size_t)ldc + col]);
                if (EPI == 1) v = fmaxf(v, 0.f);
                if (WF32)  Cf[row * (size_t)ldc + col] = v;
                if (WBF16) Cb[row * (size_t)ldc + col] = f2bf(v);
            }
}

// ============ fused attention per (b,m): all-heads phases, 3 barriers ===============
// r6: QK dot reads uint4 (4x fewer LDS ops, identical FMA order); ctx phase uint2
// (2 u32 cols per thread, per-col accumulators preserve order).
template<int CTX, int LD>
__global__ __launch_bounds__(256) void attn_fused_kernel(
    const u16* __restrict__ QKVb, const float* __restrict__ maskf, int bm0,
    float* __restrict__ att_sum, u16* __restrict__ ctxb)
{
    __shared__ __align__(16) u16 sQ[16][520];
    __shared__ __align__(16) u16 sK[16][520];
    __shared__ __align__(16) u16 sV[CTX ? 16 : 1][520];
    __shared__ float s_p[H_][16][17];
    int bm_l = blockIdx.x;
    int tid = threadIdx.x;
    int t = tid >> 4, ch = (tid & 15) * 32;
    const u16* base = QKVb + ((size_t)bm_l * T_ + t) * LD;
    #pragma unroll
    for (int c = 0; c < 4; ++c) {
        *(uint4*)&sQ[t][ch + c * 8] = *(const uint4*)(base + ch + c * 8);
        *(uint4*)&sK[t][ch + c * 8] = *(const uint4*)(base + 512 + ch + c * 8);
        if (CTX) *(uint4*)&sV[t][ch + c * 8] = *(const uint4*)(base + 1024 + ch + c * 8);
    }
    __syncthreads();

    int b = (bm0 + bm_l) >> 5;                  // bm = b*NN + m

    #pragma unroll
    for (int r = 0; r < 8; ++r) {
        int h = r;
        int q = (tid >> 4) & 15, k = tid & 15;
        // rows are 1040B apart (520 u16) -> 16B aligned; h*32 u32 = h*8 uint4
        const uint4* qu4 = (const uint4*)&sQ[q][0] + h * 8;
        const uint4* ku4 = (const uint4*)&sK[k][0] + h * 8;
        float acc = 0.f;
        #pragma unroll
        for (int j = 0; j < 8; ++j) {
            uint4 a4 = qu4[j], b4 = ku4[j];
            #pragma unroll
            for (int w = 0; w < 4; ++w) {
                u32 a = (&a4.x)[w], bb = (&b4.x)[w];
                acc += bfv((u16)(a & 0xffff)) * bfv((u16)(bb & 0xffff));
                acc += bfv((u16)(a >> 16))    * bfv((u16)(bb >> 16));
            }
        }
        acc *= 0.125f;
        if (maskf[(size_t)(bm0 + bm_l) * T_ + q] == 0.0f) acc = -1e9f;
        s_p[h][q][k] = acc;
    }
    __syncthreads();
    if (tid < 128) {
        int h = tid >> 4, q = tid & 15;
        float mx = -3.4e38f;
        #pragma unroll
        for (int kk = 0; kk < 16; ++kk) mx = fmaxf(mx, s_p[h][q][kk]);
        float e[16], s = 0.f;
        #pragma unroll
        for (int kk = 0; kk < 16; ++kk) { e[kk] = expf(s_p[h][q][kk] - mx); s += e[kk]; }
        float inv = 1.0f / s;
        #pragma unroll
        for (int kk = 0; kk < 16; ++kk) s_p[h][q][kk] = e[kk] * inv;
    }
    __syncthreads();
    #pragma unroll
    for (int r = 0; r < 8; ++r) {
        int h = r;
        int q = (tid >> 4) & 15, k = tid & 15;
        atomicAdd(&att_sum[(((size_t)b * H_ + h) * T_ + q) * T_ + k], s_p[h][q][k]);
    }
    if (CTX) {
        // 4 consecutive cols (2 u32) per step: uint2 sV reads, uint2 ctxb writes
        #pragma unroll
        for (int rep = 0; rep < 8; ++rep) {
            int i2 = rep * 256 + tid;           // t*128 + cu, cu = uint2 col index
            int tt = i2 >> 7, cu = i2 & 127;
            int h = cu >> 4;                    // (cu*2)>>5; pair never crosses a head
            const float* pr = &s_p[h][tt][0];
            float a0 = 0.f, a1 = 0.f, a2 = 0.f, a3 = 0.f;
            #pragma unroll
            for (int kk = 0; kk < 16; ++kk) {
                uint2 vv = *((const uint2*)&sV[kk][0] + cu);
                float p = pr[kk];
                a0 += p * bfv((u16)(vv.x & 0xffff));
                a1 += p * bfv((u16)(vv.x >> 16));
                a2 += p * bfv((u16)(vv.y & 0xffff));
                a3 += p * bfv((u16)(vv.y >> 16));
            }
            uint2 o;
            o.x = (u32)f2bf(a0) | ((u32)f2bf(a1) << 16);
            o.y = (u32)f2bf(a2) | ((u32)f2bf(a3) << 16);
            *(uint2*)((u32*)(ctxb + ((size_t)bm_l * T_ + tt) * D_) + cu * 2) = o;
        }
    }
}

// ============ fused self-attention + combine + si, one block per (n,h) ==============
// r6: qk dot via float4 LDS reads (4x fewer LDS ops, identical FMA order).
__global__ __launch_bounds__(256) void siatt_kernel(
    const float* __restrict__ xemb, const float* __restrict__ att_sum,
    const float* __restrict__ attf, u16* __restrict__ sib)
{
    __shared__ float sX[16][516];
    __shared__ float sS[16][17];
    __shared__ float sA[16][17];
    int n = blockIdx.x >> 3, h = blockIdx.x & 7;
    int tid = threadIdx.x;
    int t = tid >> 4, ch = (tid & 15) * 32;
    const float* src = xemb + ((size_t)n * T_ + t) * D_;
    #pragma unroll
    for (int c = 0; c < 8; ++c)
        *(float4*)&sX[t][ch + c * 4] = *(const float4*)(src + ch + c * 4);
    __syncthreads();
    int q = tid >> 4, k = tid & 15;
    {
        // row stride 516 f32 = 2064B (16B aligned); same accumulation order
        float acc = 0.f;
        for (int d4 = 0; d4 < D_ / 4; ++d4) {
            float4 xq = *(const float4*)&sX[q][d4 * 4];
            float4 xk = *(const float4*)&sX[k][d4 * 4];
            acc += xq.x * xk.x;
            acc += xq.y * xk.y;
            acc += xq.z * xk.z;
            acc += xq.w * xk.w;
        }
        sS[q][k] = acc * 0.04419417382415922f;
    }
    __syncthreads();
    if (tid < T_) {
        float mx = -3.4e38f;
        #pragma unroll
        for (int kk = 0; kk < 16; ++kk) mx = fmaxf(mx, sS[tid][kk]);
        float e[16], s = 0.f;
        #pragma unroll
        for (int kk = 0; kk < 16; ++kk) { e[kk] = expf(sS[tid][kk] - mx); s += e[kk]; }
        float inv = 1.0f / s;
        #pragma unroll
        for (int kk = 0; kk < 16; ++kk) sS[tid][kk] = e[kk] * inv;
    }
    __syncthreads();
    float f = attf[0] * (1.0f / 32.0f);
    sA[q][k] = sS[q][k] + f * att_sum[((size_t)n * H_ + h) * 256 + q * 16 + k];
    __syncthreads();
    #pragma unroll
    for (int rep = 0; rep < 16; ++rep) {
        int i2 = rep * 256 + tid;          // q*256 + d2
        int qq = i2 >> 8, d2 = (i2 & 255) * 2;
        const float* ar = &sA[qq][0];
        float a0 = 0.f, a1 = 0.f;
        #pragma unroll
        for (int tt = 0; tt < 16; ++tt) {
            float p = ar[tt];
            a0 += p * sX[tt][d2];
            a1 += p * sX[tt][d2 + 1];
        }
        u32 o = (u32)f2bf(a0) | ((u32)f2bf(a1) << 16);
        *((u32*)(sib + (size_t)n * T_ * 4096 + (size_t)qq * 4096 + h * 512) + (d2 >> 1)) = o;
    }
}

// ---------------- positional encoding ------------------------------------------------
__global__ void pe_kernel(float* pe) {
    int i = blockIdx.x * blockDim.x + threadIdx.x;
    if (i >= T_ * 256) return;
    int t = i >> 8, j = i & 255;
    float dv = (float)pow(10000.0, (double)j / 256.0);
    float a = (float)t * dv;
    double ad = (double)a;
    pe[t * D_ + 2 * j]     = (float)sin(ad);
    pe[t * D_ + 2 * j + 1] = (float)cos(ad);
}

// ---------------- x features + embed -------------------------------------------------
__global__ void xemb_kernel(const float* x, const float* Wx, const float* bx,
                            const float* pe, float* xemb) {
    int row = blockIdx.x;              // t*N + n
    int t = row / N_, n = row % N_;
    float x0 = x[row * 6 + 0], x1 = x[row * 6 + 1];
    float x2 = x[row * 6 + 2], x3 = x[row * 6 + 3];
    float x4 = x[row * 6 + 4], x5 = x[row * 6 + 5];
    float vel = sqrtf(x2 * x2 + x3 * x3);
    float ang = atanf(x5 / x4);
    float f0 = ntn(x0), f1 = ntn(x1), f2 = ntn(vel), f3 = ntn(ang);
    for (int d = threadIdx.x; d < D_; d += blockDim.x) {
        xemb[((size_t)n * T_ + t) * D_ + d] =
            f0 * Wx[0 * D_ + d] + f1 * Wx[1 * D_ + d]
          + f2 * Wx[2 * D_ + d] + f3 * Wx[3 * D_ + d]
          + bx[d] + pe[t * D_ + d];
    }
}

// ---------------- neighbor features + mask -------------------------------------------
__global__ void nbr_kernel(const float* x, const float* nbr, float* nf, float* maskf) {
    int idx = blockIdx.x * blockDim.x + threadIdx.x;   // t*N*NN + n*NN + m
    if (idx >= T_ * N_ * NN_) return;
    int m = idx % NN_;
    int tn = idx / NN_;
    int n = tn % N_, t = tn / N_;
    float px = x[((size_t)t * N_ + n) * 6 + 0];
    float py = x[((size_t)t * N_ + n) * 6 + 1];
    float vx, vy;
    if (t == 0) {
        vx = x[((size_t)1 * N_ + n) * 6 + 2];
        vy = x[((size_t)1 * N_ + n) * 6 + 3];
    } else {
        vx = px - x[((size_t)(t - 1) * N_ + n) * 6 + 0];
        vy = py - x[((size_t)(t - 1) * N_ + n) * 6 + 1];
    }
    float nx  = nbr[(size_t)idx * 4 + 0], ny  = nbr[(size_t)idx * 4 + 1];
    float nvx = nbr[(size_t)idx * 4 + 2], nvy = nbr[(size_t)idx * 4 + 3];
    float dpx = nx - px, dpy = ny - py;
    float dvx = nvx - vx, dvy = nvy - vy;
    float dist = sqrtf(dpx * dpx + dpy * dpy);
    maskf[((size_t)n * NN_ + m) * T_ + t] = (dist <= 2.0f) ? 1.0f : 0.0f;
    float vn = sqrtf(vx * vx + vy * vy);
    float bearing = (dpx * vx + dpy * vy) / (dist * vn);
    if (isnan(bearing)) bearing = 0.0f;
    float dvn = sqrtf(dvx * dvx + dvy * dvy);
    float tau = -(dpx * dvx + dpy * dvy) / dvn;
    if (isnan(tau)) tau = 0.0f;
    tau = fminf(fmaxf(tau, 0.0f), 7.0f);
    float mx_ = dpx + tau * dvx, my_ = dpy + tau * dvy;
    float mpd = sqrtf(mx_ * mx_ + my_ * my_);
    nf[(size_t)idx * 3 + 0] = ntn(dist);
    nf[(size_t)idx * 3 + 1] = ntn(bearing);
    nf[(size_t)idx * 3 + 2] = ntn(mpd);
}

// ---------------- neighbor embed: bf16 n_emb only ------------------------------------
__global__ void nemb_kernel(const float* nf, const float* Wn, const float* bn,
                            const float* pe, u16* Ab) {
    int row = blockIdx.x;              // (b*NN+m)*T + t
    int t = row % T_;
    int bm = row / T_;
    int m = bm % NN_, b = bm / NN_;
    size_t nfrow = (((size_t)t * N_ + b) * NN_ + m) * 3;
    float f0 = nf[nfrow], f1 = nf[nfrow + 1], f2 = nf[nfrow + 2];
    for (int d = threadIdx.x; d < D_; d += blockDim.x) {
        float v = f0 * Wn[d] + f1 * Wn[D_ + d] + f2 * Wn[2 * D_ + d]
                + bn[d] + pe[t * D_ + d];
        Ab[(size_t)row * D_ + d] = f2bf(v);
    }
}

// ---------------- LayerNorm, one wave per row; input f32 or bf16; dual out -----------
// r6: vectorized -- lane owns 8 CONTIGUOUS elements (short8 / 2x float4 loads,
// packed stores). Reduction set identical (order perturbation ~1e-6, tol 1.6e-2).
template<int INBF>
__global__ __launch_bounds__(256) void ln_kernel(
    const void* X, const float* g, const float* b, float* outF, u16* outB, int nrows) {
    int row = blockIdx.x * 4 + (threadIdx.x >> 6);
    if (row >= nrows) return;
    int lane = threadIdx.x & 63;
    int d0 = lane * 8;
    float v[8];
    if (INBF) {
        short8 x8 = *(const short8*)((const u16*)X + (size_t)row * D_ + d0);
        #pragma unroll
        for (int r = 0; r < 8; ++r) v[r] = bfv((u16)x8[r]);
    } else {
        float4 a = *(const float4*)((const float*)X + (size_t)row * D_ + d0);
        float4 c = *(const float4*)((const float*)X + (size_t)row * D_ + d0 + 4);
        v[0] = a.x; v[1] = a.y; v[2] = a.z; v[3] = a.w;
        v[4] = c.x; v[5] = c.y; v[6] = c.z; v[7] = c.w;
    }
    float s = 0.f;
    #pragma unroll
    for (int r = 0; r < 8; ++r) s += v[r];
    s = wave_sum(s);
    float mean = s * (1.0f / 512.0f);
    float vs = 0.f;
    #pragma unroll
    for (int r = 0; r < 8; ++r) { float d = v[r] - mean; vs += d * d; }
    vs = wave_sum(vs);
    float rstd = rsqrtf(vs * (1.0f / 512.0f) + 1e-5f);
    float4 g0 = *(const float4*)&g[d0], g1 = *(const float4*)&g[d0 + 4];
    float4 b0 = *(const float4*)&b[d0], b1 = *(const float4*)&b[d0 + 4];
    float o[8];
    o[0] = (v[0] - mean) * rstd * g0.x + b0.x;
    o[1] = (v[1] - mean) * rstd * g0.y + b0.y;
    o[2] = (v[2] - mean) * rstd * g0.z + b0.z;
    o[3] = (v[3] - mean) * rstd * g0.w + b0.w;
    o[4] = (v[4] - mean) * rstd * g1.x + b1.x;
    o[5] = (v[5] - mean) * rstd * g1.y + b1.y;
    o[6] = (v[6] - mean) * rstd * g1.z + b1.z;
    o[7] = (v[7] - mean) * rstd * g1.w + b1.w;
    if (outF) {
        float4 w0 = {o[0], o[1], o[2], o[3]};
        float4 w1 = {o[4], o[5], o[6], o[7]};
        *(float4*)(outF + (size_t)row * D_ + d0) = w0;
        *(float4*)(outF + (size_t)row * D_ + d0 + 4) = w1;
    }
    if (outB) {
        short8 w;
        #pragma unroll
        for (int r = 0; r < 8; ++r) w[r] = (short)f2bf(o[r]);
        *(short8*)(outB + (size_t)row * D_ + d0) = w;
    }
}

// ---------------- prediction head + broadcast fused (f32 out) ------------------------
__global__ void predbcast_kernel(const float* xemb, const float* Wp, const float* bp,
                                 float* out) {
    int idx = blockIdx.x * blockDim.x + threadIdx.x;   // (n*T+t)*2 + c
    if (idx >= N_ * T_ * 2) return;
    int c = idx & 1;
    int nt = idx >> 1;
    int n = nt / T_, t = nt % T_;
    float acc = bp[c];
    for (int j = 0; j < D_; ++j) acc += xemb[(size_t)nt * D_ + j] * Wp[(size_t)j * 2 + c];
    #pragma unroll
    for (int p = 0; p < NPRED_; ++p)
        out[(((size_t)p * T_ + t) * N_ + n) * 2 + c] = acc;
}

extern "C" void kernel_launch(void* const* d_in, const int* in_sizes, int n_in,
                              void* d_out, int out_size, void* d_ws, size_t ws_size,
                              hipStream_t stream) {
    (void)in_sizes; (void)n_in; (void)out_size; (void)ws_size;

    const float* x    = (const float*)d_in[0];
    const float* nbr  = (const float*)d_in[1];
    const float* attf = (const float*)d_in[2];
    const float* Wx   = (const float*)d_in[3];
    const float* bx   = (const float*)d_in[4];
    const float* Wn   = (const float*)d_in[5];
    const float* bn   = (const float*)d_in[6];
    const float* Wp   = (const float*)d_in[7];
    const float* bp   = (const float*)d_in[8];
    const float* WQ   = (const float*)d_in[9];
    const float* WK   = (const float*)d_in[10];
    const float* WV   = (const float*)d_in[11];
    const float* Wfc  = (const float*)d_in[12];
    const float* mlng = (const float*)d_in[13];
    const float* mlnb = (const float*)d_in[14];
    const float* WSI  = (const float*)d_in[15];
    const float* fsw1 = (const float*)d_in[16];
    const float* fsw2 = (const float*)d_in[17];
    const float* fsg  = (const float*)d_in[18];
    const float* fsb  = (const float*)d_in[19];
    const float* fiw1 = (const float*)d_in[20];
    const float* fiw2 = (const float*)d_in[21];
    const float* fig  = (const float*)d_in[22];
    const float* fib  = (const float*)d_in[23];

    char* w = (char*)d_ws;
    size_t off = 0;
    auto alloc = [&](size_t bytes) -> void* {
        void* p = w + off;
        off = (off + bytes + 255) & ~(size_t)255;
        return p;
    };
    const size_t MiB = 1024 * 1024;

    const int BM = N_ * NN_;          // 2048 (b,m) pairs
    const int ROWS_I = BM * T_;       // 32768 neighbor rows
    const int CB = 1024;              // bm per chunk (NCH=2, l=0 only)
    const int RC = CB * T_;           // 16384 rows per chunk
    const int NCH = ROWS_I / RC;      // 2

    float* pe      = (float*)alloc((size_t)T_ * D_ * 4);
    float* xemb    = (float*)alloc((size_t)N_ * T_ * D_ * 4);
    float* nf      = (float*)alloc((size_t)T_ * N_ * NN_ * 3 * 4);
    float* maskf   = (float*)alloc((size_t)BM * T_ * 4);
    u16*   Ab      = (u16*)alloc((size_t)ROWS_I * D_ * 2);     // n_emb bf16  32 MiB
    u16* tQKV[2], *tWSI[2], *tfs1[2], *tfs2[2];
    for (int l = 0; l < 2; ++l) {
        tQKV[l] = (u16*)alloc((size_t)1536 * 512 * 2);
        tWSI[l] = (u16*)alloc((size_t)512 * 4096 * 2);
        tfs1[l] = (u16*)alloc((size_t)2048 * 512 * 2);
        tfs2[l] = (u16*)alloc((size_t)512 * 2048 * 2);
    }
    u16* tWfc = (u16*)alloc((size_t)512 * 512 * 2);
    u16* tfi1 = (u16*)alloc((size_t)2048 * 512 * 2);
    u16* tfi2 = (u16*)alloc((size_t)512 * 2048 * 2);
    // scratch union: l0 chunk: QKVb 48 + ctxb 16 | hid 64 ; l1: QK full 64 MiB
    char* SCR  = (char*)alloc(64 * MiB);
    u16*   QKVb = (u16*)SCR;
    u16*   ctxb = (u16*)(SCR + 48 * MiB);
    u16*   hid  = (u16*)SCR;
    u16*   BbA    = (u16*)alloc((size_t)RC * D_ * 2);  // pre-LN bf16 chunk    16 MiB
    u16*   Bb_res = (u16*)alloc((size_t)RC * D_ * 2);  // res_inter bf16       16 MiB
    float* att_sum = (float*)alloc((size_t)N_ * H_ * 256 * 4);
    u16*   sib     = (u16*)alloc((size_t)N_ * T_ * 4096 * 2);  // 8 MiB
    float* xnew    = (float*)alloc((size_t)N_ * T_ * D_ * 4);
    u16*   xnb     = (u16*)alloc((size_t)N_ * T_ * D_ * 2);
    // total ~170 MiB

    // ---- batched weight conversion: 14 jobs, one launch ----
    WJobs jobs;
    int ntiles = 0;
    auto addJob = [&](int idx, const float* src, u16* dst, int K, int N) {
        jobs.j[idx] = {src, dst, K, N, ntiles};
        ntiles += (N >> 5) * (K >> 5);
    };
    addJob(0,  WQ,                            tQKV[0],              512, 512);
    addJob(1,  WK,                            tQKV[0] + 512 * 512,  512, 512);
    addJob(2,  WV,                            tQKV[0] + 1024 * 512, 512, 512);   // dead at l=1
    addJob(3,  WQ + (size_t)512 * 512,        tQKV[1],              512, 512);
    addJob(4,  WK + (size_t)512 * 512,        tQKV[1] + 512 * 512,  512, 512);
    addJob(5,  Wfc,                           tWfc,                 512, 512);
    addJob(6,  WSI,                           tWSI[0],              4096, 512);
    addJob(7,  WSI + (size_t)4096 * 512,      tWSI[1],              4096, 512);
    addJob(8,  fsw1,                          tfs1[0],              512, 2048);
    addJob(9,  fsw1 + (size_t)512 * 2048,     tfs1[1],              512, 2048);
    addJob(10, fsw2,                          tfs2[0],              2048, 512);
    addJob(11, fsw2 + (size_t)2048 * 512,     tfs2[1],              2048, 512);
    addJob(12, fiw1,                          tfi1,                 512, 2048);
    addJob(13, fiw2,                          tfi2,                 2048, 512);
    wconv_all<<<ntiles, 256, 0, stream>>>(jobs, ntiles);

    pe_kernel<<<16, 256, 0, stream>>>(pe);
    xemb_kernel<<<T_ * N_, 256, 0, stream>>>(x, Wx, bx, pe, xemb);
    nbr_kernel<<<(T_ * N_ * NN_ + 255) / 256, 256, 0, stream>>>(x, nbr, nf, maskf);
    nemb_kernel<<<BM * T_, 256, 0, stream>>>(nf, Wn, bn, pe, Ab);

    for (int l = 0; l < L_; ++l) {
        hipMemsetAsync(att_sum, 0, (size_t)N_ * H_ * 256 * 4, stream);
        if (l == 0) {
            for (int c = 0; c < NCH; ++c) {
                u16* Acb = Ab + (size_t)c * RC * D_;
                // QKV fused GEMM: N=1536 (1536 blocks = 3 exact rounds @2/CU)
                gemm_ct<0, 0, 1><<<dim3(12, RC / 128), 256, 0, stream>>>(
                    Acb, tQKV[0], nullptr, QKVb, nullptr, 512, 1536);
                attn_fused_kernel<1, 1536><<<CB, 256, 0, stream>>>(
                    QKVb, maskf, c * CB, att_sum, ctxb);
                // fc + residual(n_emb bf16) -> pre-LN bf16 (512 blocks = 1 round)
                gemm_ct<3, 0, 1><<<dim3(4, RC / 128), 256, 0, stream>>>(
                    ctxb, tWfc, nullptr, BbA, Acb, 512, 512);
                ln_kernel<1><<<RC / 4, 256, 0, stream>>>(
                    BbA, mlng, mlnb, nullptr, Bb_res, RC);   // res_inter bf16
                // ffi1 relu: N=2048 (2048 blocks = 4 exact rounds)
                gemm_ct<1, 0, 1><<<dim3(16, RC / 128), 256, 0, stream>>>(
                    Bb_res, tfi1, nullptr, hid, nullptr, 512, 2048);
                // ffi2 + residual(res_inter bf16) -> pre-LN bf16 (512 blocks)
                gemm_ct<3, 0, 1><<<dim3(4, RC / 128), 256, 0, stream>>>(
                    hid, tfi2, nullptr, BbA, Bb_res, 2048, 512);
                ln_kernel<1><<<RC / 4, 256, 0, stream>>>(
                    BbA, fig, fib, nullptr, Acb, RC);        // new n_emb (bf16)
            }
        } else {
            // l=1: unchunked QK (N=1024, ldc=1024; 64 MiB = SCR): 2048 blocks
            gemm_ct<0, 0, 1><<<dim3(8, ROWS_I / 128), 256, 0, stream>>>(
                Ab, tQKV[1], nullptr, QKVb, nullptr, 512, 1024);
            attn_fused_kernel<0, 1024><<<BM, 256, 0, stream>>>(
                QKVb, maskf, 0, att_sum, nullptr);
        }

        // ---- self-attention + si + ffs (updates xemb; f32 chain unchanged) ----
        siatt_kernel<<<N_ * H_, 256, 0, stream>>>(xemb, att_sum, attf, sib);
        gemm_bt<32, 64, 0, 1, 1><<<dim3(8, 32), 256, 0, stream>>>(
            sib, tWSI[l], xnew, xnb, nullptr, 4096, 512);
        gemm_bt<32, 64, 1, 0, 1><<<dim3(32, 32), 256, 0, stream>>>(
            xnb, tfs1[l], nullptr, hid, nullptr, 512, 2048);
        gemm_bt<32, 64, 2, 1, 0><<<dim3(8, 32), 256, 0, stream>>>(
            hid, tfs2[l], xemb, nullptr, xnew, 2048, 512);
        ln_kernel<0><<<(N_ * T_) / 4, 256, 0, stream>>>(
            xemb, fsg + l * D_, fsb + l * D_, xemb, nullptr, N_ * T_);
    }

    predbcast_kernel<<<(N_ * T_ * 2 + 255) / 256, 256, 0, stream>>>(
        xemb, Wp, bp, (float*)d_out);
}

// Round 7
// 768.347 us; speedup vs baseline: 1.1121x; 1.0291x over previous
//
#include <hip/hip_runtime.h>
#include <math.h>

// DTYPE COMMITMENTS (evidence-backed): inputs f32, output f32 (rounds 4-14 PASS).
// WS BUDGET: <= ~210 MB decimal; this build ~170 MiB.
// r7: GEMMs frozen at r4/r6 state (gemm_ct best measured). attn_fused QK^T moved
// to MFMA (verified 16x16x32 layout; S stays f32 -> softmax numerics unchanged).
// predbcast vectorized. Everything else byte-identical to the 790us build.

#define T_ 16
#define N_ 64
#define NN_ 32
#define D_ 512
#define H_ 8
#define DK_ 64
#define DFF_ 2048
#define L_ 2
#define NPRED_ 20

typedef unsigned short u16;
typedef unsigned int u32;
typedef __attribute__((ext_vector_type(8))) short short8;
typedef __attribute__((ext_vector_type(4))) float f32x4;

__device__ __forceinline__ u16 f2bf(float f) {
    u32 u = __float_as_uint(f);
    u32 r = u + 0x7fffu + ((u >> 16) & 1u);
    return (u16)(r >> 16);
}
__device__ __forceinline__ float bfv(u16 v) {
    return __uint_as_float(((u32)v) << 16);
}
__device__ __forceinline__ float ntn(float v) {
    if (isnan(v)) return 0.0f;
    if (isinf(v)) return v > 0.0f ? 3.4028234663852886e38f : -3.4028234663852886e38f;
    return v;
}
__device__ __forceinline__ float wave_sum(float v) {
    #pragma unroll
    for (int o = 32; o > 0; o >>= 1) v += __shfl_xor(v, o, 64);
    return v;
}
// async 16B HBM->LDS: writes ldsbase + lane*16 (wave-uniform base, per-lane gptr)
__device__ __forceinline__ void gload_lds(const u16* g, u16* l) {
    __builtin_amdgcn_global_load_lds(
        (const __attribute__((address_space(1))) u32*)g,
        (__attribute__((address_space(3))) u32*)l, 16, 0, 0);
}

// ============ batched weight convert+transpose: 14 jobs in ONE launch ===============
struct WJob { const float* src; u16* dst; int K; int N; int t0; };
struct WJobs { WJob j[14]; };
__global__ __launch_bounds__(256) void wconv_all(WJobs jobs, int ntiles) {
    int bid = blockIdx.x;
    if (bid >= ntiles) return;
    int ji = 0;
    #pragma unroll 1
    for (int i = 1; i < 14; ++i) if (bid >= jobs.j[i].t0) ji = i;
    const float* in = jobs.j[ji].src;
    u16* out = jobs.j[ji].dst;
    int K = jobs.j[ji].K, N = jobs.j[ji].N;
    int lt = bid - jobs.j[ji].t0;
    int ntx = N >> 5;
    int nb = (lt % ntx) * 32, kb = (lt / ntx) * 32;
    __shared__ float tile[32][33];
    int tx = threadIdx.x & 31, ty = threadIdx.x >> 5;
    #pragma unroll
    for (int r = ty; r < 32; r += 8)
        tile[r][tx] = in[(size_t)(kb + r) * N + nb + tx];
    __syncthreads();
    #pragma unroll
    for (int r = ty; r < 32; r += 8)
        out[(size_t)(nb + r) * K + kb + tx] = f2bf(tile[tx][r]);
}

// ============ MFMA GEMM v3 + XCD-band remap (kept for small M=1024 GEMMs) ===========
// DMA staging + 3-bit XOR chunk swizzle (r9: 0 bank conflicts); XCD remap (r10).
// EPI: 0 none, 1 relu, 2 +res f32, 3 +res bf16.
template<int TM, int TN, int EPI, int WF32, int WBF16>
__global__ __launch_bounds__(256) void gemm_bt(
    const u16* __restrict__ Ab, const u16* __restrict__ Btb,
    float* __restrict__ Cf, u16* __restrict__ Cb, const void* __restrict__ Rg,
    int K, int ldc)
{
    constexpr int WR = TM / 32, WC = TN / 32;
    constexpr int ITA = TM / 32, ITB = TN / 32;
    __shared__ __align__(16) u16 As[TM][64];
    __shared__ __align__(16) u16 Bs[TN][64];
    int tid = threadIdx.x;
    int lane = tid & 63, wave = tid >> 6;
    int quad = lane >> 4, l16 = lane & 15;
    int wm = (wave >> 1) * (TM / 2), wn = (wave & 1) * (TN / 2);

    int gx = gridDim.x, gy = gridDim.y;
    int bx, by;
    if ((gy & 7) == 0) {
        int id = blockIdx.y * gx + blockIdx.x;
        int xcd = id & 7;
        int slot = id >> 3;
        bx = slot % gx;
        by = xcd * (gy >> 3) + slot / gx;
    } else {
        bx = blockIdx.x;
        by = blockIdx.y;
    }
    size_t row0 = (size_t)by * TM;
    size_t col0 = (size_t)bx * TN;

    f32x4 acc[WR][WC];
    #pragma unroll
    for (int i = 0; i < WR; ++i)
        #pragma unroll
        for (int j = 0; j < WC; ++j)
            acc[i][j] = (f32x4){0.f, 0.f, 0.f, 0.f};

    int srow = lane >> 3;
    int c8 = (lane & 7) ^ srow;
    int h8 = l16 & 7;

    for (int k0 = 0; k0 < K; k0 += 64) {
        __syncthreads();
        #pragma unroll
        for (int it = 0; it < ITA; ++it) {
            int g = wave + it * 4;
            gload_lds(Ab + (row0 + g * 8 + srow) * (size_t)K + k0 + c8 * 8, &As[g * 8][0]);
        }
        #pragma unroll
        for (int it = 0; it < ITB; ++it) {
            int g = wave + it * 4;
            gload_lds(Btb + (col0 + g * 8 + srow) * (size_t)K + k0 + c8 * 8, &Bs[g * 8][0]);
        }
        __syncthreads();
        #pragma unroll
        for (int s = 0; s < 2; ++s) {
            int coff = ((s * 4 + quad) ^ h8) * 8;   // full 3-bit XOR (r9-verified)
            short8 af[WR], bf[WC];
            #pragma unroll
            for (int i = 0; i < WR; ++i)
                af[i] = *(short8*)&As[wm + i * 16 + l16][coff];
            #pragma unroll
            for (int j = 0; j < WC; ++j)
                bf[j] = *(short8*)&Bs[wn + j * 16 + l16][coff];
            #pragma unroll
            for (int i = 0; i < WR; ++i)
                #pragma unroll
                for (int j = 0; j < WC; ++j)
                    acc[i][j] = __builtin_amdgcn_mfma_f32_16x16x32_bf16(
                        af[i], bf[j], acc[i][j], 0, 0, 0);
        }
    }
    // C/D layout (on-target verified): col = lane&15, row = quad*4 + reg
    #pragma unroll
    for (int i = 0; i < WR; ++i)
        #pragma unroll
        for (int j = 0; j < WC; ++j)
            #pragma unroll
            for (int reg = 0; reg < 4; ++reg) {
                size_t row = row0 + wm + i * 16 + quad * 4 + reg;
                size_t col = col0 + wn + j * 16 + l16;
                float v = acc[i][j][reg];
                if (EPI == 2) v += ((const float*)Rg)[row * (size_t)ldc + col];
                if (EPI == 3) v += bfv(((const u16*)Rg)[row * (size_t)ldc + col]);
                if (EPI == 1) v = fmaxf(v, 0.f);
                if (WF32)  Cf[row * (size_t)ldc + col] = v;
                if (WBF16) Cb[row * (size_t)ldc + col] = f2bf(v);
            }
}

// ============ counted-pipeline GEMM: 128x128, BK=64, 2 barriers/tile (r4 best) ======
// Per K-tile: (1) issue 8 gload_lds for tile t+1 into the other LDS buffer FIRST;
// (2) s_waitcnt vmcnt(8) -- counted: the 8 just-issued loads stay IN FLIGHT, only
// tile t's loads (issued one full tile ago) must have landed; (3) one rendezvous
// s_barrier; (4) full 32-MFMA compute, setprio-wrapped, no intra-tile barriers;
// (5) one end barrier protecting the buffer restaged next iteration. vmcnt(0) only
// at the last tile. LDS 64KiB -> 2 blocks/CU. r9 XOR swizzle (0 conflicts).
// Requires M%128==0, N%128==0, K%64==0 (K>=128), gridDim.y%8==0 (XCD remap).
template<int EPI, int WF32, int WBF16>
__global__ __launch_bounds__(256, 2) void gemm_ct(
    const u16* __restrict__ Ab, const u16* __restrict__ Btb,
    float* __restrict__ Cf, u16* __restrict__ Cb, const void* __restrict__ Rg,
    int K, int ldc)
{
    __shared__ __align__(16) u16 As[2][128][64];
    __shared__ __align__(16) u16 Bs[2][128][64];
    int tid = threadIdx.x;
    int lane = tid & 63, wave = tid >> 6;       // 4 waves: 2M x 2N
    int quad = lane >> 4, l16 = lane & 15;
    int wm = (wave >> 1) * 64, wn = (wave & 1) * 64;

    int gx = gridDim.x, gy = gridDim.y;
    int id = blockIdx.y * gx + blockIdx.x;
    int xcd = id & 7, slot = id >> 3;
    int bx = slot % gx;
    int by = xcd * (gy >> 3) + slot / gx;
    size_t row0 = (size_t)by * 128;
    size_t col0 = (size_t)bx * 128;

    f32x4 acc[4][4];
    #pragma unroll
    for (int i = 0; i < 4; ++i)
        #pragma unroll
        for (int j = 0; j < 4; ++j)
            acc[i][j] = (f32x4){0.f, 0.f, 0.f, 0.f};

    // staging swizzle (r9-verified): physical 16B chunk p of row r holds logical
    // chunk p ^ (r&7)
    int srow = lane >> 3;
    int c8 = (lane & 7) ^ srow;
    int h8 = l16 & 7;
    size_t aoff[4], boff[4];
    #pragma unroll
    for (int it = 0; it < 4; ++it) {
        aoff[it] = (row0 + (size_t)(wave + it * 4) * 8 + srow) * (size_t)K + c8 * 8;
        boff[it] = (col0 + (size_t)(wave + it * 4) * 8 + srow) * (size_t)K + c8 * 8;
    }

    int nt = K >> 6;
    // prologue: stage tile 0 -> buf 0 (8 loads in flight, no wait)
    #pragma unroll
    for (int it = 0; it < 4; ++it)
        gload_lds(Ab + aoff[it], &As[0][(wave + it * 4) * 8][0]);
    #pragma unroll
    for (int it = 0; it < 4; ++it)
        gload_lds(Btb + boff[it], &Bs[0][(wave + it * 4) * 8][0]);

    #pragma unroll 1
    for (int t = 0; t < nt; ++t) {
        int cur = t & 1;
        if (t + 1 < nt) {
            // stage tile t+1 into other buffer (freed by iter t-1's end barrier)
            size_t ko = (size_t)(t + 1) * 64;
            #pragma unroll
            for (int it = 0; it < 4; ++it)
                gload_lds(Ab + aoff[it] + ko, &As[cur ^ 1][(wave + it * 4) * 8][0]);
            #pragma unroll
            for (int it = 0; it < 4; ++it)
                gload_lds(Btb + boff[it] + ko, &Bs[cur ^ 1][(wave + it * 4) * 8][0]);
            __builtin_amdgcn_sched_barrier(0);
            asm volatile("s_waitcnt vmcnt(8)" ::: "memory");   // tile t landed; t+1 in flight
        } else {
            __builtin_amdgcn_sched_barrier(0);
            asm volatile("s_waitcnt vmcnt(0)" ::: "memory");   // final tile only
        }
        __builtin_amdgcn_sched_barrier(0);
        __builtin_amdgcn_s_barrier();                          // rendezvous: tile t staged
        __builtin_amdgcn_sched_barrier(0);
        __builtin_amdgcn_s_setprio(1);
        #pragma unroll
        for (int kh = 0; kh < 2; ++kh) {
            int coff = ((kh * 4 + quad) ^ h8) * 8;
            short8 af[4], bf[4];
            #pragma unroll
            for (int j = 0; j < 4; ++j)
                bf[j] = *(short8*)&Bs[cur][wn + j * 16 + l16][coff];
            #pragma unroll
            for (int i = 0; i < 4; ++i)
                af[i] = *(short8*)&As[cur][wm + i * 16 + l16][coff];
            #pragma unroll
            for (int i = 0; i < 4; ++i)
                #pragma unroll
                for (int j = 0; j < 4; ++j)
                    acc[i][j] = __builtin_amdgcn_mfma_f32_16x16x32_bf16(
                        af[i], bf[j], acc[i][j], 0, 0, 0);
        }
        __builtin_amdgcn_s_setprio(0);
        __builtin_amdgcn_sched_barrier(0);                     // reads done before barrier
        __builtin_amdgcn_s_barrier();                          // frees buf[cur] for restage
    }

    // C/D layout (on-target verified): col = lane&15, row = quad*4 + reg
    #pragma unroll
    for (int i = 0; i < 4; ++i)
        #pragma unroll
        for (int j = 0; j < 4; ++j)
            #pragma unroll
            for (int reg = 0; reg < 4; ++reg) {
                size_t row = row0 + wm + i * 16 + quad * 4 + reg;
                size_t col = col0 + wn + j * 16 + l16;
                float v = acc[i][j][reg];
                if (EPI == 2) v += ((const float*)Rg)[row * (size_t)ldc + col];
                if (EPI == 3) v += bfv(((const u16*)Rg)[row * (size_t)ldc + col]);
                if (EPI == 1) v = fmaxf(v, 0.f);
                if (WF32)  Cf[row * (size_t)ldc + col] = v;
                if (WBF16) Cb[row * (size_t)ldc + col] = f2bf(v);
            }
}

// ============ fused attention per (b,m): all-heads phases, 3 barriers ===============
// r7: QK^T via MFMA 16x16x32 (verified layout: A row=l16 k=quad*8+j, B col=l16,
// D row=quad*4+reg col=l16). 4 waves x 2 heads; S stays f32 (softmax numerics
// unchanged). Softmax / atomicAdd / ctx phases identical to r6.
template<int CTX, int LD>
__global__ __launch_bounds__(256) void attn_fused_kernel(
    const u16* __restrict__ QKVb, const float* __restrict__ maskf, int bm0,
    float* __restrict__ att_sum, u16* __restrict__ ctxb)
{
    __shared__ __align__(16) u16 sQ[16][520];
    __shared__ __align__(16) u16 sK[16][520];
    __shared__ __align__(16) u16 sV[CTX ? 16 : 1][520];
    __shared__ float s_p[H_][16][17];
    __shared__ float sMask[16];
    int bm_l = blockIdx.x;
    int tid = threadIdx.x;
    int t = tid >> 4, ch = (tid & 15) * 32;
    const u16* base = QKVb + ((size_t)bm_l * T_ + t) * LD;
    #pragma unroll
    for (int c = 0; c < 4; ++c) {
        *(uint4*)&sQ[t][ch + c * 8] = *(const uint4*)(base + ch + c * 8);
        *(uint4*)&sK[t][ch + c * 8] = *(const uint4*)(base + 512 + ch + c * 8);
        if (CTX) *(uint4*)&sV[t][ch + c * 8] = *(const uint4*)(base + 1024 + ch + c * 8);
    }
    if (tid < 16) sMask[tid] = maskf[(size_t)(bm0 + bm_l) * T_ + tid];
    __syncthreads();

    int b = (bm0 + bm_l) >> 5;                  // bm = b*NN + m
    int lane = tid & 63, wid = tid >> 6;
    int l16 = lane & 15, quad = lane >> 4;

    // QK^T: per wave heads {wid, wid+4}; S[q=quad*4+reg][kt=l16] = Q[q][:] . K[kt][:]
    #pragma unroll
    for (int hh = 0; hh < 2; ++hh) {
        int h = wid + hh * 4;
        short8 aq0 = *(const short8*)&sQ[l16][h * 64 + quad * 8];
        short8 aq1 = *(const short8*)&sQ[l16][h * 64 + 32 + quad * 8];
        short8 bk0 = *(const short8*)&sK[l16][h * 64 + quad * 8];
        short8 bk1 = *(const short8*)&sK[l16][h * 64 + 32 + quad * 8];
        f32x4 acc = (f32x4){0.f, 0.f, 0.f, 0.f};
        acc = __builtin_amdgcn_mfma_f32_16x16x32_bf16(aq0, bk0, acc, 0, 0, 0);
        acc = __builtin_amdgcn_mfma_f32_16x16x32_bf16(aq1, bk1, acc, 0, 0, 0);
        #pragma unroll
        for (int reg = 0; reg < 4; ++reg) {
            int q = quad * 4 + reg;
            float v = acc[reg] * 0.125f;
            if (sMask[q] == 0.0f) v = -1e9f;
            s_p[h][q][l16] = v;
        }
    }
    __syncthreads();
    if (tid < 128) {
        int h = tid >> 4, q = tid & 15;
        float mx = -3.4e38f;
        #pragma unroll
        for (int kk = 0; kk < 16; ++kk) mx = fmaxf(mx, s_p[h][q][kk]);
        float e[16], s = 0.f;
        #pragma unroll
        for (int kk = 0; kk < 16; ++kk) { e[kk] = expf(s_p[h][q][kk] - mx); s += e[kk]; }
        float inv = 1.0f / s;
        #pragma unroll
        for (int kk = 0; kk < 16; ++kk) s_p[h][q][kk] = e[kk] * inv;
    }
    __syncthreads();
    #pragma unroll
    for (int r = 0; r < 8; ++r) {
        int h = r;
        int q = (tid >> 4) & 15, k = tid & 15;
        atomicAdd(&att_sum[(((size_t)b * H_ + h) * T_ + q) * T_ + k], s_p[h][q][k]);
    }
    if (CTX) {
        // 4 consecutive cols (2 u32) per step: uint2 sV reads, uint2 ctxb writes
        #pragma unroll
        for (int rep = 0; rep < 8; ++rep) {
            int i2 = rep * 256 + tid;           // t*128 + cu, cu = uint2 col index
            int tt = i2 >> 7, cu = i2 & 127;
            int h = cu >> 4;                    // (cu*2)>>5; pair never crosses a head
            const float* pr = &s_p[h][tt][0];
            float a0 = 0.f, a1 = 0.f, a2 = 0.f, a3 = 0.f;
            #pragma unroll
            for (int kk = 0; kk < 16; ++kk) {
                uint2 vv = *((const uint2*)&sV[kk][0] + cu);
                float p = pr[kk];
                a0 += p * bfv((u16)(vv.x & 0xffff));
                a1 += p * bfv((u16)(vv.x >> 16));
                a2 += p * bfv((u16)(vv.y & 0xffff));
                a3 += p * bfv((u16)(vv.y >> 16));
            }
            uint2 o;
            o.x = (u32)f2bf(a0) | ((u32)f2bf(a1) << 16);
            o.y = (u32)f2bf(a2) | ((u32)f2bf(a3) << 16);
            *(uint2*)((u32*)(ctxb + ((size_t)bm_l * T_ + tt) * D_) + cu * 2) = o;
        }
    }
}

// ============ fused self-attention + combine + si, one block per (n,h) ==============
// r6: qk dot via float4 LDS reads (4x fewer LDS ops, identical FMA order).
__global__ __launch_bounds__(256) void siatt_kernel(
    const float* __restrict__ xemb, const float* __restrict__ att_sum,
    const float* __restrict__ attf, u16* __restrict__ sib)
{
    __shared__ float sX[16][516];
    __shared__ float sS[16][17];
    __shared__ float sA[16][17];
    int n = blockIdx.x >> 3, h = blockIdx.x & 7;
    int tid = threadIdx.x;
    int t = tid >> 4, ch = (tid & 15) * 32;
    const float* src = xemb + ((size_t)n * T_ + t) * D_;
    #pragma unroll
    for (int c = 0; c < 8; ++c)
        *(float4*)&sX[t][ch + c * 4] = *(const float4*)(src + ch + c * 4);
    __syncthreads();
    int q = tid >> 4, k = tid & 15;
    {
        // row stride 516 f32 = 2064B (16B aligned); same accumulation order
        float acc = 0.f;
        for (int d4 = 0; d4 < D_ / 4; ++d4) {
            float4 xq = *(const float4*)&sX[q][d4 * 4];
            float4 xk = *(const float4*)&sX[k][d4 * 4];
            acc += xq.x * xk.x;
            acc += xq.y * xk.y;
            acc += xq.z * xk.z;
            acc += xq.w * xk.w;
        }
        sS[q][k] = acc * 0.04419417382415922f;
    }
    __syncthreads();
    if (tid < T_) {
        float mx = -3.4e38f;
        #pragma unroll
        for (int kk = 0; kk < 16; ++kk) mx = fmaxf(mx, sS[tid][kk]);
        float e[16], s = 0.f;
        #pragma unroll
        for (int kk = 0; kk < 16; ++kk) { e[kk] = expf(sS[tid][kk] - mx); s += e[kk]; }
        float inv = 1.0f / s;
        #pragma unroll
        for (int kk = 0; kk < 16; ++kk) sS[tid][kk] = e[kk] * inv;
    }
    __syncthreads();
    float f = attf[0] * (1.0f / 32.0f);
    sA[q][k] = sS[q][k] + f * att_sum[((size_t)n * H_ + h) * 256 + q * 16 + k];
    __syncthreads();
    #pragma unroll
    for (int rep = 0; rep < 16; ++rep) {
        int i2 = rep * 256 + tid;          // q*256 + d2
        int qq = i2 >> 8, d2 = (i2 & 255) * 2;
        const float* ar = &sA[qq][0];
        float a0 = 0.f, a1 = 0.f;
        #pragma unroll
        for (int tt = 0; tt < 16; ++tt) {
            float p = ar[tt];
            a0 += p * sX[tt][d2];
            a1 += p * sX[tt][d2 + 1];
        }
        u32 o = (u32)f2bf(a0) | ((u32)f2bf(a1) << 16);
        *((u32*)(sib + (size_t)n * T_ * 4096 + (size_t)qq * 4096 + h * 512) + (d2 >> 1)) = o;
    }
}

// ---------------- positional encoding ------------------------------------------------
__global__ void pe_kernel(float* pe) {
    int i = blockIdx.x * blockDim.x + threadIdx.x;
    if (i >= T_ * 256) return;
    int t = i >> 8, j = i & 255;
    float dv = (float)pow(10000.0, (double)j / 256.0);
    float a = (float)t * dv;
    double ad = (double)a;
    pe[t * D_ + 2 * j]     = (float)sin(ad);
    pe[t * D_ + 2 * j + 1] = (float)cos(ad);
}

// ---------------- x features + embed -------------------------------------------------
__global__ void xemb_kernel(const float* x, const float* Wx, const float* bx,
                            const float* pe, float* xemb) {
    int row = blockIdx.x;              // t*N + n
    int t = row / N_, n = row % N_;
    float x0 = x[row * 6 + 0], x1 = x[row * 6 + 1];
    float x2 = x[row * 6 + 2], x3 = x[row * 6 + 3];
    float x4 = x[row * 6 + 4], x5 = x[row * 6 + 5];
    float vel = sqrtf(x2 * x2 + x3 * x3);
    float ang = atanf(x5 / x4);
    float f0 = ntn(x0), f1 = ntn(x1), f2 = ntn(vel), f3 = ntn(ang);
    for (int d = threadIdx.x; d < D_; d += blockDim.x) {
        xemb[((size_t)n * T_ + t) * D_ + d] =
            f0 * Wx[0 * D_ + d] + f1 * Wx[1 * D_ + d]
          + f2 * Wx[2 * D_ + d] + f3 * Wx[3 * D_ + d]
          + bx[d] + pe[t * D_ + d];
    }
}

// ---------------- neighbor features + mask -------------------------------------------
__global__ void nbr_kernel(const float* x, const float* nbr, float* nf, float* maskf) {
    int idx = blockIdx.x * blockDim.x + threadIdx.x;   // t*N*NN + n*NN + m
    if (idx >= T_ * N_ * NN_) return;
    int m = idx % NN_;
    int tn = idx / NN_;
    int n = tn % N_, t = tn / N_;
    float px = x[((size_t)t * N_ + n) * 6 + 0];
    float py = x[((size_t)t * N_ + n) * 6 + 1];
    float vx, vy;
    if (t == 0) {
        vx = x[((size_t)1 * N_ + n) * 6 + 2];
        vy = x[((size_t)1 * N_ + n) * 6 + 3];
    } else {
        vx = px - x[((size_t)(t - 1) * N_ + n) * 6 + 0];
        vy = py - x[((size_t)(t - 1) * N_ + n) * 6 + 1];
    }
    float nx  = nbr[(size_t)idx * 4 + 0], ny  = nbr[(size_t)idx * 4 + 1];
    float nvx = nbr[(size_t)idx * 4 + 2], nvy = nbr[(size_t)idx * 4 + 3];
    float dpx = nx - px, dpy = ny - py;
    float dvx = nvx - vx, dvy = nvy - vy;
    float dist = sqrtf(dpx * dpx + dpy * dpy);
    maskf[((size_t)n * NN_ + m) * T_ + t] = (dist <= 2.0f) ? 1.0f : 0.0f;
    float vn = sqrtf(vx * vx + vy * vy);
    float bearing = (dpx * vx + dpy * vy) / (dist * vn);
    if (isnan(bearing)) bearing = 0.0f;
    float dvn = sqrtf(dvx * dvx + dvy * dvy);
    float tau = -(dpx * dvx + dpy * dvy) / dvn;
    if (isnan(tau)) tau = 0.0f;
    tau = fminf(fmaxf(tau, 0.0f), 7.0f);
    float mx_ = dpx + tau * dvx, my_ = dpy + tau * dvy;
    float mpd = sqrtf(mx_ * mx_ + my_ * my_);
    nf[(size_t)idx * 3 + 0] = ntn(dist);
    nf[(size_t)idx * 3 + 1] = ntn(bearing);
    nf[(size_t)idx * 3 + 2] = ntn(mpd);
}

// ---------------- neighbor embed: bf16 n_emb only ------------------------------------
__global__ void nemb_kernel(const float* nf, const float* Wn, const float* bn,
                            const float* pe, u16* Ab) {
    int row = blockIdx.x;              // (b*NN+m)*T + t
    int t = row % T_;
    int bm = row / T_;
    int m = bm % NN_, b = bm / NN_;
    size_t nfrow = (((size_t)t * N_ + b) * NN_ + m) * 3;
    float f0 = nf[nfrow], f1 = nf[nfrow + 1], f2 = nf[nfrow + 2];
    for (int d = threadIdx.x; d < D_; d += blockDim.x) {
        float v = f0 * Wn[d] + f1 * Wn[D_ + d] + f2 * Wn[2 * D_ + d]
                + bn[d] + pe[t * D_ + d];
        Ab[(size_t)row * D_ + d] = f2bf(v);
    }
}

// ---------------- LayerNorm, one wave per row; input f32 or bf16; dual out -----------
// r6: vectorized -- lane owns 8 CONTIGUOUS elements (short8 / 2x float4 loads,
// packed stores). Reduction set identical (order perturbation ~1e-6, tol 1.6e-2).
template<int INBF>
__global__ __launch_bounds__(256) void ln_kernel(
    const void* X, const float* g, const float* b, float* outF, u16* outB, int nrows) {
    int row = blockIdx.x * 4 + (threadIdx.x >> 6);
    if (row >= nrows) return;
    int lane = threadIdx.x & 63;
    int d0 = lane * 8;
    float v[8];
    if (INBF) {
        short8 x8 = *(const short8*)((const u16*)X + (size_t)row * D_ + d0);
        #pragma unroll
        for (int r = 0; r < 8; ++r) v[r] = bfv((u16)x8[r]);
    } else {
        float4 a = *(const float4*)((const float*)X + (size_t)row * D_ + d0);
        float4 c = *(const float4*)((const float*)X + (size_t)row * D_ + d0 + 4);
        v[0] = a.x; v[1] = a.y; v[2] = a.z; v[3] = a.w;
        v[4] = c.x; v[5] = c.y; v[6] = c.z; v[7] = c.w;
    }
    float s = 0.f;
    #pragma unroll
    for (int r = 0; r < 8; ++r) s += v[r];
    s = wave_sum(s);
    float mean = s * (1.0f / 512.0f);
    float vs = 0.f;
    #pragma unroll
    for (int r = 0; r < 8; ++r) { float d = v[r] - mean; vs += d * d; }
    vs = wave_sum(vs);
    float rstd = rsqrtf(vs * (1.0f / 512.0f) + 1e-5f);
    float4 g0 = *(const float4*)&g[d0], g1 = *(const float4*)&g[d0 + 4];
    float4 b0 = *(const float4*)&b[d0], b1 = *(const float4*)&b[d0 + 4];
    float o[8];
    o[0] = (v[0] - mean) * rstd * g0.x + b0.x;
    o[1] = (v[1] - mean) * rstd * g0.y + b0.y;
    o[2] = (v[2] - mean) * rstd * g0.z + b0.z;
    o[3] = (v[3] - mean) * rstd * g0.w + b0.w;
    o[4] = (v[4] - mean) * rstd * g1.x + b1.x;
    o[5] = (v[5] - mean) * rstd * g1.y + b1.y;
    o[6] = (v[6] - mean) * rstd * g1.z + b1.z;
    o[7] = (v[7] - mean) * rstd * g1.w + b1.w;
    if (outF) {
        float4 w0 = {o[0], o[1], o[2], o[3]};
        float4 w1 = {o[4], o[5], o[6], o[7]};
        *(float4*)(outF + (size_t)row * D_ + d0) = w0;
        *(float4*)(outF + (size_t)row * D_ + d0 + 4) = w1;
    }
    if (outB) {
        short8 w;
        #pragma unroll
        for (int r = 0; r < 8; ++r) w[r] = (short)f2bf(o[r]);
        *(short8*)(outB + (size_t)row * D_ + d0) = w;
    }
}

// ---------------- prediction head + broadcast fused (f32 out) ------------------------
// r7: one thread per (n,t); float4 loads of xemb row and Wp; per-c accumulation
// order preserved (j ascending).
__global__ __launch_bounds__(256) void predbcast_kernel(
    const float* __restrict__ xemb, const float* __restrict__ Wp,
    const float* __restrict__ bp, float* __restrict__ out) {
    int nt = blockIdx.x * blockDim.x + threadIdx.x;    // n*T + t
    if (nt >= N_ * T_) return;
    int n = nt / T_, t = nt % T_;
    float a0 = bp[0], a1 = bp[1];
    const float* xr = xemb + (size_t)nt * D_;
    for (int j = 0; j < D_; j += 4) {
        float4 xv = *(const float4*)&xr[j];
        float4 w0 = *(const float4*)&Wp[(size_t)j * 2];      // W[j][0..1], W[j+1][0..1]
        float4 w1 = *(const float4*)&Wp[(size_t)j * 2 + 4];  // W[j+2][0..1], W[j+3][0..1]
        a0 += xv.x * w0.x; a1 += xv.x * w0.y;
        a0 += xv.y * w0.z; a1 += xv.y * w0.w;
        a0 += xv.z * w1.x; a1 += xv.z * w1.y;
        a0 += xv.w * w1.z; a1 += xv.w * w1.w;
    }
    #pragma unroll
    for (int p = 0; p < NPRED_; ++p) {
        size_t o = (((size_t)p * T_ + t) * N_ + n) * 2;
        out[o]     = a0;
        out[o + 1] = a1;
    }
}

extern "C" void kernel_launch(void* const* d_in, const int* in_sizes, int n_in,
                              void* d_out, int out_size, void* d_ws, size_t ws_size,
                              hipStream_t stream) {
    (void)in_sizes; (void)n_in; (void)out_size; (void)ws_size;

    const float* x    = (const float*)d_in[0];
    const float* nbr  = (const float*)d_in[1];
    const float* attf = (const float*)d_in[2];
    const float* Wx   = (const float*)d_in[3];
    const float* bx   = (const float*)d_in[4];
    const float* Wn   = (const float*)d_in[5];
    const float* bn   = (const float*)d_in[6];
    const float* Wp   = (const float*)d_in[7];
    const float* bp   = (const float*)d_in[8];
    const float* WQ   = (const float*)d_in[9];
    const float* WK   = (const float*)d_in[10];
    const float* WV   = (const float*)d_in[11];
    const float* Wfc  = (const float*)d_in[12];
    const float* mlng = (const float*)d_in[13];
    const float* mlnb = (const float*)d_in[14];
    const float* WSI  = (const float*)d_in[15];
    const float* fsw1 = (const float*)d_in[16];
    const float* fsw2 = (const float*)d_in[17];
    const float* fsg  = (const float*)d_in[18];
    const float* fsb  = (const float*)d_in[19];
    const float* fiw1 = (const float*)d_in[20];
    const float* fiw2 = (const float*)d_in[21];
    const float* fig  = (const float*)d_in[22];
    const float* fib  = (const float*)d_in[23];

    char* w = (char*)d_ws;
    size_t off = 0;
    auto alloc = [&](size_t bytes) -> void* {
        void* p = w + off;
        off = (off + bytes + 255) & ~(size_t)255;
        return p;
    };
    const size_t MiB = 1024 * 1024;

    const int BM = N_ * NN_;          // 2048 (b,m) pairs
    const int ROWS_I = BM * T_;       // 32768 neighbor rows
    const int CB = 1024;              // bm per chunk (NCH=2, l=0 only)
    const int RC = CB * T_;           // 16384 rows per chunk
    const int NCH = ROWS_I / RC;      // 2

    float* pe      = (float*)alloc((size_t)T_ * D_ * 4);
    float* xemb    = (float*)alloc((size_t)N_ * T_ * D_ * 4);
    float* nf      = (float*)alloc((size_t)T_ * N_ * NN_ * 3 * 4);
    float* maskf   = (float*)alloc((size_t)BM * T_ * 4);
    u16*   Ab      = (u16*)alloc((size_t)ROWS_I * D_ * 2);     // n_emb bf16  32 MiB
    u16* tQKV[2], *tWSI[2], *tfs1[2], *tfs2[2];
    for (int l = 0; l < 2; ++l) {
        tQKV[l] = (u16*)alloc((size_t)1536 * 512 * 2);
        tWSI[l] = (u16*)alloc((size_t)512 * 4096 * 2);
        tfs1[l] = (u16*)alloc((size_t)2048 * 512 * 2);
        tfs2[l] = (u16*)alloc((size_t)512 * 2048 * 2);
    }
    u16* tWfc = (u16*)alloc((size_t)512 * 512 * 2);
    u16* tfi1 = (u16*)alloc((size_t)2048 * 512 * 2);
    u16* tfi2 = (u16*)alloc((size_t)512 * 2048 * 2);
    // scratch union: l0 chunk: QKVb 48 + ctxb 16 | hid 64 ; l1: QK full 64 MiB
    char* SCR  = (char*)alloc(64 * MiB);
    u16*   QKVb = (u16*)SCR;
    u16*   ctxb = (u16*)(SCR + 48 * MiB);
    u16*   hid  = (u16*)SCR;
    u16*   BbA    = (u16*)alloc((size_t)RC * D_ * 2);  // pre-LN bf16 chunk    16 MiB
    u16*   Bb_res = (u16*)alloc((size_t)RC * D_ * 2);  // res_inter bf16       16 MiB
    float* att_sum = (float*)alloc((size_t)N_ * H_ * 256 * 4);
    u16*   sib     = (u16*)alloc((size_t)N_ * T_ * 4096 * 2);  // 8 MiB
    float* xnew    = (float*)alloc((size_t)N_ * T_ * D_ * 4);
    u16*   xnb     = (u16*)alloc((size_t)N_ * T_ * D_ * 2);
    // total ~170 MiB

    // ---- batched weight conversion: 14 jobs, one launch ----
    WJobs jobs;
    int ntiles = 0;
    auto addJob = [&](int idx, const float* src, u16* dst, int K, int N) {
        jobs.j[idx] = {src, dst, K, N, ntiles};
        ntiles += (N >> 5) * (K >> 5);
    };
    addJob(0,  WQ,                            tQKV[0],              512, 512);
    addJob(1,  WK,                            tQKV[0] + 512 * 512,  512, 512);
    addJob(2,  WV,                            tQKV[0] + 1024 * 512, 512, 512);   // dead at l=1
    addJob(3,  WQ + (size_t)512 * 512,        tQKV[1],              512, 512);
    addJob(4,  WK + (size_t)512 * 512,        tQKV[1] + 512 * 512,  512, 512);
    addJob(5,  Wfc,                           tWfc,                 512, 512);
    addJob(6,  WSI,                           tWSI[0],              4096, 512);
    addJob(7,  WSI + (size_t)4096 * 512,      tWSI[1],              4096, 512);
    addJob(8,  fsw1,                          tfs1[0],              512, 2048);
    addJob(9,  fsw1 + (size_t)512 * 2048,     tfs1[1],              512, 2048);
    addJob(10, fsw2,                          tfs2[0],              2048, 512);
    addJob(11, fsw2 + (size_t)2048 * 512,     tfs2[1],              2048, 512);
    addJob(12, fiw1,                          tfi1,                 512, 2048);
    addJob(13, fiw2,                          tfi2,                 2048, 512);
    wconv_all<<<ntiles, 256, 0, stream>>>(jobs, ntiles);

    pe_kernel<<<16, 256, 0, stream>>>(pe);
    xemb_kernel<<<T_ * N_, 256, 0, stream>>>(x, Wx, bx, pe, xemb);
    nbr_kernel<<<(T_ * N_ * NN_ + 255) / 256, 256, 0, stream>>>(x, nbr, nf, maskf);
    nemb_kernel<<<BM * T_, 256, 0, stream>>>(nf, Wn, bn, pe, Ab);

    for (int l = 0; l < L_; ++l) {
        hipMemsetAsync(att_sum, 0, (size_t)N_ * H_ * 256 * 4, stream);
        if (l == 0) {
            for (int c = 0; c < NCH; ++c) {
                u16* Acb = Ab + (size_t)c * RC * D_;
                // QKV fused GEMM: N=1536 (1536 blocks = 3 exact rounds @2/CU)
                gemm_ct<0, 0, 1><<<dim3(12, RC / 128), 256, 0, stream>>>(
                    Acb, tQKV[0], nullptr, QKVb, nullptr, 512, 1536);
                attn_fused_kernel<1, 1536><<<CB, 256, 0, stream>>>(
                    QKVb, maskf, c * CB, att_sum, ctxb);
                // fc + residual(n_emb bf16) -> pre-LN bf16 (512 blocks = 1 round)
                gemm_ct<3, 0, 1><<<dim3(4, RC / 128), 256, 0, stream>>>(
                    ctxb, tWfc, nullptr, BbA, Acb, 512, 512);
                ln_kernel<1><<<RC / 4, 256, 0, stream>>>(
                    BbA, mlng, mlnb, nullptr, Bb_res, RC);   // res_inter bf16
                // ffi1 relu: N=2048 (2048 blocks = 4 exact rounds)
                gemm_ct<1, 0, 1><<<dim3(16, RC / 128), 256, 0, stream>>>(
                    Bb_res, tfi1, nullptr, hid, nullptr, 512, 2048);
                // ffi2 + residual(res_inter bf16) -> pre-LN bf16 (512 blocks)
                gemm_ct<3, 0, 1><<<dim3(4, RC / 128), 256, 0, stream>>>(
                    hid, tfi2, nullptr, BbA, Bb_res, 2048, 512);
                ln_kernel<1><<<RC / 4, 256, 0, stream>>>(
                    BbA, fig, fib, nullptr, Acb, RC);        // new n_emb (bf16)
            }
        } else {
            // l=1: unchunked QK (N=1024, ldc=1024; 64 MiB = SCR): 2048 blocks
            gemm_ct<0, 0, 1><<<dim3(8, ROWS_I / 128), 256, 0, stream>>>(
                Ab, tQKV[1], nullptr, QKVb, nullptr, 512, 1024);
            attn_fused_kernel<0, 1024><<<BM, 256, 0, stream>>>(
                QKVb, maskf, 0, att_sum, nullptr);
        }

        // ---- self-attention + si + ffs (updates xemb; f32 chain unchanged) ----
        siatt_kernel<<<N_ * H_, 256, 0, stream>>>(xemb, att_sum, attf, sib);
        gemm_bt<32, 64, 0, 1, 1><<<dim3(8, 32), 256, 0, stream>>>(
            sib, tWSI[l], xnew, xnb, nullptr, 4096, 512);
        gemm_bt<32, 64, 1, 0, 1><<<dim3(32, 32), 256, 0, stream>>>(
            xnb, tfs1[l], nullptr, hid, nullptr, 512, 2048);
        gemm_bt<32, 64, 2, 1, 0><<<dim3(8, 32), 256, 0, stream>>>(
            hid, tfs2[l], xemb, nullptr, xnew, 2048, 512);
        ln_kernel<0><<<(N_ * T_) / 4, 256, 0, stream>>>(
            xemb, fsg + l * D_, fsb + l * D_, xemb, nullptr, N_ * T_);
    }

    predbcast_kernel<<<(N_ * T_ + 255) / 256, 256, 0, stream>>>(
        xemb, Wp, bp, (float*)d_out);
}

// Round 8
// 755.664 us; speedup vs baseline: 1.1308x; 1.0168x over previous
//
#include <hip/hip_runtime.h>
#include <math.h>

// DTYPE COMMITMENTS (evidence-backed): inputs f32, output f32 (rounds 4-14 PASS).
// WS BUDGET: <= ~210 MB decimal; this build ~170 MiB (+0: partials alias SCR).
// r8: ffs chain (WSI/fs1/fs2, M=1024) moved from gemm_bt<32,64> (64 serial K-steps
// behind full drains, 1 blk/CU) to split-K gemm_ks (gemm_ct schedule + blockIdx.z
// K-partition, f32 partials, no atomics) + vectorized ksum epilogue. Pure f32
// reassociation -> numerics unchanged. Everything else frozen at the 768us state.

#define T_ 16
#define N_ 64
#define NN_ 32
#define D_ 512
#define H_ 8
#define DK_ 64
#define DFF_ 2048
#define L_ 2
#define NPRED_ 20

typedef unsigned short u16;
typedef unsigned int u32;
typedef __attribute__((ext_vector_type(8))) short short8;
typedef __attribute__((ext_vector_type(4))) float f32x4;

__device__ __forceinline__ u16 f2bf(float f) {
    u32 u = __float_as_uint(f);
    u32 r = u + 0x7fffu + ((u >> 16) & 1u);
    return (u16)(r >> 16);
}
__device__ __forceinline__ float bfv(u16 v) {
    return __uint_as_float(((u32)v) << 16);
}
__device__ __forceinline__ float ntn(float v) {
    if (isnan(v)) return 0.0f;
    if (isinf(v)) return v > 0.0f ? 3.4028234663852886e38f : -3.4028234663852886e38f;
    return v;
}
__device__ __forceinline__ float wave_sum(float v) {
    #pragma unroll
    for (int o = 32; o > 0; o >>= 1) v += __shfl_xor(v, o, 64);
    return v;
}
// async 16B HBM->LDS: writes ldsbase + lane*16 (wave-uniform base, per-lane gptr)
__device__ __forceinline__ void gload_lds(const u16* g, u16* l) {
    __builtin_amdgcn_global_load_lds(
        (const __attribute__((address_space(1))) u32*)g,
        (__attribute__((address_space(3))) u32*)l, 16, 0, 0);
}

// ============ batched weight convert+transpose: 14 jobs in ONE launch ===============
struct WJob { const float* src; u16* dst; int K; int N; int t0; };
struct WJobs { WJob j[14]; };
__global__ __launch_bounds__(256) void wconv_all(WJobs jobs, int ntiles) {
    int bid = blockIdx.x;
    if (bid >= ntiles) return;
    int ji = 0;
    #pragma unroll 1
    for (int i = 1; i < 14; ++i) if (bid >= jobs.j[i].t0) ji = i;
    const float* in = jobs.j[ji].src;
    u16* out = jobs.j[ji].dst;
    int K = jobs.j[ji].K, N = jobs.j[ji].N;
    int lt = bid - jobs.j[ji].t0;
    int ntx = N >> 5;
    int nb = (lt % ntx) * 32, kb = (lt / ntx) * 32;
    __shared__ float tile[32][33];
    int tx = threadIdx.x & 31, ty = threadIdx.x >> 5;
    #pragma unroll
    for (int r = ty; r < 32; r += 8)
        tile[r][tx] = in[(size_t)(kb + r) * N + nb + tx];
    __syncthreads();
    #pragma unroll
    for (int r = ty; r < 32; r += 8)
        out[(size_t)(nb + r) * K + kb + tx] = f2bf(tile[tx][r]);
}

// ============ counted-pipeline GEMM: 128x128, BK=64, 2 barriers/tile (r4 best) ======
// Per K-tile: (1) issue 8 gload_lds for tile t+1 into the other LDS buffer FIRST;
// (2) s_waitcnt vmcnt(8) -- counted: the 8 just-issued loads stay IN FLIGHT, only
// tile t's loads (issued one full tile ago) must have landed; (3) one rendezvous
// s_barrier; (4) full 32-MFMA compute, setprio-wrapped, no intra-tile barriers;
// (5) one end barrier protecting the buffer restaged next iteration. vmcnt(0) only
// at the last tile. LDS 64KiB -> 2 blocks/CU. r9 XOR swizzle (0 conflicts).
// Requires M%128==0, N%128==0, K%64==0 (K>=128), gridDim.y%8==0 (XCD remap).
template<int EPI, int WF32, int WBF16>
__global__ __launch_bounds__(256, 2) void gemm_ct(
    const u16* __restrict__ Ab, const u16* __restrict__ Btb,
    float* __restrict__ Cf, u16* __restrict__ Cb, const void* __restrict__ Rg,
    int K, int ldc)
{
    __shared__ __align__(16) u16 As[2][128][64];
    __shared__ __align__(16) u16 Bs[2][128][64];
    int tid = threadIdx.x;
    int lane = tid & 63, wave = tid >> 6;       // 4 waves: 2M x 2N
    int quad = lane >> 4, l16 = lane & 15;
    int wm = (wave >> 1) * 64, wn = (wave & 1) * 64;

    int gx = gridDim.x, gy = gridDim.y;
    int id = blockIdx.y * gx + blockIdx.x;
    int xcd = id & 7, slot = id >> 3;
    int bx = slot % gx;
    int by = xcd * (gy >> 3) + slot / gx;
    size_t row0 = (size_t)by * 128;
    size_t col0 = (size_t)bx * 128;

    f32x4 acc[4][4];
    #pragma unroll
    for (int i = 0; i < 4; ++i)
        #pragma unroll
        for (int j = 0; j < 4; ++j)
            acc[i][j] = (f32x4){0.f, 0.f, 0.f, 0.f};

    // staging swizzle (r9-verified): physical 16B chunk p of row r holds logical
    // chunk p ^ (r&7)
    int srow = lane >> 3;
    int c8 = (lane & 7) ^ srow;
    int h8 = l16 & 7;
    size_t aoff[4], boff[4];
    #pragma unroll
    for (int it = 0; it < 4; ++it) {
        aoff[it] = (row0 + (size_t)(wave + it * 4) * 8 + srow) * (size_t)K + c8 * 8;
        boff[it] = (col0 + (size_t)(wave + it * 4) * 8 + srow) * (size_t)K + c8 * 8;
    }

    int nt = K >> 6;
    // prologue: stage tile 0 -> buf 0 (8 loads in flight, no wait)
    #pragma unroll
    for (int it = 0; it < 4; ++it)
        gload_lds(Ab + aoff[it], &As[0][(wave + it * 4) * 8][0]);
    #pragma unroll
    for (int it = 0; it < 4; ++it)
        gload_lds(Btb + boff[it], &Bs[0][(wave + it * 4) * 8][0]);

    #pragma unroll 1
    for (int t = 0; t < nt; ++t) {
        int cur = t & 1;
        if (t + 1 < nt) {
            // stage tile t+1 into other buffer (freed by iter t-1's end barrier)
            size_t ko = (size_t)(t + 1) * 64;
            #pragma unroll
            for (int it = 0; it < 4; ++it)
                gload_lds(Ab + aoff[it] + ko, &As[cur ^ 1][(wave + it * 4) * 8][0]);
            #pragma unroll
            for (int it = 0; it < 4; ++it)
                gload_lds(Btb + boff[it] + ko, &Bs[cur ^ 1][(wave + it * 4) * 8][0]);
            __builtin_amdgcn_sched_barrier(0);
            asm volatile("s_waitcnt vmcnt(8)" ::: "memory");   // tile t landed; t+1 in flight
        } else {
            __builtin_amdgcn_sched_barrier(0);
            asm volatile("s_waitcnt vmcnt(0)" ::: "memory");   // final tile only
        }
        __builtin_amdgcn_sched_barrier(0);
        __builtin_amdgcn_s_barrier();                          // rendezvous: tile t staged
        __builtin_amdgcn_sched_barrier(0);
        __builtin_amdgcn_s_setprio(1);
        #pragma unroll
        for (int kh = 0; kh < 2; ++kh) {
            int coff = ((kh * 4 + quad) ^ h8) * 8;
            short8 af[4], bf[4];
            #pragma unroll
            for (int j = 0; j < 4; ++j)
                bf[j] = *(short8*)&Bs[cur][wn + j * 16 + l16][coff];
            #pragma unroll
            for (int i = 0; i < 4; ++i)
                af[i] = *(short8*)&As[cur][wm + i * 16 + l16][coff];
            #pragma unroll
            for (int i = 0; i < 4; ++i)
                #pragma unroll
                for (int j = 0; j < 4; ++j)
                    acc[i][j] = __builtin_amdgcn_mfma_f32_16x16x32_bf16(
                        af[i], bf[j], acc[i][j], 0, 0, 0);
        }
        __builtin_amdgcn_s_setprio(0);
        __builtin_amdgcn_sched_barrier(0);                     // reads done before barrier
        __builtin_amdgcn_s_barrier();                          // frees buf[cur] for restage
    }

    // C/D layout (on-target verified): col = lane&15, row = quad*4 + reg
    #pragma unroll
    for (int i = 0; i < 4; ++i)
        #pragma unroll
        for (int j = 0; j < 4; ++j)
            #pragma unroll
            for (int reg = 0; reg < 4; ++reg) {
                size_t row = row0 + wm + i * 16 + quad * 4 + reg;
                size_t col = col0 + wn + j * 16 + l16;
                float v = acc[i][j][reg];
                if (EPI == 2) v += ((const float*)Rg)[row * (size_t)ldc + col];
                if (EPI == 3) v += bfv(((const u16*)Rg)[row * (size_t)ldc + col]);
                if (EPI == 1) v = fmaxf(v, 0.f);
                if (WF32)  Cf[row * (size_t)ldc + col] = v;
                if (WBF16) Cb[row * (size_t)ldc + col] = f2bf(v);
            }
}

// ============ split-K GEMM for small-M (ffs chain): gemm_ct schedule + z-split ======
// grid (N/128, M/128=8, NS); block z computes K-range [z*Kc,(z+1)*Kc), Kc=K/NS
// (Kc%64==0, Kc>=128), writes f32 partial to Pf + z*M*ldc. No atomics; ksum_kernel
// reduces. Identical pipeline/swizzle to gemm_ct (refcheck'd r4-r7).
template<int NS>
__global__ __launch_bounds__(256, 2) void gemm_ks(
    const u16* __restrict__ Ab, const u16* __restrict__ Btb,
    float* __restrict__ Pf, int K, int ldc)
{
    __shared__ __align__(16) u16 As[2][128][64];
    __shared__ __align__(16) u16 Bs[2][128][64];
    int tid = threadIdx.x;
    int lane = tid & 63, wave = tid >> 6;
    int quad = lane >> 4, l16 = lane & 15;
    int wm = (wave >> 1) * 64, wn = (wave & 1) * 64;

    int gx = gridDim.x, gy = gridDim.y;
    int id = blockIdx.y * gx + blockIdx.x;
    int xcd = id & 7, slot = id >> 3;
    int bx = slot % gx;
    int by = xcd * (gy >> 3) + slot / gx;
    int z = blockIdx.z;
    int Kc = K / NS;
    size_t row0 = (size_t)by * 128;
    size_t col0 = (size_t)bx * 128;
    size_t M = (size_t)gy * 128;

    f32x4 acc[4][4];
    #pragma unroll
    for (int i = 0; i < 4; ++i)
        #pragma unroll
        for (int j = 0; j < 4; ++j)
            acc[i][j] = (f32x4){0.f, 0.f, 0.f, 0.f};

    int srow = lane >> 3;
    int c8 = (lane & 7) ^ srow;
    int h8 = l16 & 7;
    size_t kbase = (size_t)z * Kc;
    size_t aoff[4], boff[4];
    #pragma unroll
    for (int it = 0; it < 4; ++it) {
        aoff[it] = (row0 + (size_t)(wave + it * 4) * 8 + srow) * (size_t)K + kbase + c8 * 8;
        boff[it] = (col0 + (size_t)(wave + it * 4) * 8 + srow) * (size_t)K + kbase + c8 * 8;
    }

    int nt = Kc >> 6;
    #pragma unroll
    for (int it = 0; it < 4; ++it)
        gload_lds(Ab + aoff[it], &As[0][(wave + it * 4) * 8][0]);
    #pragma unroll
    for (int it = 0; it < 4; ++it)
        gload_lds(Btb + boff[it], &Bs[0][(wave + it * 4) * 8][0]);

    #pragma unroll 1
    for (int t = 0; t < nt; ++t) {
        int cur = t & 1;
        if (t + 1 < nt) {
            size_t ko = (size_t)(t + 1) * 64;
            #pragma unroll
            for (int it = 0; it < 4; ++it)
                gload_lds(Ab + aoff[it] + ko, &As[cur ^ 1][(wave + it * 4) * 8][0]);
            #pragma unroll
            for (int it = 0; it < 4; ++it)
                gload_lds(Btb + boff[it] + ko, &Bs[cur ^ 1][(wave + it * 4) * 8][0]);
            __builtin_amdgcn_sched_barrier(0);
            asm volatile("s_waitcnt vmcnt(8)" ::: "memory");
        } else {
            __builtin_amdgcn_sched_barrier(0);
            asm volatile("s_waitcnt vmcnt(0)" ::: "memory");
        }
        __builtin_amdgcn_sched_barrier(0);
        __builtin_amdgcn_s_barrier();
        __builtin_amdgcn_sched_barrier(0);
        __builtin_amdgcn_s_setprio(1);
        #pragma unroll
        for (int kh = 0; kh < 2; ++kh) {
            int coff = ((kh * 4 + quad) ^ h8) * 8;
            short8 af[4], bf[4];
            #pragma unroll
            for (int j = 0; j < 4; ++j)
                bf[j] = *(short8*)&Bs[cur][wn + j * 16 + l16][coff];
            #pragma unroll
            for (int i = 0; i < 4; ++i)
                af[i] = *(short8*)&As[cur][wm + i * 16 + l16][coff];
            #pragma unroll
            for (int i = 0; i < 4; ++i)
                #pragma unroll
                for (int j = 0; j < 4; ++j)
                    acc[i][j] = __builtin_amdgcn_mfma_f32_16x16x32_bf16(
                        af[i], bf[j], acc[i][j], 0, 0, 0);
        }
        __builtin_amdgcn_s_setprio(0);
        __builtin_amdgcn_sched_barrier(0);
        __builtin_amdgcn_s_barrier();
    }

    float* P = Pf + (size_t)z * M * (size_t)ldc;
    #pragma unroll
    for (int i = 0; i < 4; ++i)
        #pragma unroll
        for (int j = 0; j < 4; ++j)
            #pragma unroll
            for (int reg = 0; reg < 4; ++reg) {
                size_t row = row0 + wm + i * 16 + quad * 4 + reg;
                size_t col = col0 + wn + j * 16 + l16;
                P[row * (size_t)ldc + col] = acc[i][j][reg];
            }
}

// ---- split-K reduce + epilogue: sum NS f32 partials; EPI 1=relu 2=+res; dual out --
template<int NS, int EPI, int WF32, int WBF16>
__global__ __launch_bounds__(256) void ksum_kernel(
    const float* __restrict__ P, const float* __restrict__ res,
    float* __restrict__ outF, u16* __restrict__ outB, int total)
{
    int i = blockIdx.x * blockDim.x + threadIdx.x;
    size_t o4 = (size_t)i * 4;
    if (o4 >= (size_t)total) return;
    float4 s = *(const float4*)(P + o4);
    #pragma unroll
    for (int p = 1; p < NS; ++p) {
        float4 v = *(const float4*)(P + (size_t)p * total + o4);
        s.x += v.x; s.y += v.y; s.z += v.z; s.w += v.w;
    }
    if (EPI == 2) {
        float4 r = *(const float4*)(res + o4);
        s.x += r.x; s.y += r.y; s.z += r.z; s.w += r.w;
    }
    if (EPI == 1) {
        s.x = fmaxf(s.x, 0.f); s.y = fmaxf(s.y, 0.f);
        s.z = fmaxf(s.z, 0.f); s.w = fmaxf(s.w, 0.f);
    }
    if (WF32) *(float4*)(outF + o4) = s;
    if (WBF16) {
        uint2 w;
        w.x = (u32)f2bf(s.x) | ((u32)f2bf(s.y) << 16);
        w.y = (u32)f2bf(s.z) | ((u32)f2bf(s.w) << 16);
        *(uint2*)(outB + o4) = w;
    }
}

// ============ fused attention per (b,m): all-heads phases, 3 barriers ===============
// r7: QK^T via MFMA 16x16x32 (verified layout: A row=l16 k=quad*8+j, B col=l16,
// D row=quad*4+reg col=l16). 4 waves x 2 heads; S stays f32 (softmax numerics
// unchanged). Softmax / atomicAdd / ctx phases identical to r6.
template<int CTX, int LD>
__global__ __launch_bounds__(256) void attn_fused_kernel(
    const u16* __restrict__ QKVb, const float* __restrict__ maskf, int bm0,
    float* __restrict__ att_sum, u16* __restrict__ ctxb)
{
    __shared__ __align__(16) u16 sQ[16][520];
    __shared__ __align__(16) u16 sK[16][520];
    __shared__ __align__(16) u16 sV[CTX ? 16 : 1][520];
    __shared__ float s_p[H_][16][17];
    __shared__ float sMask[16];
    int bm_l = blockIdx.x;
    int tid = threadIdx.x;
    int t = tid >> 4, ch = (tid & 15) * 32;
    const u16* base = QKVb + ((size_t)bm_l * T_ + t) * LD;
    #pragma unroll
    for (int c = 0; c < 4; ++c) {
        *(uint4*)&sQ[t][ch + c * 8] = *(const uint4*)(base + ch + c * 8);
        *(uint4*)&sK[t][ch + c * 8] = *(const uint4*)(base + 512 + ch + c * 8);
        if (CTX) *(uint4*)&sV[t][ch + c * 8] = *(const uint4*)(base + 1024 + ch + c * 8);
    }
    if (tid < 16) sMask[tid] = maskf[(size_t)(bm0 + bm_l) * T_ + tid];
    __syncthreads();

    int b = (bm0 + bm_l) >> 5;                  // bm = b*NN + m
    int lane = tid & 63, wid = tid >> 6;
    int l16 = lane & 15, quad = lane >> 4;

    // QK^T: per wave heads {wid, wid+4}; S[q=quad*4+reg][kt=l16] = Q[q][:] . K[kt][:]
    #pragma unroll
    for (int hh = 0; hh < 2; ++hh) {
        int h = wid + hh * 4;
        short8 aq0 = *(const short8*)&sQ[l16][h * 64 + quad * 8];
        short8 aq1 = *(const short8*)&sQ[l16][h * 64 + 32 + quad * 8];
        short8 bk0 = *(const short8*)&sK[l16][h * 64 + quad * 8];
        short8 bk1 = *(const short8*)&sK[l16][h * 64 + 32 + quad * 8];
        f32x4 acc = (f32x4){0.f, 0.f, 0.f, 0.f};
        acc = __builtin_amdgcn_mfma_f32_16x16x32_bf16(aq0, bk0, acc, 0, 0, 0);
        acc = __builtin_amdgcn_mfma_f32_16x16x32_bf16(aq1, bk1, acc, 0, 0, 0);
        #pragma unroll
        for (int reg = 0; reg < 4; ++reg) {
            int q = quad * 4 + reg;
            float v = acc[reg] * 0.125f;
            if (sMask[q] == 0.0f) v = -1e9f;
            s_p[h][q][l16] = v;
        }
    }
    __syncthreads();
    if (tid < 128) {
        int h = tid >> 4, q = tid & 15;
        float mx = -3.4e38f;
        #pragma unroll
        for (int kk = 0; kk < 16; ++kk) mx = fmaxf(mx, s_p[h][q][kk]);
        float e[16], s = 0.f;
        #pragma unroll
        for (int kk = 0; kk < 16; ++kk) { e[kk] = expf(s_p[h][q][kk] - mx); s += e[kk]; }
        float inv = 1.0f / s;
        #pragma unroll
        for (int kk = 0; kk < 16; ++kk) s_p[h][q][kk] = e[kk] * inv;
    }
    __syncthreads();
    #pragma unroll
    for (int r = 0; r < 8; ++r) {
        int h = r;
        int q = (tid >> 4) & 15, k = tid & 15;
        atomicAdd(&att_sum[(((size_t)b * H_ + h) * T_ + q) * T_ + k], s_p[h][q][k]);
    }
    if (CTX) {
        // 4 consecutive cols (2 u32) per step: uint2 sV reads, uint2 ctxb writes
        #pragma unroll
        for (int rep = 0; rep < 8; ++rep) {
            int i2 = rep * 256 + tid;           // t*128 + cu, cu = uint2 col index
            int tt = i2 >> 7, cu = i2 & 127;
            int h = cu >> 4;                    // (cu*2)>>5; pair never crosses a head
            const float* pr = &s_p[h][tt][0];
            float a0 = 0.f, a1 = 0.f, a2 = 0.f, a3 = 0.f;
            #pragma unroll
            for (int kk = 0; kk < 16; ++kk) {
                uint2 vv = *((const uint2*)&sV[kk][0] + cu);
                float p = pr[kk];
                a0 += p * bfv((u16)(vv.x & 0xffff));
                a1 += p * bfv((u16)(vv.x >> 16));
                a2 += p * bfv((u16)(vv.y & 0xffff));
                a3 += p * bfv((u16)(vv.y >> 16));
            }
            uint2 o;
            o.x = (u32)f2bf(a0) | ((u32)f2bf(a1) << 16);
            o.y = (u32)f2bf(a2) | ((u32)f2bf(a3) << 16);
            *(uint2*)((u32*)(ctxb + ((size_t)bm_l * T_ + tt) * D_) + cu * 2) = o;
        }
    }
}

// ============ fused self-attention + combine + si, one block per (n,h) ==============
// r6: qk dot via float4 LDS reads (4x fewer LDS ops, identical FMA order).
__global__ __launch_bounds__(256) void siatt_kernel(
    const float* __restrict__ xemb, const float* __restrict__ att_sum,
    const float* __restrict__ attf, u16* __restrict__ sib)
{
    __shared__ float sX[16][516];
    __shared__ float sS[16][17];
    __shared__ float sA[16][17];
    int n = blockIdx.x >> 3, h = blockIdx.x & 7;
    int tid = threadIdx.x;
    int t = tid >> 4, ch = (tid & 15) * 32;
    const float* src = xemb + ((size_t)n * T_ + t) * D_;
    #pragma unroll
    for (int c = 0; c < 8; ++c)
        *(float4*)&sX[t][ch + c * 4] = *(const float4*)(src + ch + c * 4);
    __syncthreads();
    int q = tid >> 4, k = tid & 15;
    {
        // row stride 516 f32 = 2064B (16B aligned); same accumulation order
        float acc = 0.f;
        for (int d4 = 0; d4 < D_ / 4; ++d4) {
            float4 xq = *(const float4*)&sX[q][d4 * 4];
            float4 xk = *(const float4*)&sX[k][d4 * 4];
            acc += xq.x * xk.x;
            acc += xq.y * xk.y;
            acc += xq.z * xk.z;
            acc += xq.w * xk.w;
        }
        sS[q][k] = acc * 0.04419417382415922f;
    }
    __syncthreads();
    if (tid < T_) {
        float mx = -3.4e38f;
        #pragma unroll
        for (int kk = 0; kk < 16; ++kk) mx = fmaxf(mx, sS[tid][kk]);
        float e[16], s = 0.f;
        #pragma unroll
        for (int kk = 0; kk < 16; ++kk) { e[kk] = expf(sS[tid][kk] - mx); s += e[kk]; }
        float inv = 1.0f / s;
        #pragma unroll
        for (int kk = 0; kk < 16; ++kk) sS[tid][kk] = e[kk] * inv;
    }
    __syncthreads();
    float f = attf[0] * (1.0f / 32.0f);
    sA[q][k] = sS[q][k] + f * att_sum[((size_t)n * H_ + h) * 256 + q * 16 + k];
    __syncthreads();
    #pragma unroll
    for (int rep = 0; rep < 16; ++rep) {
        int i2 = rep * 256 + tid;          // q*256 + d2
        int qq = i2 >> 8, d2 = (i2 & 255) * 2;
        const float* ar = &sA[qq][0];
        float a0 = 0.f, a1 = 0.f;
        #pragma unroll
        for (int tt = 0; tt < 16; ++tt) {
            float p = ar[tt];
            a0 += p * sX[tt][d2];
            a1 += p * sX[tt][d2 + 1];
        }
        u32 o = (u32)f2bf(a0) | ((u32)f2bf(a1) << 16);
        *((u32*)(sib + (size_t)n * T_ * 4096 + (size_t)qq * 4096 + h * 512) + (d2 >> 1)) = o;
    }
}

// ---------------- positional encoding ------------------------------------------------
__global__ void pe_kernel(float* pe) {
    int i = blockIdx.x * blockDim.x + threadIdx.x;
    if (i >= T_ * 256) return;
    int t = i >> 8, j = i & 255;
    float dv = (float)pow(10000.0, (double)j / 256.0);
    float a = (float)t * dv;
    double ad = (double)a;
    pe[t * D_ + 2 * j]     = (float)sin(ad);
    pe[t * D_ + 2 * j + 1] = (float)cos(ad);
}

// ---------------- x features + embed -------------------------------------------------
__global__ void xemb_kernel(const float* x, const float* Wx, const float* bx,
                            const float* pe, float* xemb) {
    int row = blockIdx.x;              // t*N + n
    int t = row / N_, n = row % N_;
    float x0 = x[row * 6 + 0], x1 = x[row * 6 + 1];
    float x2 = x[row * 6 + 2], x3 = x[row * 6 + 3];
    float x4 = x[row * 6 + 4], x5 = x[row * 6 + 5];
    float vel = sqrtf(x2 * x2 + x3 * x3);
    float ang = atanf(x5 / x4);
    float f0 = ntn(x0), f1 = ntn(x1), f2 = ntn(vel), f3 = ntn(ang);
    for (int d = threadIdx.x; d < D_; d += blockDim.x) {
        xemb[((size_t)n * T_ + t) * D_ + d] =
            f0 * Wx[0 * D_ + d] + f1 * Wx[1 * D_ + d]
          + f2 * Wx[2 * D_ + d] + f3 * Wx[3 * D_ + d]
          + bx[d] + pe[t * D_ + d];
    }
}

// ---------------- neighbor features + mask -------------------------------------------
__global__ void nbr_kernel(const float* x, const float* nbr, float* nf, float* maskf) {
    int idx = blockIdx.x * blockDim.x + threadIdx.x;   // t*N*NN + n*NN + m
    if (idx >= T_ * N_ * NN_) return;
    int m = idx % NN_;
    int tn = idx / NN_;
    int n = tn % N_, t = tn / N_;
    float px = x[((size_t)t * N_ + n) * 6 + 0];
    float py = x[((size_t)t * N_ + n) * 6 + 1];
    float vx, vy;
    if (t == 0) {
        vx = x[((size_t)1 * N_ + n) * 6 + 2];
        vy = x[((size_t)1 * N_ + n) * 6 + 3];
    } else {
        vx = px - x[((size_t)(t - 1) * N_ + n) * 6 + 0];
        vy = py - x[((size_t)(t - 1) * N_ + n) * 6 + 1];
    }
    float nx  = nbr[(size_t)idx * 4 + 0], ny  = nbr[(size_t)idx * 4 + 1];
    float nvx = nbr[(size_t)idx * 4 + 2], nvy = nbr[(size_t)idx * 4 + 3];
    float dpx = nx - px, dpy = ny - py;
    float dvx = nvx - vx, dvy = nvy - vy;
    float dist = sqrtf(dpx * dpx + dpy * dpy);
    maskf[((size_t)n * NN_ + m) * T_ + t] = (dist <= 2.0f) ? 1.0f : 0.0f;
    float vn = sqrtf(vx * vx + vy * vy);
    float bearing = (dpx * vx + dpy * vy) / (dist * vn);
    if (isnan(bearing)) bearing = 0.0f;
    float dvn = sqrtf(dvx * dvx + dvy * dvy);
    float tau = -(dpx * dvx + dpy * dvy) / dvn;
    if (isnan(tau)) tau = 0.0f;
    tau = fminf(fmaxf(tau, 0.0f), 7.0f);
    float mx_ = dpx + tau * dvx, my_ = dpy + tau * dvy;
    float mpd = sqrtf(mx_ * mx_ + my_ * my_);
    nf[(size_t)idx * 3 + 0] = ntn(dist);
    nf[(size_t)idx * 3 + 1] = ntn(bearing);
    nf[(size_t)idx * 3 + 2] = ntn(mpd);
}

// ---------------- neighbor embed: bf16 n_emb only ------------------------------------
__global__ void nemb_kernel(const float* nf, const float* Wn, const float* bn,
                            const float* pe, u16* Ab) {
    int row = blockIdx.x;              // (b*NN+m)*T + t
    int t = row % T_;
    int bm = row / T_;
    int m = bm % NN_, b = bm / NN_;
    size_t nfrow = (((size_t)t * N_ + b) * NN_ + m) * 3;
    float f0 = nf[nfrow], f1 = nf[nfrow + 1], f2 = nf[nfrow + 2];
    for (int d = threadIdx.x; d < D_; d += blockDim.x) {
        float v = f0 * Wn[d] + f1 * Wn[D_ + d] + f2 * Wn[2 * D_ + d]
                + bn[d] + pe[t * D_ + d];
        Ab[(size_t)row * D_ + d] = f2bf(v);
    }
}

// ---------------- LayerNorm, one wave per row; input f32 or bf16; dual out -----------
// r6: vectorized -- lane owns 8 CONTIGUOUS elements (short8 / 2x float4 loads,
// packed stores). Reduction set identical (order perturbation ~1e-6, tol 1.6e-2).
template<int INBF>
__global__ __launch_bounds__(256) void ln_kernel(
    const void* X, const float* g, const float* b, float* outF, u16* outB, int nrows) {
    int row = blockIdx.x * 4 + (threadIdx.x >> 6);
    if (row >= nrows) return;
    int lane = threadIdx.x & 63;
    int d0 = lane * 8;
    float v[8];
    if (INBF) {
        short8 x8 = *(const short8*)((const u16*)X + (size_t)row * D_ + d0);
        #pragma unroll
        for (int r = 0; r < 8; ++r) v[r] = bfv((u16)x8[r]);
    } else {
        float4 a = *(const float4*)((const float*)X + (size_t)row * D_ + d0);
        float4 c = *(const float4*)((const float*)X + (size_t)row * D_ + d0 + 4);
        v[0] = a.x; v[1] = a.y; v[2] = a.z; v[3] = a.w;
        v[4] = c.x; v[5] = c.y; v[6] = c.z; v[7] = c.w;
    }
    float s = 0.f;
    #pragma unroll
    for (int r = 0; r < 8; ++r) s += v[r];
    s = wave_sum(s);
    float mean = s * (1.0f / 512.0f);
    float vs = 0.f;
    #pragma unroll
    for (int r = 0; r < 8; ++r) { float d = v[r] - mean; vs += d * d; }
    vs = wave_sum(vs);
    float rstd = rsqrtf(vs * (1.0f / 512.0f) + 1e-5f);
    float4 g0 = *(const float4*)&g[d0], g1 = *(const float4*)&g[d0 + 4];
    float4 b0 = *(const float4*)&b[d0], b1 = *(const float4*)&b[d0 + 4];
    float o[8];
    o[0] = (v[0] - mean) * rstd * g0.x + b0.x;
    o[1] = (v[1] - mean) * rstd * g0.y + b0.y;
    o[2] = (v[2] - mean) * rstd * g0.z + b0.z;
    o[3] = (v[3] - mean) * rstd * g0.w + b0.w;
    o[4] = (v[4] - mean) * rstd * g1.x + b1.x;
    o[5] = (v[5] - mean) * rstd * g1.y + b1.y;
    o[6] = (v[6] - mean) * rstd * g1.z + b1.z;
    o[7] = (v[7] - mean) * rstd * g1.w + b1.w;
    if (outF) {
        float4 w0 = {o[0], o[1], o[2], o[3]};
        float4 w1 = {o[4], o[5], o[6], o[7]};
        *(float4*)(outF + (size_t)row * D_ + d0) = w0;
        *(float4*)(outF + (size_t)row * D_ + d0 + 4) = w1;
    }
    if (outB) {
        short8 w;
        #pragma unroll
        for (int r = 0; r < 8; ++r) w[r] = (short)f2bf(o[r]);
        *(short8*)(outB + (size_t)row * D_ + d0) = w;
    }
}

// ---------------- prediction head + broadcast fused (f32 out) ------------------------
// r7: one thread per (n,t); float4 loads of xemb row and Wp; per-c accumulation
// order preserved (j ascending).
__global__ __launch_bounds__(256) void predbcast_kernel(
    const float* __restrict__ xemb, const float* __restrict__ Wp,
    const float* __restrict__ bp, float* __restrict__ out) {
    int nt = blockIdx.x * blockDim.x + threadIdx.x;    // n*T + t
    if (nt >= N_ * T_) return;
    int n = nt / T_, t = nt % T_;
    float a0 = bp[0], a1 = bp[1];
    const float* xr = xemb + (size_t)nt * D_;
    for (int j = 0; j < D_; j += 4) {
        float4 xv = *(const float4*)&xr[j];
        float4 w0 = *(const float4*)&Wp[(size_t)j * 2];      // W[j][0..1], W[j+1][0..1]
        float4 w1 = *(const float4*)&Wp[(size_t)j * 2 + 4];  // W[j+2][0..1], W[j+3][0..1]
        a0 += xv.x * w0.x; a1 += xv.x * w0.y;
        a0 += xv.y * w0.z; a1 += xv.y * w0.w;
        a0 += xv.z * w1.x; a1 += xv.z * w1.y;
        a0 += xv.w * w1.z; a1 += xv.w * w1.w;
    }
    #pragma unroll
    for (int p = 0; p < NPRED_; ++p) {
        size_t o = (((size_t)p * T_ + t) * N_ + n) * 2;
        out[o]     = a0;
        out[o + 1] = a1;
    }
}

extern "C" void kernel_launch(void* const* d_in, const int* in_sizes, int n_in,
                              void* d_out, int out_size, void* d_ws, size_t ws_size,
                              hipStream_t stream) {
    (void)in_sizes; (void)n_in; (void)out_size; (void)ws_size;

    const float* x    = (const float*)d_in[0];
    const float* nbr  = (const float*)d_in[1];
    const float* attf = (const float*)d_in[2];
    const float* Wx   = (const float*)d_in[3];
    const float* bx   = (const float*)d_in[4];
    const float* Wn   = (const float*)d_in[5];
    const float* bn   = (const float*)d_in[6];
    const float* Wp   = (const float*)d_in[7];
    const float* bp   = (const float*)d_in[8];
    const float* WQ   = (const float*)d_in[9];
    const float* WK   = (const float*)d_in[10];
    const float* WV   = (const float*)d_in[11];
    const float* Wfc  = (const float*)d_in[12];
    const float* mlng = (const float*)d_in[13];
    const float* mlnb = (const float*)d_in[14];
    const float* WSI  = (const float*)d_in[15];
    const float* fsw1 = (const float*)d_in[16];
    const float* fsw2 = (const float*)d_in[17];
    const float* fsg  = (const float*)d_in[18];
    const float* fsb  = (const float*)d_in[19];
    const float* fiw1 = (const float*)d_in[20];
    const float* fiw2 = (const float*)d_in[21];
    const float* fig  = (const float*)d_in[22];
    const float* fib  = (const float*)d_in[23];

    char* w = (char*)d_ws;
    size_t off = 0;
    auto alloc = [&](size_t bytes) -> void* {
        void* p = w + off;
        off = (off + bytes + 255) & ~(size_t)255;
        return p;
    };
    const size_t MiB = 1024 * 1024;

    const int BM = N_ * NN_;          // 2048 (b,m) pairs
    const int ROWS_I = BM * T_;       // 32768 neighbor rows
    const int CB = 1024;              // bm per chunk (NCH=2, l=0 only)
    const int RC = CB * T_;           // 16384 rows per chunk
    const int NCH = ROWS_I / RC;      // 2

    float* pe      = (float*)alloc((size_t)T_ * D_ * 4);
    float* xemb    = (float*)alloc((size_t)N_ * T_ * D_ * 4);
    float* nf      = (float*)alloc((size_t)T_ * N_ * NN_ * 3 * 4);
    float* maskf   = (float*)alloc((size_t)BM * T_ * 4);
    u16*   Ab      = (u16*)alloc((size_t)ROWS_I * D_ * 2);     // n_emb bf16  32 MiB
    u16* tQKV[2], *tWSI[2], *tfs1[2], *tfs2[2];
    for (int l = 0; l < 2; ++l) {
        tQKV[l] = (u16*)alloc((size_t)1536 * 512 * 2);
        tWSI[l] = (u16*)alloc((size_t)512 * 4096 * 2);
        tfs1[l] = (u16*)alloc((size_t)2048 * 512 * 2);
        tfs2[l] = (u16*)alloc((size_t)512 * 2048 * 2);
    }
    u16* tWfc = (u16*)alloc((size_t)512 * 512 * 2);
    u16* tfi1 = (u16*)alloc((size_t)2048 * 512 * 2);
    u16* tfi2 = (u16*)alloc((size_t)512 * 2048 * 2);
    // scratch union: l0 chunk: QKVb 48 + ctxb 16 | hid 64 ; l1: QK full 64 MiB
    // ffs phase: hid(ffs) 4 MiB @ SCR+0, split-K partials 16 MiB @ SCR+16MiB
    char* SCR  = (char*)alloc(64 * MiB);
    u16*   QKVb = (u16*)SCR;
    u16*   ctxb = (u16*)(SCR + 48 * MiB);
    u16*   hid  = (u16*)SCR;
    float* Pk   = (float*)(SCR + 16 * MiB);
    u16*   BbA    = (u16*)alloc((size_t)RC * D_ * 2);  // pre-LN bf16 chunk    16 MiB
    u16*   Bb_res = (u16*)alloc((size_t)RC * D_ * 2);  // res_inter bf16       16 MiB
    float* att_sum = (float*)alloc((size_t)N_ * H_ * 256 * 4);
    u16*   sib     = (u16*)alloc((size_t)N_ * T_ * 4096 * 2);  // 8 MiB
    float* xnew    = (float*)alloc((size_t)N_ * T_ * D_ * 4);
    u16*   xnb     = (u16*)alloc((size_t)N_ * T_ * D_ * 2);
    // total ~170 MiB

    // ---- batched weight conversion: 14 jobs, one launch ----
    WJobs jobs;
    int ntiles = 0;
    auto addJob = [&](int idx, const float* src, u16* dst, int K, int N) {
        jobs.j[idx] = {src, dst, K, N, ntiles};
        ntiles += (N >> 5) * (K >> 5);
    };
    addJob(0,  WQ,                            tQKV[0],              512, 512);
    addJob(1,  WK,                            tQKV[0] + 512 * 512,  512, 512);
    addJob(2,  WV,                            tQKV[0] + 1024 * 512, 512, 512);   // dead at l=1
    addJob(3,  WQ + (size_t)512 * 512,        tQKV[1],              512, 512);
    addJob(4,  WK + (size_t)512 * 512,        tQKV[1] + 512 * 512,  512, 512);
    addJob(5,  Wfc,                           tWfc,                 512, 512);
    addJob(6,  WSI,                           tWSI[0],              4096, 512);
    addJob(7,  WSI + (size_t)4096 * 512,      tWSI[1],              4096, 512);
    addJob(8,  fsw1,                          tfs1[0],              512, 2048);
    addJob(9,  fsw1 + (size_t)512 * 2048,     tfs1[1],              512, 2048);
    addJob(10, fsw2,                          tfs2[0],              2048, 512);
    addJob(11, fsw2 + (size_t)2048 * 512,     tfs2[1],              2048, 512);
    addJob(12, fiw1,                          tfi1,                 512, 2048);
    addJob(13, fiw2,                          tfi2,                 2048, 512);
    wconv_all<<<ntiles, 256, 0, stream>>>(jobs, ntiles);

    pe_kernel<<<16, 256, 0, stream>>>(pe);
    xemb_kernel<<<T_ * N_, 256, 0, stream>>>(x, Wx, bx, pe, xemb);
    nbr_kernel<<<(T_ * N_ * NN_ + 255) / 256, 256, 0, stream>>>(x, nbr, nf, maskf);
    nemb_kernel<<<BM * T_, 256, 0, stream>>>(nf, Wn, bn, pe, Ab);

    for (int l = 0; l < L_; ++l) {
        hipMemsetAsync(att_sum, 0, (size_t)N_ * H_ * 256 * 4, stream);
        if (l == 0) {
            for (int c = 0; c < NCH; ++c) {
                u16* Acb = Ab + (size_t)c * RC * D_;
                // QKV fused GEMM: N=1536 (1536 blocks = 3 exact rounds @2/CU)
                gemm_ct<0, 0, 1><<<dim3(12, RC / 128), 256, 0, stream>>>(
                    Acb, tQKV[0], nullptr, QKVb, nullptr, 512, 1536);
                attn_fused_kernel<1, 1536><<<CB, 256, 0, stream>>>(
                    QKVb, maskf, c * CB, att_sum, ctxb);
                // fc + residual(n_emb bf16) -> pre-LN bf16 (512 blocks = 1 round)
                gemm_ct<3, 0, 1><<<dim3(4, RC / 128), 256, 0, stream>>>(
                    ctxb, tWfc, nullptr, BbA, Acb, 512, 512);
                ln_kernel<1><<<RC / 4, 256, 0, stream>>>(
                    BbA, mlng, mlnb, nullptr, Bb_res, RC);   // res_inter bf16
                // ffi1 relu: N=2048 (2048 blocks = 4 exact rounds)
                gemm_ct<1, 0, 1><<<dim3(16, RC / 128), 256, 0, stream>>>(
                    Bb_res, tfi1, nullptr, hid, nullptr, 512, 2048);
                // ffi2 + residual(res_inter bf16) -> pre-LN bf16 (512 blocks)
                gemm_ct<3, 0, 1><<<dim3(4, RC / 128), 256, 0, stream>>>(
                    hid, tfi2, nullptr, BbA, Bb_res, 2048, 512);
                ln_kernel<1><<<RC / 4, 256, 0, stream>>>(
                    BbA, fig, fib, nullptr, Acb, RC);        // new n_emb (bf16)
            }
        } else {
            // l=1: unchunked QK (N=1024, ldc=1024; 64 MiB = SCR): 2048 blocks
            gemm_ct<0, 0, 1><<<dim3(8, ROWS_I / 128), 256, 0, stream>>>(
                Ab, tQKV[1], nullptr, QKVb, nullptr, 512, 1024);
            attn_fused_kernel<0, 1024><<<BM, 256, 0, stream>>>(
                QKVb, maskf, 0, att_sum, nullptr);
        }

        // ---- self-attention + si + ffs (updates xemb; split-K, f32 chain) ----
        siatt_kernel<<<N_ * H_, 256, 0, stream>>>(xemb, att_sum, attf, sib);
        // xnew/xnb = sib @ tWSI (M=1024, N=512, K=4096): NS=8 -> 256 blocks, Kc=512
        gemm_ks<8><<<dim3(4, 8, 8), 256, 0, stream>>>(sib, tWSI[l], Pk, 4096, 512);
        ksum_kernel<8, 0, 1, 1><<<512, 256, 0, stream>>>(
            Pk, nullptr, xnew, xnb, 1024 * 512);
        // hid = relu(xnb @ tfs1) (N=2048, K=512): NS=2 -> 256 blocks, Kc=256
        gemm_ks<2><<<dim3(16, 8, 2), 256, 0, stream>>>(xnb, tfs1[l], Pk, 512, 2048);
        ksum_kernel<2, 1, 0, 1><<<2048, 256, 0, stream>>>(
            Pk, nullptr, nullptr, hid, 1024 * 2048);
        // xemb = (hid @ tfs2) + xnew (N=512, K=2048): NS=8 -> 256 blocks, Kc=256
        gemm_ks<8><<<dim3(4, 8, 8), 256, 0, stream>>>(hid, tfs2[l], Pk, 2048, 512);
        ksum_kernel<8, 2, 1, 0><<<512, 256, 0, stream>>>(
            Pk, xnew, xemb, nullptr, 1024 * 512);
        ln_kernel<0><<<(N_ * T_) / 4, 256, 0, stream>>>(
            xemb, fsg + l * D_, fsb + l * D_, xemb, nullptr, N_ * T_);
    }

    predbcast_kernel<<<(N_ * T_ + 255) / 256, 256, 0, stream>>>(
        xemb, Wp, bp, (float*)d_out);
}

// Round 10
// 752.974 us; speedup vs baseline: 1.1349x; 1.0036x over previous
//
#include <hip/hip_runtime.h>
#include <math.h>

// DTYPE COMMITMENTS (evidence-backed): inputs f32, output f32 (rounds 4-14 PASS).
// WS BUDGET: <= ~210 MB decimal; this build ~170 MiB (+0: partials alias SCR).
// r10: r9's gemm_8p FAILED correctness (K-tile pair aliased one LDS buffer ->
// double-accumulated one tile). 8-phase family is 0/4 -> abandoned; GEMMs frozen
// at the r8 state (755.7us, verified). This round = exact r8 revert + vectorized
// nemb/xemb prologue (row-per-wave, short8/float4 stores; per-element math
// bit-identical).

#define T_ 16
#define N_ 64
#define NN_ 32
#define D_ 512
#define H_ 8
#define DK_ 64
#define DFF_ 2048
#define L_ 2
#define NPRED_ 20

typedef unsigned short u16;
typedef unsigned int u32;
typedef __attribute__((ext_vector_type(8))) short short8;
typedef __attribute__((ext_vector_type(4))) float f32x4;

__device__ __forceinline__ u16 f2bf(float f) {
    u32 u = __float_as_uint(f);
    u32 r = u + 0x7fffu + ((u >> 16) & 1u);
    return (u16)(r >> 16);
}
__device__ __forceinline__ float bfv(u16 v) {
    return __uint_as_float(((u32)v) << 16);
}
__device__ __forceinline__ float ntn(float v) {
    if (isnan(v)) return 0.0f;
    if (isinf(v)) return v > 0.0f ? 3.4028234663852886e38f : -3.4028234663852886e38f;
    return v;
}
__device__ __forceinline__ float wave_sum(float v) {
    #pragma unroll
    for (int o = 32; o > 0; o >>= 1) v += __shfl_xor(v, o, 64);
    return v;
}
// async 16B HBM->LDS: writes ldsbase + lane*16 (wave-uniform base, per-lane gptr)
__device__ __forceinline__ void gload_lds(const u16* g, u16* l) {
    __builtin_amdgcn_global_load_lds(
        (const __attribute__((address_space(1))) u32*)g,
        (__attribute__((address_space(3))) u32*)l, 16, 0, 0);
}

// ============ batched weight convert+transpose: 14 jobs in ONE launch ===============
struct WJob { const float* src; u16* dst; int K; int N; int t0; };
struct WJobs { WJob j[14]; };
__global__ __launch_bounds__(256) void wconv_all(WJobs jobs, int ntiles) {
    int bid = blockIdx.x;
    if (bid >= ntiles) return;
    int ji = 0;
    #pragma unroll 1
    for (int i = 1; i < 14; ++i) if (bid >= jobs.j[i].t0) ji = i;
    const float* in = jobs.j[ji].src;
    u16* out = jobs.j[ji].dst;
    int K = jobs.j[ji].K, N = jobs.j[ji].N;
    int lt = bid - jobs.j[ji].t0;
    int ntx = N >> 5;
    int nb = (lt % ntx) * 32, kb = (lt / ntx) * 32;
    __shared__ float tile[32][33];
    int tx = threadIdx.x & 31, ty = threadIdx.x >> 5;
    #pragma unroll
    for (int r = ty; r < 32; r += 8)
        tile[r][tx] = in[(size_t)(kb + r) * N + nb + tx];
    __syncthreads();
    #pragma unroll
    for (int r = ty; r < 32; r += 8)
        out[(size_t)(nb + r) * K + kb + tx] = f2bf(tile[tx][r]);
}

// ============ counted-pipeline GEMM: 128x128, BK=64, 2 barriers/tile (r4 best) ======
// Per K-tile: (1) issue 8 gload_lds for tile t+1 into the other LDS buffer FIRST;
// (2) s_waitcnt vmcnt(8) -- counted: the 8 just-issued loads stay IN FLIGHT, only
// tile t's loads (issued one full tile ago) must have landed; (3) one rendezvous
// s_barrier; (4) full 32-MFMA compute, setprio-wrapped, no intra-tile barriers;
// (5) one end barrier protecting the buffer restaged next iteration. vmcnt(0) only
// at the last tile. LDS 64KiB -> 2 blocks/CU. r9 XOR swizzle (0 conflicts).
// Requires M%128==0, N%128==0, K%64==0 (K>=128), gridDim.y%8==0 (XCD remap).
template<int EPI, int WF32, int WBF16>
__global__ __launch_bounds__(256, 2) void gemm_ct(
    const u16* __restrict__ Ab, const u16* __restrict__ Btb,
    float* __restrict__ Cf, u16* __restrict__ Cb, const void* __restrict__ Rg,
    int K, int ldc)
{
    __shared__ __align__(16) u16 As[2][128][64];
    __shared__ __align__(16) u16 Bs[2][128][64];
    int tid = threadIdx.x;
    int lane = tid & 63, wave = tid >> 6;       // 4 waves: 2M x 2N
    int quad = lane >> 4, l16 = lane & 15;
    int wm = (wave >> 1) * 64, wn = (wave & 1) * 64;

    int gx = gridDim.x, gy = gridDim.y;
    int id = blockIdx.y * gx + blockIdx.x;
    int xcd = id & 7, slot = id >> 3;
    int bx = slot % gx;
    int by = xcd * (gy >> 3) + slot / gx;
    size_t row0 = (size_t)by * 128;
    size_t col0 = (size_t)bx * 128;

    f32x4 acc[4][4];
    #pragma unroll
    for (int i = 0; i < 4; ++i)
        #pragma unroll
        for (int j = 0; j < 4; ++j)
            acc[i][j] = (f32x4){0.f, 0.f, 0.f, 0.f};

    // staging swizzle (r9-verified): physical 16B chunk p of row r holds logical
    // chunk p ^ (r&7)
    int srow = lane >> 3;
    int c8 = (lane & 7) ^ srow;
    int h8 = l16 & 7;
    size_t aoff[4], boff[4];
    #pragma unroll
    for (int it = 0; it < 4; ++it) {
        aoff[it] = (row0 + (size_t)(wave + it * 4) * 8 + srow) * (size_t)K + c8 * 8;
        boff[it] = (col0 + (size_t)(wave + it * 4) * 8 + srow) * (size_t)K + c8 * 8;
    }

    int nt = K >> 6;
    // prologue: stage tile 0 -> buf 0 (8 loads in flight, no wait)
    #pragma unroll
    for (int it = 0; it < 4; ++it)
        gload_lds(Ab + aoff[it], &As[0][(wave + it * 4) * 8][0]);
    #pragma unroll
    for (int it = 0; it < 4; ++it)
        gload_lds(Btb + boff[it], &Bs[0][(wave + it * 4) * 8][0]);

    #pragma unroll 1
    for (int t = 0; t < nt; ++t) {
        int cur = t & 1;
        if (t + 1 < nt) {
            // stage tile t+1 into other buffer (freed by iter t-1's end barrier)
            size_t ko = (size_t)(t + 1) * 64;
            #pragma unroll
            for (int it = 0; it < 4; ++it)
                gload_lds(Ab + aoff[it] + ko, &As[cur ^ 1][(wave + it * 4) * 8][0]);
            #pragma unroll
            for (int it = 0; it < 4; ++it)
                gload_lds(Btb + boff[it] + ko, &Bs[cur ^ 1][(wave + it * 4) * 8][0]);
            __builtin_amdgcn_sched_barrier(0);
            asm volatile("s_waitcnt vmcnt(8)" ::: "memory");   // tile t landed; t+1 in flight
        } else {
            __builtin_amdgcn_sched_barrier(0);
            asm volatile("s_waitcnt vmcnt(0)" ::: "memory");   // final tile only
        }
        __builtin_amdgcn_sched_barrier(0);
        __builtin_amdgcn_s_barrier();                          // rendezvous: tile t staged
        __builtin_amdgcn_sched_barrier(0);
        __builtin_amdgcn_s_setprio(1);
        #pragma unroll
        for (int kh = 0; kh < 2; ++kh) {
            int coff = ((kh * 4 + quad) ^ h8) * 8;
            short8 af[4], bf[4];
            #pragma unroll
            for (int j = 0; j < 4; ++j)
                bf[j] = *(short8*)&Bs[cur][wn + j * 16 + l16][coff];
            #pragma unroll
            for (int i = 0; i < 4; ++i)
                af[i] = *(short8*)&As[cur][wm + i * 16 + l16][coff];
            #pragma unroll
            for (int i = 0; i < 4; ++i)
                #pragma unroll
                for (int j = 0; j < 4; ++j)
                    acc[i][j] = __builtin_amdgcn_mfma_f32_16x16x32_bf16(
                        af[i], bf[j], acc[i][j], 0, 0, 0);
        }
        __builtin_amdgcn_s_setprio(0);
        __builtin_amdgcn_sched_barrier(0);                     // reads done before barrier
        __builtin_amdgcn_s_barrier();                          // frees buf[cur] for restage
    }

    // C/D layout (on-target verified): col = lane&15, row = quad*4 + reg
    #pragma unroll
    for (int i = 0; i < 4; ++i)
        #pragma unroll
        for (int j = 0; j < 4; ++j)
            #pragma unroll
            for (int reg = 0; reg < 4; ++reg) {
                size_t row = row0 + wm + i * 16 + quad * 4 + reg;
                size_t col = col0 + wn + j * 16 + l16;
                float v = acc[i][j][reg];
                if (EPI == 2) v += ((const float*)Rg)[row * (size_t)ldc + col];
                if (EPI == 3) v += bfv(((const u16*)Rg)[row * (size_t)ldc + col]);
                if (EPI == 1) v = fmaxf(v, 0.f);
                if (WF32)  Cf[row * (size_t)ldc + col] = v;
                if (WBF16) Cb[row * (size_t)ldc + col] = f2bf(v);
            }
}

// ============ split-K GEMM for small-M (ffs chain): gemm_ct schedule + z-split ======
// grid (N/128, M/128=8, NS); block z computes K-range [z*Kc,(z+1)*Kc), Kc=K/NS
// (Kc%64==0, Kc>=128), writes f32 partial to Pf + z*M*ldc. No atomics; ksum_kernel
// reduces. Identical pipeline/swizzle to gemm_ct (refcheck'd r4-r8).
template<int NS>
__global__ __launch_bounds__(256, 2) void gemm_ks(
    const u16* __restrict__ Ab, const u16* __restrict__ Btb,
    float* __restrict__ Pf, int K, int ldc)
{
    __shared__ __align__(16) u16 As[2][128][64];
    __shared__ __align__(16) u16 Bs[2][128][64];
    int tid = threadIdx.x;
    int lane = tid & 63, wave = tid >> 6;
    int quad = lane >> 4, l16 = lane & 15;
    int wm = (wave >> 1) * 64, wn = (wave & 1) * 64;

    int gx = gridDim.x, gy = gridDim.y;
    int id = blockIdx.y * gx + blockIdx.x;
    int xcd = id & 7, slot = id >> 3;
    int bx = slot % gx;
    int by = xcd * (gy >> 3) + slot / gx;
    int z = blockIdx.z;
    int Kc = K / NS;
    size_t row0 = (size_t)by * 128;
    size_t col0 = (size_t)bx * 128;
    size_t M = (size_t)gy * 128;

    f32x4 acc[4][4];
    #pragma unroll
    for (int i = 0; i < 4; ++i)
        #pragma unroll
        for (int j = 0; j < 4; ++j)
            acc[i][j] = (f32x4){0.f, 0.f, 0.f, 0.f};

    int srow = lane >> 3;
    int c8 = (lane & 7) ^ srow;
    int h8 = l16 & 7;
    size_t kbase = (size_t)z * Kc;
    size_t aoff[4], boff[4];
    #pragma unroll
    for (int it = 0; it < 4; ++it) {
        aoff[it] = (row0 + (size_t)(wave + it * 4) * 8 + srow) * (size_t)K + kbase + c8 * 8;
        boff[it] = (col0 + (size_t)(wave + it * 4) * 8 + srow) * (size_t)K + kbase + c8 * 8;
    }

    int nt = Kc >> 6;
    #pragma unroll
    for (int it = 0; it < 4; ++it)
        gload_lds(Ab + aoff[it], &As[0][(wave + it * 4) * 8][0]);
    #pragma unroll
    for (int it = 0; it < 4; ++it)
        gload_lds(Btb + boff[it], &Bs[0][(wave + it * 4) * 8][0]);

    #pragma unroll 1
    for (int t = 0; t < nt; ++t) {
        int cur = t & 1;
        if (t + 1 < nt) {
            size_t ko = (size_t)(t + 1) * 64;
            #pragma unroll
            for (int it = 0; it < 4; ++it)
                gload_lds(Ab + aoff[it] + ko, &As[cur ^ 1][(wave + it * 4) * 8][0]);
            #pragma unroll
            for (int it = 0; it < 4; ++it)
                gload_lds(Btb + boff[it] + ko, &Bs[cur ^ 1][(wave + it * 4) * 8][0]);
            __builtin_amdgcn_sched_barrier(0);
            asm volatile("s_waitcnt vmcnt(8)" ::: "memory");
        } else {
            __builtin_amdgcn_sched_barrier(0);
            asm volatile("s_waitcnt vmcnt(0)" ::: "memory");
        }
        __builtin_amdgcn_sched_barrier(0);
        __builtin_amdgcn_s_barrier();
        __builtin_amdgcn_sched_barrier(0);
        __builtin_amdgcn_s_setprio(1);
        #pragma unroll
        for (int kh = 0; kh < 2; ++kh) {
            int coff = ((kh * 4 + quad) ^ h8) * 8;
            short8 af[4], bf[4];
            #pragma unroll
            for (int j = 0; j < 4; ++j)
                bf[j] = *(short8*)&Bs[cur][wn + j * 16 + l16][coff];
            #pragma unroll
            for (int i = 0; i < 4; ++i)
                af[i] = *(short8*)&As[cur][wm + i * 16 + l16][coff];
            #pragma unroll
            for (int i = 0; i < 4; ++i)
                #pragma unroll
                for (int j = 0; j < 4; ++j)
                    acc[i][j] = __builtin_amdgcn_mfma_f32_16x16x32_bf16(
                        af[i], bf[j], acc[i][j], 0, 0, 0);
        }
        __builtin_amdgcn_s_setprio(0);
        __builtin_amdgcn_sched_barrier(0);
        __builtin_amdgcn_s_barrier();
    }

    float* P = Pf + (size_t)z * M * (size_t)ldc;
    #pragma unroll
    for (int i = 0; i < 4; ++i)
        #pragma unroll
        for (int j = 0; j < 4; ++j)
            #pragma unroll
            for (int reg = 0; reg < 4; ++reg) {
                size_t row = row0 + wm + i * 16 + quad * 4 + reg;
                size_t col = col0 + wn + j * 16 + l16;
                P[row * (size_t)ldc + col] = acc[i][j][reg];
            }
}

// ---- split-K reduce + epilogue: sum NS f32 partials; EPI 1=relu 2=+res; dual out --
template<int NS, int EPI, int WF32, int WBF16>
__global__ __launch_bounds__(256) void ksum_kernel(
    const float* __restrict__ P, const float* __restrict__ res,
    float* __restrict__ outF, u16* __restrict__ outB, int total)
{
    int i = blockIdx.x * blockDim.x + threadIdx.x;
    size_t o4 = (size_t)i * 4;
    if (o4 >= (size_t)total) return;
    float4 s = *(const float4*)(P + o4);
    #pragma unroll
    for (int p = 1; p < NS; ++p) {
        float4 v = *(const float4*)(P + (size_t)p * total + o4);
        s.x += v.x; s.y += v.y; s.z += v.z; s.w += v.w;
    }
    if (EPI == 2) {
        float4 r = *(const float4*)(res + o4);
        s.x += r.x; s.y += r.y; s.z += r.z; s.w += r.w;
    }
    if (EPI == 1) {
        s.x = fmaxf(s.x, 0.f); s.y = fmaxf(s.y, 0.f);
        s.z = fmaxf(s.z, 0.f); s.w = fmaxf(s.w, 0.f);
    }
    if (WF32) *(float4*)(outF + o4) = s;
    if (WBF16) {
        uint2 w;
        w.x = (u32)f2bf(s.x) | ((u32)f2bf(s.y) << 16);
        w.y = (u32)f2bf(s.z) | ((u32)f2bf(s.w) << 16);
        *(uint2*)(outB + o4) = w;
    }
}

// ============ fused attention per (b,m): all-heads phases, 3 barriers ===============
// r7: QK^T via MFMA 16x16x32 (verified layout); S stays f32. ctx phase uint2.
template<int CTX, int LD>
__global__ __launch_bounds__(256) void attn_fused_kernel(
    const u16* __restrict__ QKVb, const float* __restrict__ maskf, int bm0,
    float* __restrict__ att_sum, u16* __restrict__ ctxb)
{
    __shared__ __align__(16) u16 sQ[16][520];
    __shared__ __align__(16) u16 sK[16][520];
    __shared__ __align__(16) u16 sV[CTX ? 16 : 1][520];
    __shared__ float s_p[H_][16][17];
    __shared__ float sMask[16];
    int bm_l = blockIdx.x;
    int tid = threadIdx.x;
    int t = tid >> 4, ch = (tid & 15) * 32;
    const u16* base = QKVb + ((size_t)bm_l * T_ + t) * LD;
    #pragma unroll
    for (int c = 0; c < 4; ++c) {
        *(uint4*)&sQ[t][ch + c * 8] = *(const uint4*)(base + ch + c * 8);
        *(uint4*)&sK[t][ch + c * 8] = *(const uint4*)(base + 512 + ch + c * 8);
        if (CTX) *(uint4*)&sV[t][ch + c * 8] = *(const uint4*)(base + 1024 + ch + c * 8);
    }
    if (tid < 16) sMask[tid] = maskf[(size_t)(bm0 + bm_l) * T_ + tid];
    __syncthreads();

    int b = (bm0 + bm_l) >> 5;                  // bm = b*NN + m
    int lane = tid & 63, wid = tid >> 6;
    int l16 = lane & 15, quad = lane >> 4;

    // QK^T: per wave heads {wid, wid+4}; S[q=quad*4+reg][kt=l16] = Q[q][:] . K[kt][:]
    #pragma unroll
    for (int hh = 0; hh < 2; ++hh) {
        int h = wid + hh * 4;
        short8 aq0 = *(const short8*)&sQ[l16][h * 64 + quad * 8];
        short8 aq1 = *(const short8*)&sQ[l16][h * 64 + 32 + quad * 8];
        short8 bk0 = *(const short8*)&sK[l16][h * 64 + quad * 8];
        short8 bk1 = *(const short8*)&sK[l16][h * 64 + 32 + quad * 8];
        f32x4 acc = (f32x4){0.f, 0.f, 0.f, 0.f};
        acc = __builtin_amdgcn_mfma_f32_16x16x32_bf16(aq0, bk0, acc, 0, 0, 0);
        acc = __builtin_amdgcn_mfma_f32_16x16x32_bf16(aq1, bk1, acc, 0, 0, 0);
        #pragma unroll
        for (int reg = 0; reg < 4; ++reg) {
            int q = quad * 4 + reg;
            float v = acc[reg] * 0.125f;
            if (sMask[q] == 0.0f) v = -1e9f;
            s_p[h][q][l16] = v;
        }
    }
    __syncthreads();
    if (tid < 128) {
        int h = tid >> 4, q = tid & 15;
        float mx = -3.4e38f;
        #pragma unroll
        for (int kk = 0; kk < 16; ++kk) mx = fmaxf(mx, s_p[h][q][kk]);
        float e[16], s = 0.f;
        #pragma unroll
        for (int kk = 0; kk < 16; ++kk) { e[kk] = expf(s_p[h][q][kk] - mx); s += e[kk]; }
        float inv = 1.0f / s;
        #pragma unroll
        for (int kk = 0; kk < 16; ++kk) s_p[h][q][kk] = e[kk] * inv;
    }
    __syncthreads();
    #pragma unroll
    for (int r = 0; r < 8; ++r) {
        int h = r;
        int q = (tid >> 4) & 15, k = tid & 15;
        atomicAdd(&att_sum[(((size_t)b * H_ + h) * T_ + q) * T_ + k], s_p[h][q][k]);
    }
    if (CTX) {
        // 4 consecutive cols (2 u32) per step: uint2 sV reads, uint2 ctxb writes
        #pragma unroll
        for (int rep = 0; rep < 8; ++rep) {
            int i2 = rep * 256 + tid;           // t*128 + cu, cu = uint2 col index
            int tt = i2 >> 7, cu = i2 & 127;
            int h = cu >> 4;                    // (cu*2)>>5; pair never crosses a head
            const float* pr = &s_p[h][tt][0];
            float a0 = 0.f, a1 = 0.f, a2 = 0.f, a3 = 0.f;
            #pragma unroll
            for (int kk = 0; kk < 16; ++kk) {
                uint2 vv = *((const uint2*)&sV[kk][0] + cu);
                float p = pr[kk];
                a0 += p * bfv((u16)(vv.x & 0xffff));
                a1 += p * bfv((u16)(vv.x >> 16));
                a2 += p * bfv((u16)(vv.y & 0xffff));
                a3 += p * bfv((u16)(vv.y >> 16));
            }
            uint2 o;
            o.x = (u32)f2bf(a0) | ((u32)f2bf(a1) << 16);
            o.y = (u32)f2bf(a2) | ((u32)f2bf(a3) << 16);
            *(uint2*)((u32*)(ctxb + ((size_t)bm_l * T_ + tt) * D_) + cu * 2) = o;
        }
    }
}

// ============ fused self-attention + combine + si, one block per (n,h) ==============
__global__ __launch_bounds__(256) void siatt_kernel(
    const float* __restrict__ xemb, const float* __restrict__ att_sum,
    const float* __restrict__ attf, u16* __restrict__ sib)
{
    __shared__ float sX[16][516];
    __shared__ float sS[16][17];
    __shared__ float sA[16][17];
    int n = blockIdx.x >> 3, h = blockIdx.x & 7;
    int tid = threadIdx.x;
    int t = tid >> 4, ch = (tid & 15) * 32;
    const float* src = xemb + ((size_t)n * T_ + t) * D_;
    #pragma unroll
    for (int c = 0; c < 8; ++c)
        *(float4*)&sX[t][ch + c * 4] = *(const float4*)(src + ch + c * 4);
    __syncthreads();
    int q = tid >> 4, k = tid & 15;
    {
        float acc = 0.f;
        for (int d4 = 0; d4 < D_ / 4; ++d4) {
            float4 xq = *(const float4*)&sX[q][d4 * 4];
            float4 xk = *(const float4*)&sX[k][d4 * 4];
            acc += xq.x * xk.x;
            acc += xq.y * xk.y;
            acc += xq.z * xk.z;
            acc += xq.w * xk.w;
        }
        sS[q][k] = acc * 0.04419417382415922f;
    }
    __syncthreads();
    if (tid < T_) {
        float mx = -3.4e38f;
        #pragma unroll
        for (int kk = 0; kk < 16; ++kk) mx = fmaxf(mx, sS[tid][kk]);
        float e[16], s = 0.f;
        #pragma unroll
        for (int kk = 0; kk < 16; ++kk) { e[kk] = expf(sS[tid][kk] - mx); s += e[kk]; }
        float inv = 1.0f / s;
        #pragma unroll
        for (int kk = 0; kk < 16; ++kk) sS[tid][kk] = e[kk] * inv;
    }
    __syncthreads();
    float f = attf[0] * (1.0f / 32.0f);
    sA[q][k] = sS[q][k] + f * att_sum[((size_t)n * H_ + h) * 256 + q * 16 + k];
    __syncthreads();
    #pragma unroll
    for (int rep = 0; rep < 16; ++rep) {
        int i2 = rep * 256 + tid;          // q*256 + d2
        int qq = i2 >> 8, d2 = (i2 & 255) * 2;
        const float* ar = &sA[qq][0];
        float a0 = 0.f, a1 = 0.f;
        #pragma unroll
        for (int tt = 0; tt < 16; ++tt) {
            float p = ar[tt];
            a0 += p * sX[tt][d2];
            a1 += p * sX[tt][d2 + 1];
        }
        u32 o = (u32)f2bf(a0) | ((u32)f2bf(a1) << 16);
        *((u32*)(sib + (size_t)n * T_ * 4096 + (size_t)qq * 4096 + h * 512) + (d2 >> 1)) = o;
    }
}

// ---------------- positional encoding ------------------------------------------------
__global__ void pe_kernel(float* pe) {
    int i = blockIdx.x * blockDim.x + threadIdx.x;
    if (i >= T_ * 256) return;
    int t = i >> 8, j = i & 255;
    float dv = (float)pow(10000.0, (double)j / 256.0);
    float a = (float)t * dv;
    double ad = (double)a;
    pe[t * D_ + 2 * j]     = (float)sin(ad);
    pe[t * D_ + 2 * j + 1] = (float)cos(ad);
}

// ---------------- x features + embed (r10: row-per-wave, float4 stores) --------------
__global__ __launch_bounds__(256) void xemb_kernel(
    const float* __restrict__ x, const float* __restrict__ Wx,
    const float* __restrict__ bx, const float* __restrict__ pe,
    float* __restrict__ xemb) {
    int row = blockIdx.x * 4 + (threadIdx.x >> 6);   // t*N + n
    if (row >= T_ * N_) return;
    int lane = threadIdx.x & 63;
    int t = row / N_, n = row % N_;
    float x0 = x[row * 6 + 0], x1 = x[row * 6 + 1];
    float x2 = x[row * 6 + 2], x3 = x[row * 6 + 3];
    float x4 = x[row * 6 + 4], x5 = x[row * 6 + 5];
    float vel = sqrtf(x2 * x2 + x3 * x3);
    float ang = atanf(x5 / x4);
    float f0 = ntn(x0), f1 = ntn(x1), f2 = ntn(vel), f3 = ntn(ang);
    int d0 = lane * 8;
    float o[8];
    #pragma unroll
    for (int r = 0; r < 8; ++r) {
        int d = d0 + r;
        o[r] = f0 * Wx[0 * D_ + d] + f1 * Wx[1 * D_ + d]
             + f2 * Wx[2 * D_ + d] + f3 * Wx[3 * D_ + d]
             + bx[d] + pe[t * D_ + d];
    }
    float* dst = xemb + ((size_t)n * T_ + t) * D_ + d0;
    float4 w0 = {o[0], o[1], o[2], o[3]};
    float4 w1 = {o[4], o[5], o[6], o[7]};
    *(float4*)dst = w0;
    *(float4*)(dst + 4) = w1;
}

// ---------------- neighbor features + mask -------------------------------------------
__global__ void nbr_kernel(const float* x, const float* nbr, float* nf, float* maskf) {
    int idx = blockIdx.x * blockDim.x + threadIdx.x;   // t*N*NN + n*NN + m
    if (idx >= T_ * N_ * NN_) return;
    int m = idx % NN_;
    int tn = idx / NN_;
    int n = tn % N_, t = tn / N_;
    float px = x[((size_t)t * N_ + n) * 6 + 0];
    float py = x[((size_t)t * N_ + n) * 6 + 1];
    float vx, vy;
    if (t == 0) {
        vx = x[((size_t)1 * N_ + n) * 6 + 2];
        vy = x[((size_t)1 * N_ + n) * 6 + 3];
    } else {
        vx = px - x[((size_t)(t - 1) * N_ + n) * 6 + 0];
        vy = py - x[((size_t)(t - 1) * N_ + n) * 6 + 1];
    }
    float nx  = nbr[(size_t)idx * 4 + 0], ny  = nbr[(size_t)idx * 4 + 1];
    float nvx = nbr[(size_t)idx * 4 + 2], nvy = nbr[(size_t)idx * 4 + 3];
    float dpx = nx - px, dpy = ny - py;
    float dvx = nvx - vx, dvy = nvy - vy;
    float dist = sqrtf(dpx * dpx + dpy * dpy);
    maskf[((size_t)n * NN_ + m) * T_ + t] = (dist <= 2.0f) ? 1.0f : 0.0f;
    float vn = sqrtf(vx * vx + vy * vy);
    float bearing = (dpx * vx + dpy * vy) / (dist * vn);
    if (isnan(bearing)) bearing = 0.0f;
    float dvn = sqrtf(dvx * dvx + dvy * dvy);
    float tau = -(dpx * dvx + dpy * dvy) / dvn;
    if (isnan(tau)) tau = 0.0f;
    tau = fminf(fmaxf(tau, 0.0f), 7.0f);
    float mx_ = dpx + tau * dvx, my_ = dpy + tau * dvy;
    float mpd = sqrtf(mx_ * mx_ + my_ * my_);
    nf[(size_t)idx * 3 + 0] = ntn(dist);
    nf[(size_t)idx * 3 + 1] = ntn(bearing);
    nf[(size_t)idx * 3 + 2] = ntn(mpd);
}

// ---------------- neighbor embed (r10: row-per-wave, short8 store) -------------------
__global__ __launch_bounds__(256) void nemb_kernel(
    const float* __restrict__ nf, const float* __restrict__ Wn,
    const float* __restrict__ bn, const float* __restrict__ pe,
    u16* __restrict__ Ab) {
    int row = blockIdx.x * 4 + (threadIdx.x >> 6);   // (b*NN+m)*T + t
    if (row >= N_ * NN_ * T_) return;
    int lane = threadIdx.x & 63;
    int t = row % T_;
    int bm = row / T_;
    int m = bm % NN_, b = bm / NN_;
    size_t nfrow = (((size_t)t * N_ + b) * NN_ + m) * 3;
    float f0 = nf[nfrow], f1 = nf[nfrow + 1], f2 = nf[nfrow + 2];
    int d0 = lane * 8;
    short8 w;
    #pragma unroll
    for (int r = 0; r < 8; ++r) {
        int d = d0 + r;
        float v = f0 * Wn[d] + f1 * Wn[D_ + d] + f2 * Wn[2 * D_ + d]
                + bn[d] + pe[t * D_ + d];
        w[r] = (short)f2bf(v);
    }
    *(short8*)(Ab + (size_t)row * D_ + d0) = w;
}

// ---------------- LayerNorm, one wave per row; input f32 or bf16; dual out -----------
template<int INBF>
__global__ __launch_bounds__(256) void ln_kernel(
    const void* X, const float* g, const float* b, float* outF, u16* outB, int nrows) {
    int row = blockIdx.x * 4 + (threadIdx.x >> 6);
    if (row >= nrows) return;
    int lane = threadIdx.x & 63;
    int d0 = lane * 8;
    float v[8];
    if (INBF) {
        short8 x8 = *(const short8*)((const u16*)X + (size_t)row * D_ + d0);
        #pragma unroll
        for (int r = 0; r < 8; ++r) v[r] = bfv((u16)x8[r]);
    } else {
        float4 a = *(const float4*)((const float*)X + (size_t)row * D_ + d0);
        float4 c = *(const float4*)((const float*)X + (size_t)row * D_ + d0 + 4);
        v[0] = a.x; v[1] = a.y; v[2] = a.z; v[3] = a.w;
        v[4] = c.x; v[5] = c.y; v[6] = c.z; v[7] = c.w;
    }
    float s = 0.f;
    #pragma unroll
    for (int r = 0; r < 8; ++r) s += v[r];
    s = wave_sum(s);
    float mean = s * (1.0f / 512.0f);
    float vs = 0.f;
    #pragma unroll
    for (int r = 0; r < 8; ++r) { float d = v[r] - mean; vs += d * d; }
    vs = wave_sum(vs);
    float rstd = rsqrtf(vs * (1.0f / 512.0f) + 1e-5f);
    float4 g0 = *(const float4*)&g[d0], g1 = *(const float4*)&g[d0 + 4];
    float4 b0 = *(const float4*)&b[d0], b1 = *(const float4*)&b[d0 + 4];
    float o[8];
    o[0] = (v[0] - mean) * rstd * g0.x + b0.x;
    o[1] = (v[1] - mean) * rstd * g0.y + b0.y;
    o[2] = (v[2] - mean) * rstd * g0.z + b0.z;
    o[3] = (v[3] - mean) * rstd * g0.w + b0.w;
    o[4] = (v[4] - mean) * rstd * g1.x + b1.x;
    o[5] = (v[5] - mean) * rstd * g1.y + b1.y;
    o[6] = (v[6] - mean) * rstd * g1.z + b1.z;
    o[7] = (v[7] - mean) * rstd * g1.w + b1.w;
    if (outF) {
        float4 w0 = {o[0], o[1], o[2], o[3]};
        float4 w1 = {o[4], o[5], o[6], o[7]};
        *(float4*)(outF + (size_t)row * D_ + d0) = w0;
        *(float4*)(outF + (size_t)row * D_ + d0 + 4) = w1;
    }
    if (outB) {
        short8 w;
        #pragma unroll
        for (int r = 0; r < 8; ++r) w[r] = (short)f2bf(o[r]);
        *(short8*)(outB + (size_t)row * D_ + d0) = w;
    }
}

// ---------------- prediction head + broadcast fused (f32 out) ------------------------
__global__ __launch_bounds__(256) void predbcast_kernel(
    const float* __restrict__ xemb, const float* __restrict__ Wp,
    const float* __restrict__ bp, float* __restrict__ out) {
    int nt = blockIdx.x * blockDim.x + threadIdx.x;    // n*T + t
    if (nt >= N_ * T_) return;
    int n = nt / T_, t = nt % T_;
    float a0 = bp[0], a1 = bp[1];
    const float* xr = xemb + (size_t)nt * D_;
    for (int j = 0; j < D_; j += 4) {
        float4 xv = *(const float4*)&xr[j];
        float4 w0 = *(const float4*)&Wp[(size_t)j * 2];      // W[j][0..1], W[j+1][0..1]
        float4 w1 = *(const float4*)&Wp[(size_t)j * 2 + 4];  // W[j+2][0..1], W[j+3][0..1]
        a0 += xv.x * w0.x; a1 += xv.x * w0.y;
        a0 += xv.y * w0.z; a1 += xv.y * w0.w;
        a0 += xv.z * w1.x; a1 += xv.z * w1.y;
        a0 += xv.w * w1.z; a1 += xv.w * w1.w;
    }
    #pragma unroll
    for (int p = 0; p < NPRED_; ++p) {
        size_t o = (((size_t)p * T_ + t) * N_ + n) * 2;
        out[o]     = a0;
        out[o + 1] = a1;
    }
}

extern "C" void kernel_launch(void* const* d_in, const int* in_sizes, int n_in,
                              void* d_out, int out_size, void* d_ws, size_t ws_size,
                              hipStream_t stream) {
    (void)in_sizes; (void)n_in; (void)out_size; (void)ws_size;

    const float* x    = (const float*)d_in[0];
    const float* nbr  = (const float*)d_in[1];
    const float* attf = (const float*)d_in[2];
    const float* Wx   = (const float*)d_in[3];
    const float* bx   = (const float*)d_in[4];
    const float* Wn   = (const float*)d_in[5];
    const float* bn   = (const float*)d_in[6];
    const float* Wp   = (const float*)d_in[7];
    const float* bp   = (const float*)d_in[8];
    const float* WQ   = (const float*)d_in[9];
    const float* WK   = (const float*)d_in[10];
    const float* WV   = (const float*)d_in[11];
    const float* Wfc  = (const float*)d_in[12];
    const float* mlng = (const float*)d_in[13];
    const float* mlnb = (const float*)d_in[14];
    const float* WSI  = (const float*)d_in[15];
    const float* fsw1 = (const float*)d_in[16];
    const float* fsw2 = (const float*)d_in[17];
    const float* fsg  = (const float*)d_in[18];
    const float* fsb  = (const float*)d_in[19];
    const float* fiw1 = (const float*)d_in[20];
    const float* fiw2 = (const float*)d_in[21];
    const float* fig  = (const float*)d_in[22];
    const float* fib  = (const float*)d_in[23];

    char* w = (char*)d_ws;
    size_t off = 0;
    auto alloc = [&](size_t bytes) -> void* {
        void* p = w + off;
        off = (off + bytes + 255) & ~(size_t)255;
        return p;
    };
    const size_t MiB = 1024 * 1024;

    const int BM = N_ * NN_;          // 2048 (b,m) pairs
    const int ROWS_I = BM * T_;       // 32768 neighbor rows
    const int CB = 1024;              // bm per chunk (NCH=2, l=0 only)
    const int RC = CB * T_;           // 16384 rows per chunk
    const int NCH = ROWS_I / RC;      // 2

    float* pe      = (float*)alloc((size_t)T_ * D_ * 4);
    float* xemb    = (float*)alloc((size_t)N_ * T_ * D_ * 4);
    float* nf      = (float*)alloc((size_t)T_ * N_ * NN_ * 3 * 4);
    float* maskf   = (float*)alloc((size_t)BM * T_ * 4);
    u16*   Ab      = (u16*)alloc((size_t)ROWS_I * D_ * 2);     // n_emb bf16  32 MiB
    u16* tQKV[2], *tWSI[2], *tfs1[2], *tfs2[2];
    for (int l = 0; l < 2; ++l) {
        tQKV[l] = (u16*)alloc((size_t)1536 * 512 * 2);
        tWSI[l] = (u16*)alloc((size_t)512 * 4096 * 2);
        tfs1[l] = (u16*)alloc((size_t)2048 * 512 * 2);
        tfs2[l] = (u16*)alloc((size_t)512 * 2048 * 2);
    }
    u16* tWfc = (u16*)alloc((size_t)512 * 512 * 2);
    u16* tfi1 = (u16*)alloc((size_t)2048 * 512 * 2);
    u16* tfi2 = (u16*)alloc((size_t)512 * 2048 * 2);
    // scratch union: l0 chunk: QKVb 48 + ctxb 16 | hid 64 ; l1: QK full 64 MiB
    // ffs phase: hid(ffs) 4 MiB @ SCR+0, split-K partials 16 MiB @ SCR+16MiB
    char* SCR  = (char*)alloc(64 * MiB);
    u16*   QKVb = (u16*)SCR;
    u16*   ctxb = (u16*)(SCR + 48 * MiB);
    u16*   hid  = (u16*)SCR;
    float* Pk   = (float*)(SCR + 16 * MiB);
    u16*   BbA    = (u16*)alloc((size_t)RC * D_ * 2);  // pre-LN bf16 chunk    16 MiB
    u16*   Bb_res = (u16*)alloc((size_t)RC * D_ * 2);  // res_inter bf16       16 MiB
    float* att_sum = (float*)alloc((size_t)N_ * H_ * 256 * 4);
    u16*   sib     = (u16*)alloc((size_t)N_ * T_ * 4096 * 2);  // 8 MiB
    float* xnew    = (float*)alloc((size_t)N_ * T_ * D_ * 4);
    u16*   xnb     = (u16*)alloc((size_t)N_ * T_ * D_ * 2);
    // total ~170 MiB

    // ---- batched weight conversion: 14 jobs, one launch ----
    WJobs jobs;
    int ntiles = 0;
    auto addJob = [&](int idx, const float* src, u16* dst, int K, int N) {
        jobs.j[idx] = {src, dst, K, N, ntiles};
        ntiles += (N >> 5) * (K >> 5);
    };
    addJob(0,  WQ,                            tQKV[0],              512, 512);
    addJob(1,  WK,                            tQKV[0] + 512 * 512,  512, 512);
    addJob(2,  WV,                            tQKV[0] + 1024 * 512, 512, 512);   // dead at l=1
    addJob(3,  WQ + (size_t)512 * 512,        tQKV[1],              512, 512);
    addJob(4,  WK + (size_t)512 * 512,        tQKV[1] + 512 * 512,  512, 512);
    addJob(5,  Wfc,                           tWfc,                 512, 512);
    addJob(6,  WSI,                           tWSI[0],              4096, 512);
    addJob(7,  WSI + (size_t)4096 * 512,      tWSI[1],              4096, 512);
    addJob(8,  fsw1,                          tfs1[0],              512, 2048);
    addJob(9,  fsw1 + (size_t)512 * 2048,     tfs1[1],              512, 2048);
    addJob(10, fsw2,                          tfs2[0],              2048, 512);
    addJob(11, fsw2 + (size_t)2048 * 512,     tfs2[1],              2048, 512);
    addJob(12, fiw1,                          tfi1,                 512, 2048);
    addJob(13, fiw2,                          tfi2,                 2048, 512);
    wconv_all<<<ntiles, 256, 0, stream>>>(jobs, ntiles);

    pe_kernel<<<16, 256, 0, stream>>>(pe);
    xemb_kernel<<<(T_ * N_) / 4, 256, 0, stream>>>(x, Wx, bx, pe, xemb);
    nbr_kernel<<<(T_ * N_ * NN_ + 255) / 256, 256, 0, stream>>>(x, nbr, nf, maskf);
    nemb_kernel<<<(BM * T_) / 4, 256, 0, stream>>>(nf, Wn, bn, pe, Ab);

    for (int l = 0; l < L_; ++l) {
        hipMemsetAsync(att_sum, 0, (size_t)N_ * H_ * 256 * 4, stream);
        if (l == 0) {
            for (int c = 0; c < NCH; ++c) {
                u16* Acb = Ab + (size_t)c * RC * D_;
                // QKV fused GEMM: N=1536 (1536 blocks = 3 exact rounds @2/CU)
                gemm_ct<0, 0, 1><<<dim3(12, RC / 128), 256, 0, stream>>>(
                    Acb, tQKV[0], nullptr, QKVb, nullptr, 512, 1536);
                attn_fused_kernel<1, 1536><<<CB, 256, 0, stream>>>(
                    QKVb, maskf, c * CB, att_sum, ctxb);
                // fc + residual(n_emb bf16) -> pre-LN bf16 (512 blocks = 1 round)
                gemm_ct<3, 0, 1><<<dim3(4, RC / 128), 256, 0, stream>>>(
                    ctxb, tWfc, nullptr, BbA, Acb, 512, 512);
                ln_kernel<1><<<RC / 4, 256, 0, stream>>>(
                    BbA, mlng, mlnb, nullptr, Bb_res, RC);   // res_inter bf16
                // ffi1 relu: N=2048 (2048 blocks = 4 exact rounds)
                gemm_ct<1, 0, 1><<<dim3(16, RC / 128), 256, 0, stream>>>(
                    Bb_res, tfi1, nullptr, hid, nullptr, 512, 2048);
                // ffi2 + residual(res_inter bf16) -> pre-LN bf16 (512 blocks)
                gemm_ct<3, 0, 1><<<dim3(4, RC / 128), 256, 0, stream>>>(
                    hid, tfi2, nullptr, BbA, Bb_res, 2048, 512);
                ln_kernel<1><<<RC / 4, 256, 0, stream>>>(
                    BbA, fig, fib, nullptr, Acb, RC);        // new n_emb (bf16)
            }
        } else {
            // l=1: unchunked QK (N=1024, ldc=1024; 64 MiB = SCR): 2048 blocks
            gemm_ct<0, 0, 1><<<dim3(8, ROWS_I / 128), 256, 0, stream>>>(
                Ab, tQKV[1], nullptr, QKVb, nullptr, 512, 1024);
            attn_fused_kernel<0, 1024><<<BM, 256, 0, stream>>>(
                QKVb, maskf, 0, att_sum, nullptr);
        }

        // ---- self-attention + si + ffs (updates xemb; split-K, f32 chain) ----
        siatt_kernel<<<N_ * H_, 256, 0, stream>>>(xemb, att_sum, attf, sib);
        // xnew/xnb = sib @ tWSI (M=1024, N=512, K=4096): NS=8 -> 256 blocks, Kc=512
        gemm_ks<8><<<dim3(4, 8, 8), 256, 0, stream>>>(sib, tWSI[l], Pk, 4096, 512);
        ksum_kernel<8, 0, 1, 1><<<512, 256, 0, stream>>>(
            Pk, nullptr, xnew, xnb, 1024 * 512);
        // hid = relu(xnb @ tfs1) (N=2048, K=512): NS=2 -> 256 blocks, Kc=256
        gemm_ks<2><<<dim3(16, 8, 2), 256, 0, stream>>>(xnb, tfs1[l], Pk, 512, 2048);
        ksum_kernel<2, 1, 0, 1><<<2048, 256, 0, stream>>>(
            Pk, nullptr, nullptr, hid, 1024 * 2048);
        // xemb = (hid @ tfs2) + xnew (N=512, K=2048): NS=8 -> 256 blocks, Kc=256
        gemm_ks<8><<<dim3(4, 8, 8), 256, 0, stream>>>(hid, tfs2[l], Pk, 2048, 512);
        ksum_kernel<8, 2, 1, 0><<<512, 256, 0, stream>>>(
            Pk, xnew, xemb, nullptr, 1024 * 512);
        ln_kernel<0><<<(N_ * T_) / 4, 256, 0, stream>>>(
            xemb, fsg + l * D_, fsb + l * D_, xemb, nullptr, N_ * T_);
    }

    predbcast_kernel<<<(N_ * T_ + 255) / 256, 256, 0, stream>>>(
        xemb, Wp, bp, (float*)d_out);
}

// Round 11
// 723.803 us; speedup vs baseline: 1.1806x; 1.0403x over previous
//
#include <hip/hip_runtime.h>
#include <math.h>

// DTYPE COMMITMENTS (evidence-backed): inputs f32, output f32 (rounds 4-14 PASS).
// WS BUDGET: <= ~210 MB decimal; this build ~170 MiB (+0: partials alias SCR).
// r11: launch-count + traffic reduction in ffs chain. fs1 -> direct gemm_ct (r7
// numerics, no split-K); fs2 ksum+LN fused into ksln_kernel (element-wise
// bit-identical to ksum->ln). GEMMs frozen at r8 state; 8-phase abandoned (0/4).

#define T_ 16
#define N_ 64
#define NN_ 32
#define D_ 512
#define H_ 8
#define DK_ 64
#define DFF_ 2048
#define L_ 2
#define NPRED_ 20

typedef unsigned short u16;
typedef unsigned int u32;
typedef __attribute__((ext_vector_type(8))) short short8;
typedef __attribute__((ext_vector_type(4))) float f32x4;

__device__ __forceinline__ u16 f2bf(float f) {
    u32 u = __float_as_uint(f);
    u32 r = u + 0x7fffu + ((u >> 16) & 1u);
    return (u16)(r >> 16);
}
__device__ __forceinline__ float bfv(u16 v) {
    return __uint_as_float(((u32)v) << 16);
}
__device__ __forceinline__ float ntn(float v) {
    if (isnan(v)) return 0.0f;
    if (isinf(v)) return v > 0.0f ? 3.4028234663852886e38f : -3.4028234663852886e38f;
    return v;
}
__device__ __forceinline__ float wave_sum(float v) {
    #pragma unroll
    for (int o = 32; o > 0; o >>= 1) v += __shfl_xor(v, o, 64);
    return v;
}
// async 16B HBM->LDS: writes ldsbase + lane*16 (wave-uniform base, per-lane gptr)
__device__ __forceinline__ void gload_lds(const u16* g, u16* l) {
    __builtin_amdgcn_global_load_lds(
        (const __attribute__((address_space(1))) u32*)g,
        (__attribute__((address_space(3))) u32*)l, 16, 0, 0);
}

// ============ batched weight convert+transpose: 14 jobs in ONE launch ===============
struct WJob { const float* src; u16* dst; int K; int N; int t0; };
struct WJobs { WJob j[14]; };
__global__ __launch_bounds__(256) void wconv_all(WJobs jobs, int ntiles) {
    int bid = blockIdx.x;
    if (bid >= ntiles) return;
    int ji = 0;
    #pragma unroll 1
    for (int i = 1; i < 14; ++i) if (bid >= jobs.j[i].t0) ji = i;
    const float* in = jobs.j[ji].src;
    u16* out = jobs.j[ji].dst;
    int K = jobs.j[ji].K, N = jobs.j[ji].N;
    int lt = bid - jobs.j[ji].t0;
    int ntx = N >> 5;
    int nb = (lt % ntx) * 32, kb = (lt / ntx) * 32;
    __shared__ float tile[32][33];
    int tx = threadIdx.x & 31, ty = threadIdx.x >> 5;
    #pragma unroll
    for (int r = ty; r < 32; r += 8)
        tile[r][tx] = in[(size_t)(kb + r) * N + nb + tx];
    __syncthreads();
    #pragma unroll
    for (int r = ty; r < 32; r += 8)
        out[(size_t)(nb + r) * K + kb + tx] = f2bf(tile[tx][r]);
}

// ============ counted-pipeline GEMM: 128x128, BK=64, 2 barriers/tile (r4 best) ======
// Per K-tile: (1) issue 8 gload_lds for tile t+1 into the other LDS buffer FIRST;
// (2) s_waitcnt vmcnt(8) -- counted: the 8 just-issued loads stay IN FLIGHT, only
// tile t's loads (issued one full tile ago) must have landed; (3) one rendezvous
// s_barrier; (4) full 32-MFMA compute, setprio-wrapped, no intra-tile barriers;
// (5) one end barrier protecting the buffer restaged next iteration. vmcnt(0) only
// at the last tile. LDS 64KiB -> 2 blocks/CU. r9 XOR swizzle (0 conflicts).
// Requires M%128==0, N%128==0, K%64==0 (K>=128), gridDim.y%8==0 (XCD remap).
template<int EPI, int WF32, int WBF16>
__global__ __launch_bounds__(256, 2) void gemm_ct(
    const u16* __restrict__ Ab, const u16* __restrict__ Btb,
    float* __restrict__ Cf, u16* __restrict__ Cb, const void* __restrict__ Rg,
    int K, int ldc)
{
    __shared__ __align__(16) u16 As[2][128][64];
    __shared__ __align__(16) u16 Bs[2][128][64];
    int tid = threadIdx.x;
    int lane = tid & 63, wave = tid >> 6;       // 4 waves: 2M x 2N
    int quad = lane >> 4, l16 = lane & 15;
    int wm = (wave >> 1) * 64, wn = (wave & 1) * 64;

    int gx = gridDim.x, gy = gridDim.y;
    int id = blockIdx.y * gx + blockIdx.x;
    int xcd = id & 7, slot = id >> 3;
    int bx = slot % gx;
    int by = xcd * (gy >> 3) + slot / gx;
    size_t row0 = (size_t)by * 128;
    size_t col0 = (size_t)bx * 128;

    f32x4 acc[4][4];
    #pragma unroll
    for (int i = 0; i < 4; ++i)
        #pragma unroll
        for (int j = 0; j < 4; ++j)
            acc[i][j] = (f32x4){0.f, 0.f, 0.f, 0.f};

    // staging swizzle (r9-verified): physical 16B chunk p of row r holds logical
    // chunk p ^ (r&7)
    int srow = lane >> 3;
    int c8 = (lane & 7) ^ srow;
    int h8 = l16 & 7;
    size_t aoff[4], boff[4];
    #pragma unroll
    for (int it = 0; it < 4; ++it) {
        aoff[it] = (row0 + (size_t)(wave + it * 4) * 8 + srow) * (size_t)K + c8 * 8;
        boff[it] = (col0 + (size_t)(wave + it * 4) * 8 + srow) * (size_t)K + c8 * 8;
    }

    int nt = K >> 6;
    // prologue: stage tile 0 -> buf 0 (8 loads in flight, no wait)
    #pragma unroll
    for (int it = 0; it < 4; ++it)
        gload_lds(Ab + aoff[it], &As[0][(wave + it * 4) * 8][0]);
    #pragma unroll
    for (int it = 0; it < 4; ++it)
        gload_lds(Btb + boff[it], &Bs[0][(wave + it * 4) * 8][0]);

    #pragma unroll 1
    for (int t = 0; t < nt; ++t) {
        int cur = t & 1;
        if (t + 1 < nt) {
            // stage tile t+1 into other buffer (freed by iter t-1's end barrier)
            size_t ko = (size_t)(t + 1) * 64;
            #pragma unroll
            for (int it = 0; it < 4; ++it)
                gload_lds(Ab + aoff[it] + ko, &As[cur ^ 1][(wave + it * 4) * 8][0]);
            #pragma unroll
            for (int it = 0; it < 4; ++it)
                gload_lds(Btb + boff[it] + ko, &Bs[cur ^ 1][(wave + it * 4) * 8][0]);
            __builtin_amdgcn_sched_barrier(0);
            asm volatile("s_waitcnt vmcnt(8)" ::: "memory");   // tile t landed; t+1 in flight
        } else {
            __builtin_amdgcn_sched_barrier(0);
            asm volatile("s_waitcnt vmcnt(0)" ::: "memory");   // final tile only
        }
        __builtin_amdgcn_sched_barrier(0);
        __builtin_amdgcn_s_barrier();                          // rendezvous: tile t staged
        __builtin_amdgcn_sched_barrier(0);
        __builtin_amdgcn_s_setprio(1);
        #pragma unroll
        for (int kh = 0; kh < 2; ++kh) {
            int coff = ((kh * 4 + quad) ^ h8) * 8;
            short8 af[4], bf[4];
            #pragma unroll
            for (int j = 0; j < 4; ++j)
                bf[j] = *(short8*)&Bs[cur][wn + j * 16 + l16][coff];
            #pragma unroll
            for (int i = 0; i < 4; ++i)
                af[i] = *(short8*)&As[cur][wm + i * 16 + l16][coff];
            #pragma unroll
            for (int i = 0; i < 4; ++i)
                #pragma unroll
                for (int j = 0; j < 4; ++j)
                    acc[i][j] = __builtin_amdgcn_mfma_f32_16x16x32_bf16(
                        af[i], bf[j], acc[i][j], 0, 0, 0);
        }
        __builtin_amdgcn_s_setprio(0);
        __builtin_amdgcn_sched_barrier(0);                     // reads done before barrier
        __builtin_amdgcn_s_barrier();                          // frees buf[cur] for restage
    }

    // C/D layout (on-target verified): col = lane&15, row = quad*4 + reg
    #pragma unroll
    for (int i = 0; i < 4; ++i)
        #pragma unroll
        for (int j = 0; j < 4; ++j)
            #pragma unroll
            for (int reg = 0; reg < 4; ++reg) {
                size_t row = row0 + wm + i * 16 + quad * 4 + reg;
                size_t col = col0 + wn + j * 16 + l16;
                float v = acc[i][j][reg];
                if (EPI == 2) v += ((const float*)Rg)[row * (size_t)ldc + col];
                if (EPI == 3) v += bfv(((const u16*)Rg)[row * (size_t)ldc + col]);
                if (EPI == 1) v = fmaxf(v, 0.f);
                if (WF32)  Cf[row * (size_t)ldc + col] = v;
                if (WBF16) Cb[row * (size_t)ldc + col] = f2bf(v);
            }
}

// ============ split-K GEMM for small-M (ffs chain): gemm_ct schedule + z-split ======
// grid (N/128, M/128=8, NS); block z computes K-range [z*Kc,(z+1)*Kc), Kc=K/NS
// (Kc%64==0, Kc>=128), writes f32 partial to Pf + z*M*ldc. No atomics. Identical
// pipeline/swizzle to gemm_ct (refcheck'd r4-r10).
template<int NS>
__global__ __launch_bounds__(256, 2) void gemm_ks(
    const u16* __restrict__ Ab, const u16* __restrict__ Btb,
    float* __restrict__ Pf, int K, int ldc)
{
    __shared__ __align__(16) u16 As[2][128][64];
    __shared__ __align__(16) u16 Bs[2][128][64];
    int tid = threadIdx.x;
    int lane = tid & 63, wave = tid >> 6;
    int quad = lane >> 4, l16 = lane & 15;
    int wm = (wave >> 1) * 64, wn = (wave & 1) * 64;

    int gx = gridDim.x, gy = gridDim.y;
    int id = blockIdx.y * gx + blockIdx.x;
    int xcd = id & 7, slot = id >> 3;
    int bx = slot % gx;
    int by = xcd * (gy >> 3) + slot / gx;
    int z = blockIdx.z;
    int Kc = K / NS;
    size_t row0 = (size_t)by * 128;
    size_t col0 = (size_t)bx * 128;
    size_t M = (size_t)gy * 128;

    f32x4 acc[4][4];
    #pragma unroll
    for (int i = 0; i < 4; ++i)
        #pragma unroll
        for (int j = 0; j < 4; ++j)
            acc[i][j] = (f32x4){0.f, 0.f, 0.f, 0.f};

    int srow = lane >> 3;
    int c8 = (lane & 7) ^ srow;
    int h8 = l16 & 7;
    size_t kbase = (size_t)z * Kc;
    size_t aoff[4], boff[4];
    #pragma unroll
    for (int it = 0; it < 4; ++it) {
        aoff[it] = (row0 + (size_t)(wave + it * 4) * 8 + srow) * (size_t)K + kbase + c8 * 8;
        boff[it] = (col0 + (size_t)(wave + it * 4) * 8 + srow) * (size_t)K + kbase + c8 * 8;
    }

    int nt = Kc >> 6;
    #pragma unroll
    for (int it = 0; it < 4; ++it)
        gload_lds(Ab + aoff[it], &As[0][(wave + it * 4) * 8][0]);
    #pragma unroll
    for (int it = 0; it < 4; ++it)
        gload_lds(Btb + boff[it], &Bs[0][(wave + it * 4) * 8][0]);

    #pragma unroll 1
    for (int t = 0; t < nt; ++t) {
        int cur = t & 1;
        if (t + 1 < nt) {
            size_t ko = (size_t)(t + 1) * 64;
            #pragma unroll
            for (int it = 0; it < 4; ++it)
                gload_lds(Ab + aoff[it] + ko, &As[cur ^ 1][(wave + it * 4) * 8][0]);
            #pragma unroll
            for (int it = 0; it < 4; ++it)
                gload_lds(Btb + boff[it] + ko, &Bs[cur ^ 1][(wave + it * 4) * 8][0]);
            __builtin_amdgcn_sched_barrier(0);
            asm volatile("s_waitcnt vmcnt(8)" ::: "memory");
        } else {
            __builtin_amdgcn_sched_barrier(0);
            asm volatile("s_waitcnt vmcnt(0)" ::: "memory");
        }
        __builtin_amdgcn_sched_barrier(0);
        __builtin_amdgcn_s_barrier();
        __builtin_amdgcn_sched_barrier(0);
        __builtin_amdgcn_s_setprio(1);
        #pragma unroll
        for (int kh = 0; kh < 2; ++kh) {
            int coff = ((kh * 4 + quad) ^ h8) * 8;
            short8 af[4], bf[4];
            #pragma unroll
            for (int j = 0; j < 4; ++j)
                bf[j] = *(short8*)&Bs[cur][wn + j * 16 + l16][coff];
            #pragma unroll
            for (int i = 0; i < 4; ++i)
                af[i] = *(short8*)&As[cur][wm + i * 16 + l16][coff];
            #pragma unroll
            for (int i = 0; i < 4; ++i)
                #pragma unroll
                for (int j = 0; j < 4; ++j)
                    acc[i][j] = __builtin_amdgcn_mfma_f32_16x16x32_bf16(
                        af[i], bf[j], acc[i][j], 0, 0, 0);
        }
        __builtin_amdgcn_s_setprio(0);
        __builtin_amdgcn_sched_barrier(0);
        __builtin_amdgcn_s_barrier();
    }

    float* P = Pf + (size_t)z * M * (size_t)ldc;
    #pragma unroll
    for (int i = 0; i < 4; ++i)
        #pragma unroll
        for (int j = 0; j < 4; ++j)
            #pragma unroll
            for (int reg = 0; reg < 4; ++reg) {
                size_t row = row0 + wm + i * 16 + quad * 4 + reg;
                size_t col = col0 + wn + j * 16 + l16;
                P[row * (size_t)ldc + col] = acc[i][j][reg];
            }
}

// ---- split-K reduce + epilogue: sum NS f32 partials; EPI 1=relu 2=+res; dual out --
template<int NS, int EPI, int WF32, int WBF16>
__global__ __launch_bounds__(256) void ksum_kernel(
    const float* __restrict__ P, const float* __restrict__ res,
    float* __restrict__ outF, u16* __restrict__ outB, int total)
{
    int i = blockIdx.x * blockDim.x + threadIdx.x;
    size_t o4 = (size_t)i * 4;
    if (o4 >= (size_t)total) return;
    float4 s = *(const float4*)(P + o4);
    #pragma unroll
    for (int p = 1; p < NS; ++p) {
        float4 v = *(const float4*)(P + (size_t)p * total + o4);
        s.x += v.x; s.y += v.y; s.z += v.z; s.w += v.w;
    }
    if (EPI == 2) {
        float4 r = *(const float4*)(res + o4);
        s.x += r.x; s.y += r.y; s.z += r.z; s.w += r.w;
    }
    if (EPI == 1) {
        s.x = fmaxf(s.x, 0.f); s.y = fmaxf(s.y, 0.f);
        s.z = fmaxf(s.z, 0.f); s.w = fmaxf(s.w, 0.f);
    }
    if (WF32) *(float4*)(outF + o4) = s;
    if (WBF16) {
        uint2 w;
        w.x = (u32)f2bf(s.x) | ((u32)f2bf(s.y) << 16);
        w.y = (u32)f2bf(s.z) | ((u32)f2bf(s.w) << 16);
        *(uint2*)(outB + o4) = w;
    }
}

// ---- fused split-K reduce + residual + LayerNorm (r11): wave per row --------------
// Element-wise bit-identical to ksum_kernel<NS,2,...> followed by ln_kernel<0>:
// same partial-sum order (P0 + P1..P7 + res), same LN math. Saves one launch and
// the pre-LN xemb round-trip.
template<int NS>
__global__ __launch_bounds__(256) void ksln_kernel(
    const float* __restrict__ P, const float* __restrict__ res,
    const float* __restrict__ g, const float* __restrict__ b,
    float* __restrict__ outF, int nrows)
{
    int row = blockIdx.x * 4 + (threadIdx.x >> 6);
    if (row >= nrows) return;
    int lane = threadIdx.x & 63;
    int d0 = lane * 8;
    size_t base = (size_t)row * D_ + d0;
    size_t total = (size_t)nrows * D_;
    float v[8];
    {
        float4 a = *(const float4*)(P + base);
        float4 c = *(const float4*)(P + base + 4);
        v[0] = a.x; v[1] = a.y; v[2] = a.z; v[3] = a.w;
        v[4] = c.x; v[5] = c.y; v[6] = c.z; v[7] = c.w;
    }
    #pragma unroll
    for (int p = 1; p < NS; ++p) {
        float4 a = *(const float4*)(P + (size_t)p * total + base);
        float4 c = *(const float4*)(P + (size_t)p * total + base + 4);
        v[0] += a.x; v[1] += a.y; v[2] += a.z; v[3] += a.w;
        v[4] += c.x; v[5] += c.y; v[6] += c.z; v[7] += c.w;
    }
    {
        float4 a = *(const float4*)(res + base);
        float4 c = *(const float4*)(res + base + 4);
        v[0] += a.x; v[1] += a.y; v[2] += a.z; v[3] += a.w;
        v[4] += c.x; v[5] += c.y; v[6] += c.z; v[7] += c.w;
    }
    float s = 0.f;
    #pragma unroll
    for (int r = 0; r < 8; ++r) s += v[r];
    s = wave_sum(s);
    float mean = s * (1.0f / 512.0f);
    float vs = 0.f;
    #pragma unroll
    for (int r = 0; r < 8; ++r) { float d = v[r] - mean; vs += d * d; }
    vs = wave_sum(vs);
    float rstd = rsqrtf(vs * (1.0f / 512.0f) + 1e-5f);
    float4 g0 = *(const float4*)&g[d0], g1 = *(const float4*)&g[d0 + 4];
    float4 b0 = *(const float4*)&b[d0], b1 = *(const float4*)&b[d0 + 4];
    float o[8];
    o[0] = (v[0] - mean) * rstd * g0.x + b0.x;
    o[1] = (v[1] - mean) * rstd * g0.y + b0.y;
    o[2] = (v[2] - mean) * rstd * g0.z + b0.z;
    o[3] = (v[3] - mean) * rstd * g0.w + b0.w;
    o[4] = (v[4] - mean) * rstd * g1.x + b1.x;
    o[5] = (v[5] - mean) * rstd * g1.y + b1.y;
    o[6] = (v[6] - mean) * rstd * g1.z + b1.z;
    o[7] = (v[7] - mean) * rstd * g1.w + b1.w;
    float4 w0 = {o[0], o[1], o[2], o[3]};
    float4 w1 = {o[4], o[5], o[6], o[7]};
    *(float4*)(outF + base) = w0;
    *(float4*)(outF + base + 4) = w1;
}

// ============ fused attention per (b,m): all-heads phases, 3 barriers ===============
// r7: QK^T via MFMA 16x16x32 (verified layout); S stays f32. ctx phase uint2.
template<int CTX, int LD>
__global__ __launch_bounds__(256) void attn_fused_kernel(
    const u16* __restrict__ QKVb, const float* __restrict__ maskf, int bm0,
    float* __restrict__ att_sum, u16* __restrict__ ctxb)
{
    __shared__ __align__(16) u16 sQ[16][520];
    __shared__ __align__(16) u16 sK[16][520];
    __shared__ __align__(16) u16 sV[CTX ? 16 : 1][520];
    __shared__ float s_p[H_][16][17];
    __shared__ float sMask[16];
    int bm_l = blockIdx.x;
    int tid = threadIdx.x;
    int t = tid >> 4, ch = (tid & 15) * 32;
    const u16* base = QKVb + ((size_t)bm_l * T_ + t) * LD;
    #pragma unroll
    for (int c = 0; c < 4; ++c) {
        *(uint4*)&sQ[t][ch + c * 8] = *(const uint4*)(base + ch + c * 8);
        *(uint4*)&sK[t][ch + c * 8] = *(const uint4*)(base + 512 + ch + c * 8);
        if (CTX) *(uint4*)&sV[t][ch + c * 8] = *(const uint4*)(base + 1024 + ch + c * 8);
    }
    if (tid < 16) sMask[tid] = maskf[(size_t)(bm0 + bm_l) * T_ + tid];
    __syncthreads();

    int b = (bm0 + bm_l) >> 5;                  // bm = b*NN + m
    int lane = tid & 63, wid = tid >> 6;
    int l16 = lane & 15, quad = lane >> 4;

    // QK^T: per wave heads {wid, wid+4}; S[q=quad*4+reg][kt=l16] = Q[q][:] . K[kt][:]
    #pragma unroll
    for (int hh = 0; hh < 2; ++hh) {
        int h = wid + hh * 4;
        short8 aq0 = *(const short8*)&sQ[l16][h * 64 + quad * 8];
        short8 aq1 = *(const short8*)&sQ[l16][h * 64 + 32 + quad * 8];
        short8 bk0 = *(const short8*)&sK[l16][h * 64 + quad * 8];
        short8 bk1 = *(const short8*)&sK[l16][h * 64 + 32 + quad * 8];
        f32x4 acc = (f32x4){0.f, 0.f, 0.f, 0.f};
        acc = __builtin_amdgcn_mfma_f32_16x16x32_bf16(aq0, bk0, acc, 0, 0, 0);
        acc = __builtin_amdgcn_mfma_f32_16x16x32_bf16(aq1, bk1, acc, 0, 0, 0);
        #pragma unroll
        for (int reg = 0; reg < 4; ++reg) {
            int q = quad * 4 + reg;
            float v = acc[reg] * 0.125f;
            if (sMask[q] == 0.0f) v = -1e9f;
            s_p[h][q][l16] = v;
        }
    }
    __syncthreads();
    if (tid < 128) {
        int h = tid >> 4, q = tid & 15;
        float mx = -3.4e38f;
        #pragma unroll
        for (int kk = 0; kk < 16; ++kk) mx = fmaxf(mx, s_p[h][q][kk]);
        float e[16], s = 0.f;
        #pragma unroll
        for (int kk = 0; kk < 16; ++kk) { e[kk] = expf(s_p[h][q][kk] - mx); s += e[kk]; }
        float inv = 1.0f / s;
        #pragma unroll
        for (int kk = 0; kk < 16; ++kk) s_p[h][q][kk] = e[kk] * inv;
    }
    __syncthreads();
    #pragma unroll
    for (int r = 0; r < 8; ++r) {
        int h = r;
        int q = (tid >> 4) & 15, k = tid & 15;
        atomicAdd(&att_sum[(((size_t)b * H_ + h) * T_ + q) * T_ + k], s_p[h][q][k]);
    }
    if (CTX) {
        // 4 consecutive cols (2 u32) per step: uint2 sV reads, uint2 ctxb writes
        #pragma unroll
        for (int rep = 0; rep < 8; ++rep) {
            int i2 = rep * 256 + tid;           // t*128 + cu, cu = uint2 col index
            int tt = i2 >> 7, cu = i2 & 127;
            int h = cu >> 4;                    // (cu*2)>>5; pair never crosses a head
            const float* pr = &s_p[h][tt][0];
            float a0 = 0.f, a1 = 0.f, a2 = 0.f, a3 = 0.f;
            #pragma unroll
            for (int kk = 0; kk < 16; ++kk) {
                uint2 vv = *((const uint2*)&sV[kk][0] + cu);
                float p = pr[kk];
                a0 += p * bfv((u16)(vv.x & 0xffff));
                a1 += p * bfv((u16)(vv.x >> 16));
                a2 += p * bfv((u16)(vv.y & 0xffff));
                a3 += p * bfv((u16)(vv.y >> 16));
            }
            uint2 o;
            o.x = (u32)f2bf(a0) | ((u32)f2bf(a1) << 16);
            o.y = (u32)f2bf(a2) | ((u32)f2bf(a3) << 16);
            *(uint2*)((u32*)(ctxb + ((size_t)bm_l * T_ + tt) * D_) + cu * 2) = o;
        }
    }
}

// ============ fused self-attention + combine + si, one block per (n,h) ==============
__global__ __launch_bounds__(256) void siatt_kernel(
    const float* __restrict__ xemb, const float* __restrict__ att_sum,
    const float* __restrict__ attf, u16* __restrict__ sib)
{
    __shared__ float sX[16][516];
    __shared__ float sS[16][17];
    __shared__ float sA[16][17];
    int n = blockIdx.x >> 3, h = blockIdx.x & 7;
    int tid = threadIdx.x;
    int t = tid >> 4, ch = (tid & 15) * 32;
    const float* src = xemb + ((size_t)n * T_ + t) * D_;
    #pragma unroll
    for (int c = 0; c < 8; ++c)
        *(float4*)&sX[t][ch + c * 4] = *(const float4*)(src + ch + c * 4);
    __syncthreads();
    int q = tid >> 4, k = tid & 15;
    {
        float acc = 0.f;
        for (int d4 = 0; d4 < D_ / 4; ++d4) {
            float4 xq = *(const float4*)&sX[q][d4 * 4];
            float4 xk = *(const float4*)&sX[k][d4 * 4];
            acc += xq.x * xk.x;
            acc += xq.y * xk.y;
            acc += xq.z * xk.z;
            acc += xq.w * xk.w;
        }
        sS[q][k] = acc * 0.04419417382415922f;
    }
    __syncthreads();
    if (tid < T_) {
        float mx = -3.4e38f;
        #pragma unroll
        for (int kk = 0; kk < 16; ++kk) mx = fmaxf(mx, sS[tid][kk]);
        float e[16], s = 0.f;
        #pragma unroll
        for (int kk = 0; kk < 16; ++kk) { e[kk] = expf(sS[tid][kk] - mx); s += e[kk]; }
        float inv = 1.0f / s;
        #pragma unroll
        for (int kk = 0; kk < 16; ++kk) sS[tid][kk] = e[kk] * inv;
    }
    __syncthreads();
    float f = attf[0] * (1.0f / 32.0f);
    sA[q][k] = sS[q][k] + f * att_sum[((size_t)n * H_ + h) * 256 + q * 16 + k];
    __syncthreads();
    #pragma unroll
    for (int rep = 0; rep < 16; ++rep) {
        int i2 = rep * 256 + tid;          // q*256 + d2
        int qq = i2 >> 8, d2 = (i2 & 255) * 2;
        const float* ar = &sA[qq][0];
        float a0 = 0.f, a1 = 0.f;
        #pragma unroll
        for (int tt = 0; tt < 16; ++tt) {
            float p = ar[tt];
            a0 += p * sX[tt][d2];
            a1 += p * sX[tt][d2 + 1];
        }
        u32 o = (u32)f2bf(a0) | ((u32)f2bf(a1) << 16);
        *((u32*)(sib + (size_t)n * T_ * 4096 + (size_t)qq * 4096 + h * 512) + (d2 >> 1)) = o;
    }
}

// ---------------- positional encoding ------------------------------------------------
__global__ void pe_kernel(float* pe) {
    int i = blockIdx.x * blockDim.x + threadIdx.x;
    if (i >= T_ * 256) return;
    int t = i >> 8, j = i & 255;
    float dv = (float)pow(10000.0, (double)j / 256.0);
    float a = (float)t * dv;
    double ad = (double)a;
    pe[t * D_ + 2 * j]     = (float)sin(ad);
    pe[t * D_ + 2 * j + 1] = (float)cos(ad);
}

// ---------------- x features + embed (r10: row-per-wave, float4 stores) --------------
__global__ __launch_bounds__(256) void xemb_kernel(
    const float* __restrict__ x, const float* __restrict__ Wx,
    const float* __restrict__ bx, const float* __restrict__ pe,
    float* __restrict__ xemb) {
    int row = blockIdx.x * 4 + (threadIdx.x >> 6);   // t*N + n
    if (row >= T_ * N_) return;
    int lane = threadIdx.x & 63;
    int t = row / N_, n = row % N_;
    float x0 = x[row * 6 + 0], x1 = x[row * 6 + 1];
    float x2 = x[row * 6 + 2], x3 = x[row * 6 + 3];
    float x4 = x[row * 6 + 4], x5 = x[row * 6 + 5];
    float vel = sqrtf(x2 * x2 + x3 * x3);
    float ang = atanf(x5 / x4);
    float f0 = ntn(x0), f1 = ntn(x1), f2 = ntn(vel), f3 = ntn(ang);
    int d0 = lane * 8;
    float o[8];
    #pragma unroll
    for (int r = 0; r < 8; ++r) {
        int d = d0 + r;
        o[r] = f0 * Wx[0 * D_ + d] + f1 * Wx[1 * D_ + d]
             + f2 * Wx[2 * D_ + d] + f3 * Wx[3 * D_ + d]
             + bx[d] + pe[t * D_ + d];
    }
    float* dst = xemb + ((size_t)n * T_ + t) * D_ + d0;
    float4 w0 = {o[0], o[1], o[2], o[3]};
    float4 w1 = {o[4], o[5], o[6], o[7]};
    *(float4*)dst = w0;
    *(float4*)(dst + 4) = w1;
}

// ---------------- neighbor features + mask -------------------------------------------
__global__ void nbr_kernel(const float* x, const float* nbr, float* nf, float* maskf) {
    int idx = blockIdx.x * blockDim.x + threadIdx.x;   // t*N*NN + n*NN + m
    if (idx >= T_ * N_ * NN_) return;
    int m = idx % NN_;
    int tn = idx / NN_;
    int n = tn % N_, t = tn / N_;
    float px = x[((size_t)t * N_ + n) * 6 + 0];
    float py = x[((size_t)t * N_ + n) * 6 + 1];
    float vx, vy;
    if (t == 0) {
        vx = x[((size_t)1 * N_ + n) * 6 + 2];
        vy = x[((size_t)1 * N_ + n) * 6 + 3];
    } else {
        vx = px - x[((size_t)(t - 1) * N_ + n) * 6 + 0];
        vy = py - x[((size_t)(t - 1) * N_ + n) * 6 + 1];
    }
    float nx  = nbr[(size_t)idx * 4 + 0], ny  = nbr[(size_t)idx * 4 + 1];
    float nvx = nbr[(size_t)idx * 4 + 2], nvy = nbr[(size_t)idx * 4 + 3];
    float dpx = nx - px, dpy = ny - py;
    float dvx = nvx - vx, dvy = nvy - vy;
    float dist = sqrtf(dpx * dpx + dpy * dpy);
    maskf[((size_t)n * NN_ + m) * T_ + t] = (dist <= 2.0f) ? 1.0f : 0.0f;
    float vn = sqrtf(vx * vx + vy * vy);
    float bearing = (dpx * vx + dpy * vy) / (dist * vn);
    if (isnan(bearing)) bearing = 0.0f;
    float dvn = sqrtf(dvx * dvx + dvy * dvy);
    float tau = -(dpx * dvx + dpy * dvy) / dvn;
    if (isnan(tau)) tau = 0.0f;
    tau = fminf(fmaxf(tau, 0.0f), 7.0f);
    float mx_ = dpx + tau * dvx, my_ = dpy + tau * dvy;
    float mpd = sqrtf(mx_ * mx_ + my_ * my_);
    nf[(size_t)idx * 3 + 0] = ntn(dist);
    nf[(size_t)idx * 3 + 1] = ntn(bearing);
    nf[(size_t)idx * 3 + 2] = ntn(mpd);
}

// ---------------- neighbor embed (r10: row-per-wave, short8 store) -------------------
__global__ __launch_bounds__(256) void nemb_kernel(
    const float* __restrict__ nf, const float* __restrict__ Wn,
    const float* __restrict__ bn, const float* __restrict__ pe,
    u16* __restrict__ Ab) {
    int row = blockIdx.x * 4 + (threadIdx.x >> 6);   // (b*NN+m)*T + t
    if (row >= N_ * NN_ * T_) return;
    int lane = threadIdx.x & 63;
    int t = row % T_;
    int bm = row / T_;
    int m = bm % NN_, b = bm / NN_;
    size_t nfrow = (((size_t)t * N_ + b) * NN_ + m) * 3;
    float f0 = nf[nfrow], f1 = nf[nfrow + 1], f2 = nf[nfrow + 2];
    int d0 = lane * 8;
    short8 w;
    #pragma unroll
    for (int r = 0; r < 8; ++r) {
        int d = d0 + r;
        float v = f0 * Wn[d] + f1 * Wn[D_ + d] + f2 * Wn[2 * D_ + d]
                + bn[d] + pe[t * D_ + d];
        w[r] = (short)f2bf(v);
    }
    *(short8*)(Ab + (size_t)row * D_ + d0) = w;
}

// ---------------- LayerNorm, one wave per row; input f32 or bf16; dual out -----------
template<int INBF>
__global__ __launch_bounds__(256) void ln_kernel(
    const void* X, const float* g, const float* b, float* outF, u16* outB, int nrows) {
    int row = blockIdx.x * 4 + (threadIdx.x >> 6);
    if (row >= nrows) return;
    int lane = threadIdx.x & 63;
    int d0 = lane * 8;
    float v[8];
    if (INBF) {
        short8 x8 = *(const short8*)((const u16*)X + (size_t)row * D_ + d0);
        #pragma unroll
        for (int r = 0; r < 8; ++r) v[r] = bfv((u16)x8[r]);
    } else {
        float4 a = *(const float4*)((const float*)X + (size_t)row * D_ + d0);
        float4 c = *(const float4*)((const float*)X + (size_t)row * D_ + d0 + 4);
        v[0] = a.x; v[1] = a.y; v[2] = a.z; v[3] = a.w;
        v[4] = c.x; v[5] = c.y; v[6] = c.z; v[7] = c.w;
    }
    float s = 0.f;
    #pragma unroll
    for (int r = 0; r < 8; ++r) s += v[r];
    s = wave_sum(s);
    float mean = s * (1.0f / 512.0f);
    float vs = 0.f;
    #pragma unroll
    for (int r = 0; r < 8; ++r) { float d = v[r] - mean; vs += d * d; }
    vs = wave_sum(vs);
    float rstd = rsqrtf(vs * (1.0f / 512.0f) + 1e-5f);
    float4 g0 = *(const float4*)&g[d0], g1 = *(const float4*)&g[d0 + 4];
    float4 b0 = *(const float4*)&b[d0], b1 = *(const float4*)&b[d0 + 4];
    float o[8];
    o[0] = (v[0] - mean) * rstd * g0.x + b0.x;
    o[1] = (v[1] - mean) * rstd * g0.y + b0.y;
    o[2] = (v[2] - mean) * rstd * g0.z + b0.z;
    o[3] = (v[3] - mean) * rstd * g0.w + b0.w;
    o[4] = (v[4] - mean) * rstd * g1.x + b1.x;
    o[5] = (v[5] - mean) * rstd * g1.y + b1.y;
    o[6] = (v[6] - mean) * rstd * g1.z + b1.z;
    o[7] = (v[7] - mean) * rstd * g1.w + b1.w;
    if (outF) {
        float4 w0 = {o[0], o[1], o[2], o[3]};
        float4 w1 = {o[4], o[5], o[6], o[7]};
        *(float4*)(outF + (size_t)row * D_ + d0) = w0;
        *(float4*)(outF + (size_t)row * D_ + d0 + 4) = w1;
    }
    if (outB) {
        short8 w;
        #pragma unroll
        for (int r = 0; r < 8; ++r) w[r] = (short)f2bf(o[r]);
        *(short8*)(outB + (size_t)row * D_ + d0) = w;
    }
}

// ---------------- prediction head + broadcast fused (f32 out) ------------------------
__global__ __launch_bounds__(256) void predbcast_kernel(
    const float* __restrict__ xemb, const float* __restrict__ Wp,
    const float* __restrict__ bp, float* __restrict__ out) {
    int nt = blockIdx.x * blockDim.x + threadIdx.x;    // n*T + t
    if (nt >= N_ * T_) return;
    int n = nt / T_, t = nt % T_;
    float a0 = bp[0], a1 = bp[1];
    const float* xr = xemb + (size_t)nt * D_;
    for (int j = 0; j < D_; j += 4) {
        float4 xv = *(const float4*)&xr[j];
        float4 w0 = *(const float4*)&Wp[(size_t)j * 2];      // W[j][0..1], W[j+1][0..1]
        float4 w1 = *(const float4*)&Wp[(size_t)j * 2 + 4];  // W[j+2][0..1], W[j+3][0..1]
        a0 += xv.x * w0.x; a1 += xv.x * w0.y;
        a0 += xv.y * w0.z; a1 += xv.y * w0.w;
        a0 += xv.z * w1.x; a1 += xv.z * w1.y;
        a0 += xv.w * w1.z; a1 += xv.w * w1.w;
    }
    #pragma unroll
    for (int p = 0; p < NPRED_; ++p) {
        size_t o = (((size_t)p * T_ + t) * N_ + n) * 2;
        out[o]     = a0;
        out[o + 1] = a1;
    }
}

extern "C" void kernel_launch(void* const* d_in, const int* in_sizes, int n_in,
                              void* d_out, int out_size, void* d_ws, size_t ws_size,
                              hipStream_t stream) {
    (void)in_sizes; (void)n_in; (void)out_size; (void)ws_size;

    const float* x    = (const float*)d_in[0];
    const float* nbr  = (const float*)d_in[1];
    const float* attf = (const float*)d_in[2];
    const float* Wx   = (const float*)d_in[3];
    const float* bx   = (const float*)d_in[4];
    const float* Wn   = (const float*)d_in[5];
    const float* bn   = (const float*)d_in[6];
    const float* Wp   = (const float*)d_in[7];
    const float* bp   = (const float*)d_in[8];
    const float* WQ   = (const float*)d_in[9];
    const float* WK   = (const float*)d_in[10];
    const float* WV   = (const float*)d_in[11];
    const float* Wfc  = (const float*)d_in[12];
    const float* mlng = (const float*)d_in[13];
    const float* mlnb = (const float*)d_in[14];
    const float* WSI  = (const float*)d_in[15];
    const float* fsw1 = (const float*)d_in[16];
    const float* fsw2 = (const float*)d_in[17];
    const float* fsg  = (const float*)d_in[18];
    const float* fsb  = (const float*)d_in[19];
    const float* fiw1 = (const float*)d_in[20];
    const float* fiw2 = (const float*)d_in[21];
    const float* fig  = (const float*)d_in[22];
    const float* fib  = (const float*)d_in[23];

    char* w = (char*)d_ws;
    size_t off = 0;
    auto alloc = [&](size_t bytes) -> void* {
        void* p = w + off;
        off = (off + bytes + 255) & ~(size_t)255;
        return p;
    };
    const size_t MiB = 1024 * 1024;

    const int BM = N_ * NN_;          // 2048 (b,m) pairs
    const int ROWS_I = BM * T_;       // 32768 neighbor rows
    const int CB = 1024;              // bm per chunk (NCH=2, l=0 only)
    const int RC = CB * T_;           // 16384 rows per chunk
    const int NCH = ROWS_I / RC;      // 2

    float* pe      = (float*)alloc((size_t)T_ * D_ * 4);
    float* xemb    = (float*)alloc((size_t)N_ * T_ * D_ * 4);
    float* nf      = (float*)alloc((size_t)T_ * N_ * NN_ * 3 * 4);
    float* maskf   = (float*)alloc((size_t)BM * T_ * 4);
    u16*   Ab      = (u16*)alloc((size_t)ROWS_I * D_ * 2);     // n_emb bf16  32 MiB
    u16* tQKV[2], *tWSI[2], *tfs1[2], *tfs2[2];
    for (int l = 0; l < 2; ++l) {
        tQKV[l] = (u16*)alloc((size_t)1536 * 512 * 2);
        tWSI[l] = (u16*)alloc((size_t)512 * 4096 * 2);
        tfs1[l] = (u16*)alloc((size_t)2048 * 512 * 2);
        tfs2[l] = (u16*)alloc((size_t)512 * 2048 * 2);
    }
    u16* tWfc = (u16*)alloc((size_t)512 * 512 * 2);
    u16* tfi1 = (u16*)alloc((size_t)2048 * 512 * 2);
    u16* tfi2 = (u16*)alloc((size_t)512 * 2048 * 2);
    // scratch union: l0 chunk: QKVb 48 + ctxb 16 | hid 64 ; l1: QK full 64 MiB
    // ffs phase: hid(ffs) 4 MiB @ SCR+0, split-K partials 16 MiB @ SCR+16MiB
    char* SCR  = (char*)alloc(64 * MiB);
    u16*   QKVb = (u16*)SCR;
    u16*   ctxb = (u16*)(SCR + 48 * MiB);
    u16*   hid  = (u16*)SCR;
    float* Pk   = (float*)(SCR + 16 * MiB);
    u16*   BbA    = (u16*)alloc((size_t)RC * D_ * 2);  // pre-LN bf16 chunk    16 MiB
    u16*   Bb_res = (u16*)alloc((size_t)RC * D_ * 2);  // res_inter bf16       16 MiB
    float* att_sum = (float*)alloc((size_t)N_ * H_ * 256 * 4);
    u16*   sib     = (u16*)alloc((size_t)N_ * T_ * 4096 * 2);  // 8 MiB
    float* xnew    = (float*)alloc((size_t)N_ * T_ * D_ * 4);
    u16*   xnb     = (u16*)alloc((size_t)N_ * T_ * D_ * 2);
    // total ~170 MiB

    // ---- batched weight conversion: 14 jobs, one launch ----
    WJobs jobs;
    int ntiles = 0;
    auto addJob = [&](int idx, const float* src, u16* dst, int K, int N) {
        jobs.j[idx] = {src, dst, K, N, ntiles};
        ntiles += (N >> 5) * (K >> 5);
    };
    addJob(0,  WQ,                            tQKV[0],              512, 512);
    addJob(1,  WK,                            tQKV[0] + 512 * 512,  512, 512);
    addJob(2,  WV,                            tQKV[0] + 1024 * 512, 512, 512);   // dead at l=1
    addJob(3,  WQ + (size_t)512 * 512,        tQKV[1],              512, 512);
    addJob(4,  WK + (size_t)512 * 512,        tQKV[1] + 512 * 512,  512, 512);
    addJob(5,  Wfc,                           tWfc,                 512, 512);
    addJob(6,  WSI,                           tWSI[0],              4096, 512);
    addJob(7,  WSI + (size_t)4096 * 512,      tWSI[1],              4096, 512);
    addJob(8,  fsw1,                          tfs1[0],              512, 2048);
    addJob(9,  fsw1 + (size_t)512 * 2048,     tfs1[1],              512, 2048);
    addJob(10, fsw2,                          tfs2[0],              2048, 512);
    addJob(11, fsw2 + (size_t)2048 * 512,     tfs2[1],              2048, 512);
    addJob(12, fiw1,                          tfi1,                 512, 2048);
    addJob(13, fiw2,                          tfi2,                 2048, 512);
    wconv_all<<<ntiles, 256, 0, stream>>>(jobs, ntiles);

    pe_kernel<<<16, 256, 0, stream>>>(pe);
    xemb_kernel<<<(T_ * N_) / 4, 256, 0, stream>>>(x, Wx, bx, pe, xemb);
    nbr_kernel<<<(T_ * N_ * NN_ + 255) / 256, 256, 0, stream>>>(x, nbr, nf, maskf);
    nemb_kernel<<<(BM * T_) / 4, 256, 0, stream>>>(nf, Wn, bn, pe, Ab);

    for (int l = 0; l < L_; ++l) {
        hipMemsetAsync(att_sum, 0, (size_t)N_ * H_ * 256 * 4, stream);
        if (l == 0) {
            for (int c = 0; c < NCH; ++c) {
                u16* Acb = Ab + (size_t)c * RC * D_;
                // QKV fused GEMM: N=1536 (1536 blocks = 3 exact rounds @2/CU)
                gemm_ct<0, 0, 1><<<dim3(12, RC / 128), 256, 0, stream>>>(
                    Acb, tQKV[0], nullptr, QKVb, nullptr, 512, 1536);
                attn_fused_kernel<1, 1536><<<CB, 256, 0, stream>>>(
                    QKVb, maskf, c * CB, att_sum, ctxb);
                // fc + residual(n_emb bf16) -> pre-LN bf16 (512 blocks = 1 round)
                gemm_ct<3, 0, 1><<<dim3(4, RC / 128), 256, 0, stream>>>(
                    ctxb, tWfc, nullptr, BbA, Acb, 512, 512);
                ln_kernel<1><<<RC / 4, 256, 0, stream>>>(
                    BbA, mlng, mlnb, nullptr, Bb_res, RC);   // res_inter bf16
                // ffi1 relu: N=2048 (2048 blocks = 4 exact rounds)
                gemm_ct<1, 0, 1><<<dim3(16, RC / 128), 256, 0, stream>>>(
                    Bb_res, tfi1, nullptr, hid, nullptr, 512, 2048);
                // ffi2 + residual(res_inter bf16) -> pre-LN bf16 (512 blocks)
                gemm_ct<3, 0, 1><<<dim3(4, RC / 128), 256, 0, stream>>>(
                    hid, tfi2, nullptr, BbA, Bb_res, 2048, 512);
                ln_kernel<1><<<RC / 4, 256, 0, stream>>>(
                    BbA, fig, fib, nullptr, Acb, RC);        // new n_emb (bf16)
            }
        } else {
            // l=1: unchunked QK (N=1024, ldc=1024; 64 MiB = SCR): 2048 blocks
            gemm_ct<0, 0, 1><<<dim3(8, ROWS_I / 128), 256, 0, stream>>>(
                Ab, tQKV[1], nullptr, QKVb, nullptr, 512, 1024);
            attn_fused_kernel<0, 1024><<<BM, 256, 0, stream>>>(
                QKVb, maskf, 0, att_sum, nullptr);
        }

        // ---- self-attention + si + ffs (updates xemb; split-K where it pays) ----
        siatt_kernel<<<N_ * H_, 256, 0, stream>>>(xemb, att_sum, attf, sib);
        // xnew/xnb = sib @ tWSI (M=1024, N=512, K=4096): NS=8 -> 256 blocks, Kc=512
        gemm_ks<8><<<dim3(4, 8, 8), 256, 0, stream>>>(sib, tWSI[l], Pk, 4096, 512);
        ksum_kernel<8, 0, 1, 1><<<512, 256, 0, stream>>>(
            Pk, nullptr, xnew, xnb, 1024 * 512);
        // hid = relu(xnb @ tfs1) (M=1024, N=2048, K=512): direct gemm_ct, 128 blocks
        gemm_ct<1, 0, 1><<<dim3(16, 8), 256, 0, stream>>>(
            xnb, tfs1[l], nullptr, hid, nullptr, 512, 2048);
        // xemb = LN((hid @ tfs2) + xnew): split-K partials + fused ksum+LN
        gemm_ks<8><<<dim3(4, 8, 8), 256, 0, stream>>>(hid, tfs2[l], Pk, 2048, 512);
        ksln_kernel<8><<<256, 256, 0, stream>>>(
            Pk, xnew, fsg + l * D_, fsb + l * D_, xemb, 1024);
    }

    predbcast_kernel<<<(N_ * T_ + 255) / 256, 256, 0, stream>>>(
        xemb, Wp, bp, (float*)d_out);
}

// Round 12
// 712.449 us; speedup vs baseline: 1.1994x; 1.0159x over previous
//
#include <hip/hip_runtime.h>
#include <math.h>

// DTYPE COMMITMENTS (evidence-backed): inputs f32, output f32 (rounds 4-14 PASS).
// WS BUDGET: <= ~210 MB decimal; this build ~170 MiB (+0: partials alias SCR).
// r12: final fusion set. ksum drops xnew f32 output (WSI partials kept live in a
// separate region; ksln sums them directly -- element-wise identical order).
// l=1 ksln fuses the prediction head (dot+bias+broadcast to d_out), removing the
// predbcast launch and the final xemb round-trip. GEMMs frozen (8-phase 0/4,
// abandoned); everything else byte-identical to the 723.8us r11 build.

#define T_ 16
#define N_ 64
#define NN_ 32
#define D_ 512
#define H_ 8
#define DK_ 64
#define DFF_ 2048
#define L_ 2
#define NPRED_ 20

typedef unsigned short u16;
typedef unsigned int u32;
typedef __attribute__((ext_vector_type(8))) short short8;
typedef __attribute__((ext_vector_type(4))) float f32x4;

__device__ __forceinline__ u16 f2bf(float f) {
    u32 u = __float_as_uint(f);
    u32 r = u + 0x7fffu + ((u >> 16) & 1u);
    return (u16)(r >> 16);
}
__device__ __forceinline__ float bfv(u16 v) {
    return __uint_as_float(((u32)v) << 16);
}
__device__ __forceinline__ float ntn(float v) {
    if (isnan(v)) return 0.0f;
    if (isinf(v)) return v > 0.0f ? 3.4028234663852886e38f : -3.4028234663852886e38f;
    return v;
}
__device__ __forceinline__ float wave_sum(float v) {
    #pragma unroll
    for (int o = 32; o > 0; o >>= 1) v += __shfl_xor(v, o, 64);
    return v;
}
// async 16B HBM->LDS: writes ldsbase + lane*16 (wave-uniform base, per-lane gptr)
__device__ __forceinline__ void gload_lds(const u16* g, u16* l) {
    __builtin_amdgcn_global_load_lds(
        (const __attribute__((address_space(1))) u32*)g,
        (__attribute__((address_space(3))) u32*)l, 16, 0, 0);
}

// ============ batched weight convert+transpose: 14 jobs in ONE launch ===============
struct WJob { const float* src; u16* dst; int K; int N; int t0; };
struct WJobs { WJob j[14]; };
__global__ __launch_bounds__(256) void wconv_all(WJobs jobs, int ntiles) {
    int bid = blockIdx.x;
    if (bid >= ntiles) return;
    int ji = 0;
    #pragma unroll 1
    for (int i = 1; i < 14; ++i) if (bid >= jobs.j[i].t0) ji = i;
    const float* in = jobs.j[ji].src;
    u16* out = jobs.j[ji].dst;
    int K = jobs.j[ji].K, N = jobs.j[ji].N;
    int lt = bid - jobs.j[ji].t0;
    int ntx = N >> 5;
    int nb = (lt % ntx) * 32, kb = (lt / ntx) * 32;
    __shared__ float tile[32][33];
    int tx = threadIdx.x & 31, ty = threadIdx.x >> 5;
    #pragma unroll
    for (int r = ty; r < 32; r += 8)
        tile[r][tx] = in[(size_t)(kb + r) * N + nb + tx];
    __syncthreads();
    #pragma unroll
    for (int r = ty; r < 32; r += 8)
        out[(size_t)(nb + r) * K + kb + tx] = f2bf(tile[tx][r]);
}

// ============ counted-pipeline GEMM: 128x128, BK=64, 2 barriers/tile (r4 best) ======
template<int EPI, int WF32, int WBF16>
__global__ __launch_bounds__(256, 2) void gemm_ct(
    const u16* __restrict__ Ab, const u16* __restrict__ Btb,
    float* __restrict__ Cf, u16* __restrict__ Cb, const void* __restrict__ Rg,
    int K, int ldc)
{
    __shared__ __align__(16) u16 As[2][128][64];
    __shared__ __align__(16) u16 Bs[2][128][64];
    int tid = threadIdx.x;
    int lane = tid & 63, wave = tid >> 6;       // 4 waves: 2M x 2N
    int quad = lane >> 4, l16 = lane & 15;
    int wm = (wave >> 1) * 64, wn = (wave & 1) * 64;

    int gx = gridDim.x, gy = gridDim.y;
    int id = blockIdx.y * gx + blockIdx.x;
    int xcd = id & 7, slot = id >> 3;
    int bx = slot % gx;
    int by = xcd * (gy >> 3) + slot / gx;
    size_t row0 = (size_t)by * 128;
    size_t col0 = (size_t)bx * 128;

    f32x4 acc[4][4];
    #pragma unroll
    for (int i = 0; i < 4; ++i)
        #pragma unroll
        for (int j = 0; j < 4; ++j)
            acc[i][j] = (f32x4){0.f, 0.f, 0.f, 0.f};

    // staging swizzle (r9-verified): physical 16B chunk p of row r holds logical
    // chunk p ^ (r&7)
    int srow = lane >> 3;
    int c8 = (lane & 7) ^ srow;
    int h8 = l16 & 7;
    size_t aoff[4], boff[4];
    #pragma unroll
    for (int it = 0; it < 4; ++it) {
        aoff[it] = (row0 + (size_t)(wave + it * 4) * 8 + srow) * (size_t)K + c8 * 8;
        boff[it] = (col0 + (size_t)(wave + it * 4) * 8 + srow) * (size_t)K + c8 * 8;
    }

    int nt = K >> 6;
    // prologue: stage tile 0 -> buf 0 (8 loads in flight, no wait)
    #pragma unroll
    for (int it = 0; it < 4; ++it)
        gload_lds(Ab + aoff[it], &As[0][(wave + it * 4) * 8][0]);
    #pragma unroll
    for (int it = 0; it < 4; ++it)
        gload_lds(Btb + boff[it], &Bs[0][(wave + it * 4) * 8][0]);

    #pragma unroll 1
    for (int t = 0; t < nt; ++t) {
        int cur = t & 1;
        if (t + 1 < nt) {
            // stage tile t+1 into other buffer (freed by iter t-1's end barrier)
            size_t ko = (size_t)(t + 1) * 64;
            #pragma unroll
            for (int it = 0; it < 4; ++it)
                gload_lds(Ab + aoff[it] + ko, &As[cur ^ 1][(wave + it * 4) * 8][0]);
            #pragma unroll
            for (int it = 0; it < 4; ++it)
                gload_lds(Btb + boff[it] + ko, &Bs[cur ^ 1][(wave + it * 4) * 8][0]);
            __builtin_amdgcn_sched_barrier(0);
            asm volatile("s_waitcnt vmcnt(8)" ::: "memory");   // tile t landed; t+1 in flight
        } else {
            __builtin_amdgcn_sched_barrier(0);
            asm volatile("s_waitcnt vmcnt(0)" ::: "memory");   // final tile only
        }
        __builtin_amdgcn_sched_barrier(0);
        __builtin_amdgcn_s_barrier();                          // rendezvous: tile t staged
        __builtin_amdgcn_sched_barrier(0);
        __builtin_amdgcn_s_setprio(1);
        #pragma unroll
        for (int kh = 0; kh < 2; ++kh) {
            int coff = ((kh * 4 + quad) ^ h8) * 8;
            short8 af[4], bf[4];
            #pragma unroll
            for (int j = 0; j < 4; ++j)
                bf[j] = *(short8*)&Bs[cur][wn + j * 16 + l16][coff];
            #pragma unroll
            for (int i = 0; i < 4; ++i)
                af[i] = *(short8*)&As[cur][wm + i * 16 + l16][coff];
            #pragma unroll
            for (int i = 0; i < 4; ++i)
                #pragma unroll
                for (int j = 0; j < 4; ++j)
                    acc[i][j] = __builtin_amdgcn_mfma_f32_16x16x32_bf16(
                        af[i], bf[j], acc[i][j], 0, 0, 0);
        }
        __builtin_amdgcn_s_setprio(0);
        __builtin_amdgcn_sched_barrier(0);                     // reads done before barrier
        __builtin_amdgcn_s_barrier();                          // frees buf[cur] for restage
    }

    // C/D layout (on-target verified): col = lane&15, row = quad*4 + reg
    #pragma unroll
    for (int i = 0; i < 4; ++i)
        #pragma unroll
        for (int j = 0; j < 4; ++j)
            #pragma unroll
            for (int reg = 0; reg < 4; ++reg) {
                size_t row = row0 + wm + i * 16 + quad * 4 + reg;
                size_t col = col0 + wn + j * 16 + l16;
                float v = acc[i][j][reg];
                if (EPI == 2) v += ((const float*)Rg)[row * (size_t)ldc + col];
                if (EPI == 3) v += bfv(((const u16*)Rg)[row * (size_t)ldc + col]);
                if (EPI == 1) v = fmaxf(v, 0.f);
                if (WF32)  Cf[row * (size_t)ldc + col] = v;
                if (WBF16) Cb[row * (size_t)ldc + col] = f2bf(v);
            }
}

// ============ split-K GEMM for small-M (ffs chain): gemm_ct schedule + z-split ======
// grid (N/128, M/128=8, NS); block z computes K-range [z*Kc,(z+1)*Kc), Kc=K/NS
// (Kc%64==0, Kc>=128), writes f32 partial to Pf + z*M*ldc. No atomics. Identical
// pipeline/swizzle to gemm_ct (refcheck'd r4-r11).
template<int NS>
__global__ __launch_bounds__(256, 2) void gemm_ks(
    const u16* __restrict__ Ab, const u16* __restrict__ Btb,
    float* __restrict__ Pf, int K, int ldc)
{
    __shared__ __align__(16) u16 As[2][128][64];
    __shared__ __align__(16) u16 Bs[2][128][64];
    int tid = threadIdx.x;
    int lane = tid & 63, wave = tid >> 6;
    int quad = lane >> 4, l16 = lane & 15;
    int wm = (wave >> 1) * 64, wn = (wave & 1) * 64;

    int gx = gridDim.x, gy = gridDim.y;
    int id = blockIdx.y * gx + blockIdx.x;
    int xcd = id & 7, slot = id >> 3;
    int bx = slot % gx;
    int by = xcd * (gy >> 3) + slot / gx;
    int z = blockIdx.z;
    int Kc = K / NS;
    size_t row0 = (size_t)by * 128;
    size_t col0 = (size_t)bx * 128;
    size_t M = (size_t)gy * 128;

    f32x4 acc[4][4];
    #pragma unroll
    for (int i = 0; i < 4; ++i)
        #pragma unroll
        for (int j = 0; j < 4; ++j)
            acc[i][j] = (f32x4){0.f, 0.f, 0.f, 0.f};

    int srow = lane >> 3;
    int c8 = (lane & 7) ^ srow;
    int h8 = l16 & 7;
    size_t kbase = (size_t)z * Kc;
    size_t aoff[4], boff[4];
    #pragma unroll
    for (int it = 0; it < 4; ++it) {
        aoff[it] = (row0 + (size_t)(wave + it * 4) * 8 + srow) * (size_t)K + kbase + c8 * 8;
        boff[it] = (col0 + (size_t)(wave + it * 4) * 8 + srow) * (size_t)K + kbase + c8 * 8;
    }

    int nt = Kc >> 6;
    #pragma unroll
    for (int it = 0; it < 4; ++it)
        gload_lds(Ab + aoff[it], &As[0][(wave + it * 4) * 8][0]);
    #pragma unroll
    for (int it = 0; it < 4; ++it)
        gload_lds(Btb + boff[it], &Bs[0][(wave + it * 4) * 8][0]);

    #pragma unroll 1
    for (int t = 0; t < nt; ++t) {
        int cur = t & 1;
        if (t + 1 < nt) {
            size_t ko = (size_t)(t + 1) * 64;
            #pragma unroll
            for (int it = 0; it < 4; ++it)
                gload_lds(Ab + aoff[it] + ko, &As[cur ^ 1][(wave + it * 4) * 8][0]);
            #pragma unroll
            for (int it = 0; it < 4; ++it)
                gload_lds(Btb + boff[it] + ko, &Bs[cur ^ 1][(wave + it * 4) * 8][0]);
            __builtin_amdgcn_sched_barrier(0);
            asm volatile("s_waitcnt vmcnt(8)" ::: "memory");
        } else {
            __builtin_amdgcn_sched_barrier(0);
            asm volatile("s_waitcnt vmcnt(0)" ::: "memory");
        }
        __builtin_amdgcn_sched_barrier(0);
        __builtin_amdgcn_s_barrier();
        __builtin_amdgcn_sched_barrier(0);
        __builtin_amdgcn_s_setprio(1);
        #pragma unroll
        for (int kh = 0; kh < 2; ++kh) {
            int coff = ((kh * 4 + quad) ^ h8) * 8;
            short8 af[4], bf[4];
            #pragma unroll
            for (int j = 0; j < 4; ++j)
                bf[j] = *(short8*)&Bs[cur][wn + j * 16 + l16][coff];
            #pragma unroll
            for (int i = 0; i < 4; ++i)
                af[i] = *(short8*)&As[cur][wm + i * 16 + l16][coff];
            #pragma unroll
            for (int i = 0; i < 4; ++i)
                #pragma unroll
                for (int j = 0; j < 4; ++j)
                    acc[i][j] = __builtin_amdgcn_mfma_f32_16x16x32_bf16(
                        af[i], bf[j], acc[i][j], 0, 0, 0);
        }
        __builtin_amdgcn_s_setprio(0);
        __builtin_amdgcn_sched_barrier(0);
        __builtin_amdgcn_s_barrier();
    }

    float* P = Pf + (size_t)z * M * (size_t)ldc;
    #pragma unroll
    for (int i = 0; i < 4; ++i)
        #pragma unroll
        for (int j = 0; j < 4; ++j)
            #pragma unroll
            for (int reg = 0; reg < 4; ++reg) {
                size_t row = row0 + wm + i * 16 + quad * 4 + reg;
                size_t col = col0 + wn + j * 16 + l16;
                P[row * (size_t)ldc + col] = acc[i][j][reg];
            }
}

// ---- split-K reduce + epilogue: sum NS f32 partials; EPI 1=relu 2=+res; dual out --
template<int NS, int EPI, int WF32, int WBF16>
__global__ __launch_bounds__(256) void ksum_kernel(
    const float* __restrict__ P, const float* __restrict__ res,
    float* __restrict__ outF, u16* __restrict__ outB, int total)
{
    int i = blockIdx.x * blockDim.x + threadIdx.x;
    size_t o4 = (size_t)i * 4;
    if (o4 >= (size_t)total) return;
    float4 s = *(const float4*)(P + o4);
    #pragma unroll
    for (int p = 1; p < NS; ++p) {
        float4 v = *(const float4*)(P + (size_t)p * total + o4);
        s.x += v.x; s.y += v.y; s.z += v.z; s.w += v.w;
    }
    if (EPI == 2) {
        float4 r = *(const float4*)(res + o4);
        s.x += r.x; s.y += r.y; s.z += r.z; s.w += r.w;
    }
    if (EPI == 1) {
        s.x = fmaxf(s.x, 0.f); s.y = fmaxf(s.y, 0.f);
        s.z = fmaxf(s.z, 0.f); s.w = fmaxf(s.w, 0.f);
    }
    if (WF32) *(float4*)(outF + o4) = s;
    if (WBF16) {
        uint2 w;
        w.x = (u32)f2bf(s.x) | ((u32)f2bf(s.y) << 16);
        w.y = (u32)f2bf(s.z) | ((u32)f2bf(s.w) << 16);
        *(uint2*)(outB + o4) = w;
    }
}

// ---- fused split-K reduce (fs2 + WSI partial sets) + LN [+ pred head] (r12) -------
// v = (fs2P0+..+fs2P7) + (wsiP0+..+wsiP7): element-wise identical to r11's
// "fs2 partials + xnew" (xnew was exactly the WSI partial sum in the same order).
// PRED=0: write LN'd row to outF (l=0). PRED=1 (l=1): fuse prediction head --
// per-lane dot of o[8] with Wp, butterfly wave_sum, +bias, lanes 0..19 write the
// broadcast output rows directly (xemb round-trip + predbcast launch eliminated;
// f32 reassociation only).
template<int NS, int PRED>
__global__ __launch_bounds__(256) void ksln_kernel(
    const float* __restrict__ P, const float* __restrict__ Pw,
    const float* __restrict__ g, const float* __restrict__ b,
    float* __restrict__ outF, const float* __restrict__ Wp,
    const float* __restrict__ bp, float* __restrict__ out, int nrows)
{
    int row = blockIdx.x * 4 + (threadIdx.x >> 6);
    if (row >= nrows) return;
    int lane = threadIdx.x & 63;
    int d0 = lane * 8;
    size_t base = (size_t)row * D_ + d0;
    size_t total = (size_t)nrows * D_;
    float v[8];
    {
        float4 a = *(const float4*)(P + base);
        float4 c = *(const float4*)(P + base + 4);
        v[0] = a.x; v[1] = a.y; v[2] = a.z; v[3] = a.w;
        v[4] = c.x; v[5] = c.y; v[6] = c.z; v[7] = c.w;
    }
    #pragma unroll
    for (int p = 1; p < NS; ++p) {
        float4 a = *(const float4*)(P + (size_t)p * total + base);
        float4 c = *(const float4*)(P + (size_t)p * total + base + 4);
        v[0] += a.x; v[1] += a.y; v[2] += a.z; v[3] += a.w;
        v[4] += c.x; v[5] += c.y; v[6] += c.z; v[7] += c.w;
    }
    // residual = WSI partial sum (same order as the ksum that produced xnew in r11)
    float r8[8];
    {
        float4 a = *(const float4*)(Pw + base);
        float4 c = *(const float4*)(Pw + base + 4);
        r8[0] = a.x; r8[1] = a.y; r8[2] = a.z; r8[3] = a.w;
        r8[4] = c.x; r8[5] = c.y; r8[6] = c.z; r8[7] = c.w;
    }
    #pragma unroll
    for (int p = 1; p < NS; ++p) {
        float4 a = *(const float4*)(Pw + (size_t)p * total + base);
        float4 c = *(const float4*)(Pw + (size_t)p * total + base + 4);
        r8[0] += a.x; r8[1] += a.y; r8[2] += a.z; r8[3] += a.w;
        r8[4] += c.x; r8[5] += c.y; r8[6] += c.z; r8[7] += c.w;
    }
    #pragma unroll
    for (int r = 0; r < 8; ++r) v[r] += r8[r];

    float s = 0.f;
    #pragma unroll
    for (int r = 0; r < 8; ++r) s += v[r];
    s = wave_sum(s);
    float mean = s * (1.0f / 512.0f);
    float vs = 0.f;
    #pragma unroll
    for (int r = 0; r < 8; ++r) { float d = v[r] - mean; vs += d * d; }
    vs = wave_sum(vs);
    float rstd = rsqrtf(vs * (1.0f / 512.0f) + 1e-5f);
    float4 g0 = *(const float4*)&g[d0], g1 = *(const float4*)&g[d0 + 4];
    float4 b0 = *(const float4*)&b[d0], b1 = *(const float4*)&b[d0 + 4];
    float o[8];
    o[0] = (v[0] - mean) * rstd * g0.x + b0.x;
    o[1] = (v[1] - mean) * rstd * g0.y + b0.y;
    o[2] = (v[2] - mean) * rstd * g0.z + b0.z;
    o[3] = (v[3] - mean) * rstd * g0.w + b0.w;
    o[4] = (v[4] - mean) * rstd * g1.x + b1.x;
    o[5] = (v[5] - mean) * rstd * g1.y + b1.y;
    o[6] = (v[6] - mean) * rstd * g1.z + b1.z;
    o[7] = (v[7] - mean) * rstd * g1.w + b1.w;
    if (!PRED) {
        float4 w0 = {o[0], o[1], o[2], o[3]};
        float4 w1 = {o[4], o[5], o[6], o[7]};
        *(float4*)(outF + base) = w0;
        *(float4*)(outF + base + 4) = w1;
    } else {
        // prediction head: a_c = bp[c] + sum_d o_row[d] * Wp[d][c]
        float a0 = 0.f, a1 = 0.f;
        #pragma unroll
        for (int r = 0; r < 8; ++r) {
            float4 wp = *(const float4*)&Wp[(size_t)(d0 + r) * 2 & ~1];  // aligned pair pairs
            // simpler: scalar loads (Wp row = 2 floats)
        }
        #pragma unroll
        for (int r = 0; r < 8; ++r) {
            int d = d0 + r;
            a0 += o[r] * Wp[(size_t)d * 2];
            a1 += o[r] * Wp[(size_t)d * 2 + 1];
        }
        a0 = wave_sum(a0);
        a1 = wave_sum(a1);
        a0 += bp[0];
        a1 += bp[1];
        int n = row / T_, t = row % T_;
        if (lane < NPRED_) {
            size_t off = (((size_t)lane * T_ + t) * N_ + n) * 2;
            out[off]     = a0;
            out[off + 1] = a1;
        }
    }
}

// ============ fused attention per (b,m): all-heads phases, 3 barriers ===============
// r7: QK^T via MFMA 16x16x32 (verified layout); S stays f32. ctx phase uint2.
template<int CTX, int LD>
__global__ __launch_bounds__(256) void attn_fused_kernel(
    const u16* __restrict__ QKVb, const float* __restrict__ maskf, int bm0,
    float* __restrict__ att_sum, u16* __restrict__ ctxb)
{
    __shared__ __align__(16) u16 sQ[16][520];
    __shared__ __align__(16) u16 sK[16][520];
    __shared__ __align__(16) u16 sV[CTX ? 16 : 1][520];
    __shared__ float s_p[H_][16][17];
    __shared__ float sMask[16];
    int bm_l = blockIdx.x;
    int tid = threadIdx.x;
    int t = tid >> 4, ch = (tid & 15) * 32;
    const u16* base = QKVb + ((size_t)bm_l * T_ + t) * LD;
    #pragma unroll
    for (int c = 0; c < 4; ++c) {
        *(uint4*)&sQ[t][ch + c * 8] = *(const uint4*)(base + ch + c * 8);
        *(uint4*)&sK[t][ch + c * 8] = *(const uint4*)(base + 512 + ch + c * 8);
        if (CTX) *(uint4*)&sV[t][ch + c * 8] = *(const uint4*)(base + 1024 + ch + c * 8);
    }
    if (tid < 16) sMask[tid] = maskf[(size_t)(bm0 + bm_l) * T_ + tid];
    __syncthreads();

    int b = (bm0 + bm_l) >> 5;                  // bm = b*NN + m
    int lane = tid & 63, wid = tid >> 6;
    int l16 = lane & 15, quad = lane >> 4;

    // QK^T: per wave heads {wid, wid+4}; S[q=quad*4+reg][kt=l16] = Q[q][:] . K[kt][:]
    #pragma unroll
    for (int hh = 0; hh < 2; ++hh) {
        int h = wid + hh * 4;
        short8 aq0 = *(const short8*)&sQ[l16][h * 64 + quad * 8];
        short8 aq1 = *(const short8*)&sQ[l16][h * 64 + 32 + quad * 8];
        short8 bk0 = *(const short8*)&sK[l16][h * 64 + quad * 8];
        short8 bk1 = *(const short8*)&sK[l16][h * 64 + 32 + quad * 8];
        f32x4 acc = (f32x4){0.f, 0.f, 0.f, 0.f};
        acc = __builtin_amdgcn_mfma_f32_16x16x32_bf16(aq0, bk0, acc, 0, 0, 0);
        acc = __builtin_amdgcn_mfma_f32_16x16x32_bf16(aq1, bk1, acc, 0, 0, 0);
        #pragma unroll
        for (int reg = 0; reg < 4; ++reg) {
            int q = quad * 4 + reg;
            float v = acc[reg] * 0.125f;
            if (sMask[q] == 0.0f) v = -1e9f;
            s_p[h][q][l16] = v;
        }
    }
    __syncthreads();
    if (tid < 128) {
        int h = tid >> 4, q = tid & 15;
        float mx = -3.4e38f;
        #pragma unroll
        for (int kk = 0; kk < 16; ++kk) mx = fmaxf(mx, s_p[h][q][kk]);
        float e[16], s = 0.f;
        #pragma unroll
        for (int kk = 0; kk < 16; ++kk) { e[kk] = expf(s_p[h][q][kk] - mx); s += e[kk]; }
        float inv = 1.0f / s;
        #pragma unroll
        for (int kk = 0; kk < 16; ++kk) s_p[h][q][kk] = e[kk] * inv;
    }
    __syncthreads();
    #pragma unroll
    for (int r = 0; r < 8; ++r) {
        int h = r;
        int q = (tid >> 4) & 15, k = tid & 15;
        atomicAdd(&att_sum[(((size_t)b * H_ + h) * T_ + q) * T_ + k], s_p[h][q][k]);
    }
    if (CTX) {
        // 4 consecutive cols (2 u32) per step: uint2 sV reads, uint2 ctxb writes
        #pragma unroll
        for (int rep = 0; rep < 8; ++rep) {
            int i2 = rep * 256 + tid;           // t*128 + cu, cu = uint2 col index
            int tt = i2 >> 7, cu = i2 & 127;
            int h = cu >> 4;                    // (cu*2)>>5; pair never crosses a head
            const float* pr = &s_p[h][tt][0];
            float a0 = 0.f, a1 = 0.f, a2 = 0.f, a3 = 0.f;
            #pragma unroll
            for (int kk = 0; kk < 16; ++kk) {
                uint2 vv = *((const uint2*)&sV[kk][0] + cu);
                float p = pr[kk];
                a0 += p * bfv((u16)(vv.x & 0xffff));
                a1 += p * bfv((u16)(vv.x >> 16));
                a2 += p * bfv((u16)(vv.y & 0xffff));
                a3 += p * bfv((u16)(vv.y >> 16));
            }
            uint2 o;
            o.x = (u32)f2bf(a0) | ((u32)f2bf(a1) << 16);
            o.y = (u32)f2bf(a2) | ((u32)f2bf(a3) << 16);
            *(uint2*)((u32*)(ctxb + ((size_t)bm_l * T_ + tt) * D_) + cu * 2) = o;
        }
    }
}

// ============ fused self-attention + combine + si, one block per (n,h) ==============
__global__ __launch_bounds__(256) void siatt_kernel(
    const float* __restrict__ xemb, const float* __restrict__ att_sum,
    const float* __restrict__ attf, u16* __restrict__ sib)
{
    __shared__ float sX[16][516];
    __shared__ float sS[16][17];
    __shared__ float sA[16][17];
    int n = blockIdx.x >> 3, h = blockIdx.x & 7;
    int tid = threadIdx.x;
    int t = tid >> 4, ch = (tid & 15) * 32;
    const float* src = xemb + ((size_t)n * T_ + t) * D_;
    #pragma unroll
    for (int c = 0; c < 8; ++c)
        *(float4*)&sX[t][ch + c * 4] = *(const float4*)(src + ch + c * 4);
    __syncthreads();
    int q = tid >> 4, k = tid & 15;
    {
        float acc = 0.f;
        for (int d4 = 0; d4 < D_ / 4; ++d4) {
            float4 xq = *(const float4*)&sX[q][d4 * 4];
            float4 xk = *(const float4*)&sX[k][d4 * 4];
            acc += xq.x * xk.x;
            acc += xq.y * xk.y;
            acc += xq.z * xk.z;
            acc += xq.w * xk.w;
        }
        sS[q][k] = acc * 0.04419417382415922f;
    }
    __syncthreads();
    if (tid < T_) {
        float mx = -3.4e38f;
        #pragma unroll
        for (int kk = 0; kk < 16; ++kk) mx = fmaxf(mx, sS[tid][kk]);
        float e[16], s = 0.f;
        #pragma unroll
        for (int kk = 0; kk < 16; ++kk) { e[kk] = expf(sS[tid][kk] - mx); s += e[kk]; }
        float inv = 1.0f / s;
        #pragma unroll
        for (int kk = 0; kk < 16; ++kk) sS[tid][kk] = e[kk] * inv;
    }
    __syncthreads();
    float f = attf[0] * (1.0f / 32.0f);
    sA[q][k] = sS[q][k] + f * att_sum[((size_t)n * H_ + h) * 256 + q * 16 + k];
    __syncthreads();
    #pragma unroll
    for (int rep = 0; rep < 16; ++rep) {
        int i2 = rep * 256 + tid;          // q*256 + d2
        int qq = i2 >> 8, d2 = (i2 & 255) * 2;
        const float* ar = &sA[qq][0];
        float a0 = 0.f, a1 = 0.f;
        #pragma unroll
        for (int tt = 0; tt < 16; ++tt) {
            float p = ar[tt];
            a0 += p * sX[tt][d2];
            a1 += p * sX[tt][d2 + 1];
        }
        u32 o = (u32)f2bf(a0) | ((u32)f2bf(a1) << 16);
        *((u32*)(sib + (size_t)n * T_ * 4096 + (size_t)qq * 4096 + h * 512) + (d2 >> 1)) = o;
    }
}

// ---------------- positional encoding ------------------------------------------------
__global__ void pe_kernel(float* pe) {
    int i = blockIdx.x * blockDim.x + threadIdx.x;
    if (i >= T_ * 256) return;
    int t = i >> 8, j = i & 255;
    float dv = (float)pow(10000.0, (double)j / 256.0);
    float a = (float)t * dv;
    double ad = (double)a;
    pe[t * D_ + 2 * j]     = (float)sin(ad);
    pe[t * D_ + 2 * j + 1] = (float)cos(ad);
}

// ---------------- x features + embed (r10: row-per-wave, float4 stores) --------------
__global__ __launch_bounds__(256) void xemb_kernel(
    const float* __restrict__ x, const float* __restrict__ Wx,
    const float* __restrict__ bx, const float* __restrict__ pe,
    float* __restrict__ xemb) {
    int row = blockIdx.x * 4 + (threadIdx.x >> 6);   // t*N + n
    if (row >= T_ * N_) return;
    int lane = threadIdx.x & 63;
    int t = row / N_, n = row % N_;
    float x0 = x[row * 6 + 0], x1 = x[row * 6 + 1];
    float x2 = x[row * 6 + 2], x3 = x[row * 6 + 3];
    float x4 = x[row * 6 + 4], x5 = x[row * 6 + 5];
    float vel = sqrtf(x2 * x2 + x3 * x3);
    float ang = atanf(x5 / x4);
    float f0 = ntn(x0), f1 = ntn(x1), f2 = ntn(vel), f3 = ntn(ang);
    int d0 = lane * 8;
    float o[8];
    #pragma unroll
    for (int r = 0; r < 8; ++r) {
        int d = d0 + r;
        o[r] = f0 * Wx[0 * D_ + d] + f1 * Wx[1 * D_ + d]
             + f2 * Wx[2 * D_ + d] + f3 * Wx[3 * D_ + d]
             + bx[d] + pe[t * D_ + d];
    }
    float* dst = xemb + ((size_t)n * T_ + t) * D_ + d0;
    float4 w0 = {o[0], o[1], o[2], o[3]};
    float4 w1 = {o[4], o[5], o[6], o[7]};
    *(float4*)dst = w0;
    *(float4*)(dst + 4) = w1;
}

// ---------------- neighbor features + mask -------------------------------------------
__global__ void nbr_kernel(const float* x, const float* nbr, float* nf, float* maskf) {
    int idx = blockIdx.x * blockDim.x + threadIdx.x;   // t*N*NN + n*NN + m
    if (idx >= T_ * N_ * NN_) return;
    int m = idx % NN_;
    int tn = idx / NN_;
    int n = tn % N_, t = tn / N_;
    float px = x[((size_t)t * N_ + n) * 6 + 0];
    float py = x[((size_t)t * N_ + n) * 6 + 1];
    float vx, vy;
    if (t == 0) {
        vx = x[((size_t)1 * N_ + n) * 6 + 2];
        vy = x[((size_t)1 * N_ + n) * 6 + 3];
    } else {
        vx = px - x[((size_t)(t - 1) * N_ + n) * 6 + 0];
        vy = py - x[((size_t)(t - 1) * N_ + n) * 6 + 1];
    }
    float nx  = nbr[(size_t)idx * 4 + 0], ny  = nbr[(size_t)idx * 4 + 1];
    float nvx = nbr[(size_t)idx * 4 + 2], nvy = nbr[(size_t)idx * 4 + 3];
    float dpx = nx - px, dpy = ny - py;
    float dvx = nvx - vx, dvy = nvy - vy;
    float dist = sqrtf(dpx * dpx + dpy * dpy);
    maskf[((size_t)n * NN_ + m) * T_ + t] = (dist <= 2.0f) ? 1.0f : 0.0f;
    float vn = sqrtf(vx * vx + vy * vy);
    float bearing = (dpx * vx + dpy * vy) / (dist * vn);
    if (isnan(bearing)) bearing = 0.0f;
    float dvn = sqrtf(dvx * dvx + dvy * dvy);
    float tau = -(dpx * dvx + dpy * dvy) / dvn;
    if (isnan(tau)) tau = 0.0f;
    tau = fminf(fmaxf(tau, 0.0f), 7.0f);
    float mx_ = dpx + tau * dvx, my_ = dpy + tau * dvy;
    float mpd = sqrtf(mx_ * mx_ + my_ * my_);
    nf[(size_t)idx * 3 + 0] = ntn(dist);
    nf[(size_t)idx * 3 + 1] = ntn(bearing);
    nf[(size_t)idx * 3 + 2] = ntn(mpd);
}

// ---------------- neighbor embed (r10: row-per-wave, short8 store) -------------------
__global__ __launch_bounds__(256) void nemb_kernel(
    const float* __restrict__ nf, const float* __restrict__ Wn,
    const float* __restrict__ bn, const float* __restrict__ pe,
    u16* __restrict__ Ab) {
    int row = blockIdx.x * 4 + (threadIdx.x >> 6);   // (b*NN+m)*T + t
    if (row >= N_ * NN_ * T_) return;
    int lane = threadIdx.x & 63;
    int t = row % T_;
    int bm = row / T_;
    int m = bm % NN_, b = bm / NN_;
    size_t nfrow = (((size_t)t * N_ + b) * NN_ + m) * 3;
    float f0 = nf[nfrow], f1 = nf[nfrow + 1], f2 = nf[nfrow + 2];
    int d0 = lane * 8;
    short8 w;
    #pragma unroll
    for (int r = 0; r < 8; ++r) {
        int d = d0 + r;
        float v = f0 * Wn[d] + f1 * Wn[D_ + d] + f2 * Wn[2 * D_ + d]
                + bn[d] + pe[t * D_ + d];
        w[r] = (short)f2bf(v);
    }
    *(short8*)(Ab + (size_t)row * D_ + d0) = w;
}

// ---------------- LayerNorm, one wave per row; input f32 or bf16; dual out -----------
template<int INBF>
__global__ __launch_bounds__(256) void ln_kernel(
    const void* X, const float* g, const float* b, float* outF, u16* outB, int nrows) {
    int row = blockIdx.x * 4 + (threadIdx.x >> 6);
    if (row >= nrows) return;
    int lane = threadIdx.x & 63;
    int d0 = lane * 8;
    float v[8];
    if (INBF) {
        short8 x8 = *(const short8*)((const u16*)X + (size_t)row * D_ + d0);
        #pragma unroll
        for (int r = 0; r < 8; ++r) v[r] = bfv((u16)x8[r]);
    } else {
        float4 a = *(const float4*)((const float*)X + (size_t)row * D_ + d0);
        float4 c = *(const float4*)((const float*)X + (size_t)row * D_ + d0 + 4);
        v[0] = a.x; v[1] = a.y; v[2] = a.z; v[3] = a.w;
        v[4] = c.x; v[5] = c.y; v[6] = c.z; v[7] = c.w;
    }
    float s = 0.f;
    #pragma unroll
    for (int r = 0; r < 8; ++r) s += v[r];
    s = wave_sum(s);
    float mean = s * (1.0f / 512.0f);
    float vs = 0.f;
    #pragma unroll
    for (int r = 0; r < 8; ++r) { float d = v[r] - mean; vs += d * d; }
    vs = wave_sum(vs);
    float rstd = rsqrtf(vs * (1.0f / 512.0f) + 1e-5f);
    float4 g0 = *(const float4*)&g[d0], g1 = *(const float4*)&g[d0 + 4];
    float4 b0 = *(const float4*)&b[d0], b1 = *(const float4*)&b[d0 + 4];
    float o[8];
    o[0] = (v[0] - mean) * rstd * g0.x + b0.x;
    o[1] = (v[1] - mean) * rstd * g0.y + b0.y;
    o[2] = (v[2] - mean) * rstd * g0.z + b0.z;
    o[3] = (v[3] - mean) * rstd * g0.w + b0.w;
    o[4] = (v[4] - mean) * rstd * g1.x + b1.x;
    o[5] = (v[5] - mean) * rstd * g1.y + b1.y;
    o[6] = (v[6] - mean) * rstd * g1.z + b1.z;
    o[7] = (v[7] - mean) * rstd * g1.w + b1.w;
    if (outF) {
        float4 w0 = {o[0], o[1], o[2], o[3]};
        float4 w1 = {o[4], o[5], o[6], o[7]};
        *(float4*)(outF + (size_t)row * D_ + d0) = w0;
        *(float4*)(outF + (size_t)row * D_ + d0 + 4) = w1;
    }
    if (outB) {
        short8 w;
        #pragma unroll
        for (int r = 0; r < 8; ++r) w[r] = (short)f2bf(o[r]);
        *(short8*)(outB + (size_t)row * D_ + d0) = w;
    }
}

extern "C" void kernel_launch(void* const* d_in, const int* in_sizes, int n_in,
                              void* d_out, int out_size, void* d_ws, size_t ws_size,
                              hipStream_t stream) {
    (void)in_sizes; (void)n_in; (void)out_size; (void)ws_size;

    const float* x    = (const float*)d_in[0];
    const float* nbr  = (const float*)d_in[1];
    const float* attf = (const float*)d_in[2];
    const float* Wx   = (const float*)d_in[3];
    const float* bx   = (const float*)d_in[4];
    const float* Wn   = (const float*)d_in[5];
    const float* bn   = (const float*)d_in[6];
    const float* Wp   = (const float*)d_in[7];
    const float* bp   = (const float*)d_in[8];
    const float* WQ   = (const float*)d_in[9];
    const float* WK   = (const float*)d_in[10];
    const float* WV   = (const float*)d_in[11];
    const float* Wfc  = (const float*)d_in[12];
    const float* mlng = (const float*)d_in[13];
    const float* mlnb = (const float*)d_in[14];
    const float* WSI  = (const float*)d_in[15];
    const float* fsw1 = (const float*)d_in[16];
    const float* fsw2 = (const float*)d_in[17];
    const float* fsg  = (const float*)d_in[18];
    const float* fsb  = (const float*)d_in[19];
    const float* fiw1 = (const float*)d_in[20];
    const float* fiw2 = (const float*)d_in[21];
    const float* fig  = (const float*)d_in[22];
    const float* fib  = (const float*)d_in[23];

    char* w = (char*)d_ws;
    size_t off = 0;
    auto alloc = [&](size_t bytes) -> void* {
        void* p = w + off;
        off = (off + bytes + 255) & ~(size_t)255;
        return p;
    };
    const size_t MiB = 1024 * 1024;

    const int BM = N_ * NN_;          // 2048 (b,m) pairs
    const int ROWS_I = BM * T_;       // 32768 neighbor rows
    const int CB = 1024;              // bm per chunk (NCH=2, l=0 only)
    const int RC = CB * T_;           // 16384 rows per chunk
    const int NCH = ROWS_I / RC;      // 2

    float* pe      = (float*)alloc((size_t)T_ * D_ * 4);
    float* xemb    = (float*)alloc((size_t)N_ * T_ * D_ * 4);
    float* nf      = (float*)alloc((size_t)T_ * N_ * NN_ * 3 * 4);
    float* maskf   = (float*)alloc((size_t)BM * T_ * 4);
    u16*   Ab      = (u16*)alloc((size_t)ROWS_I * D_ * 2);     // n_emb bf16  32 MiB
    u16* tQKV[2], *tWSI[2], *tfs1[2], *tfs2[2];
    for (int l = 0; l < 2; ++l) {
        tQKV[l] = (u16*)alloc((size_t)1536 * 512 * 2);
        tWSI[l] = (u16*)alloc((size_t)512 * 4096 * 2);
        tfs1[l] = (u16*)alloc((size_t)2048 * 512 * 2);
        tfs2[l] = (u16*)alloc((size_t)512 * 2048 * 2);
    }
    u16* tWfc = (u16*)alloc((size_t)512 * 512 * 2);
    u16* tfi1 = (u16*)alloc((size_t)2048 * 512 * 2);
    u16* tfi2 = (u16*)alloc((size_t)512 * 2048 * 2);
    // scratch union: l0 chunk: QKVb 48 + ctxb 16 | hid 64 ; l1: QK full 64 MiB
    // ffs phase: hid(ffs) 4 MiB @ SCR+0, WSI partials 16 MiB @ SCR+16MiB,
    // fs2 partials 16 MiB @ SCR+32MiB
    char* SCR  = (char*)alloc(64 * MiB);
    u16*   QKVb = (u16*)SCR;
    u16*   ctxb = (u16*)(SCR + 48 * MiB);
    u16*   hid  = (u16*)SCR;
    float* Pw   = (float*)(SCR + 16 * MiB);
    float* Pk2  = (float*)(SCR + 32 * MiB);
    u16*   BbA    = (u16*)alloc((size_t)RC * D_ * 2);  // pre-LN bf16 chunk    16 MiB
    u16*   Bb_res = (u16*)alloc((size_t)RC * D_ * 2);  // res_inter bf16       16 MiB
    float* att_sum = (float*)alloc((size_t)N_ * H_ * 256 * 4);
    u16*   sib     = (u16*)alloc((size_t)N_ * T_ * 4096 * 2);  // 8 MiB
    u16*   xnb     = (u16*)alloc((size_t)N_ * T_ * D_ * 2);
    // total ~168 MiB

    // ---- batched weight conversion: 14 jobs, one launch ----
    WJobs jobs;
    int ntiles = 0;
    auto addJob = [&](int idx, const float* src, u16* dst, int K, int N) {
        jobs.j[idx] = {src, dst, K, N, ntiles};
        ntiles += (N >> 5) * (K >> 5);
    };
    addJob(0,  WQ,                            tQKV[0],              512, 512);
    addJob(1,  WK,                            tQKV[0] + 512 * 512,  512, 512);
    addJob(2,  WV,                            tQKV[0] + 1024 * 512, 512, 512);   // dead at l=1
    addJob(3,  WQ + (size_t)512 * 512,        tQKV[1],              512, 512);
    addJob(4,  WK + (size_t)512 * 512,        tQKV[1] + 512 * 512,  512, 512);
    addJob(5,  Wfc,                           tWfc,                 512, 512);
    addJob(6,  WSI,                           tWSI[0],              4096, 512);
    addJob(7,  WSI + (size_t)4096 * 512,      tWSI[1],              4096, 512);
    addJob(8,  fsw1,                          tfs1[0],              512, 2048);
    addJob(9,  fsw1 + (size_t)512 * 2048,     tfs1[1],              512, 2048);
    addJob(10, fsw2,                          tfs2[0],              2048, 512);
    addJob(11, fsw2 + (size_t)2048 * 512,     tfs2[1],              2048, 512);
    addJob(12, fiw1,                          tfi1,                 512, 2048);
    addJob(13, fiw2,                          tfi2,                 2048, 512);
    wconv_all<<<ntiles, 256, 0, stream>>>(jobs, ntiles);

    pe_kernel<<<16, 256, 0, stream>>>(pe);
    xemb_kernel<<<(T_ * N_) / 4, 256, 0, stream>>>(x, Wx, bx, pe, xemb);
    nbr_kernel<<<(T_ * N_ * NN_ + 255) / 256, 256, 0, stream>>>(x, nbr, nf, maskf);
    nemb_kernel<<<(BM * T_) / 4, 256, 0, stream>>>(nf, Wn, bn, pe, Ab);

    for (int l = 0; l < L_; ++l) {
        hipMemsetAsync(att_sum, 0, (size_t)N_ * H_ * 256 * 4, stream);
        if (l == 0) {
            for (int c = 0; c < NCH; ++c) {
                u16* Acb = Ab + (size_t)c * RC * D_;
                // QKV fused GEMM: N=1536 (1536 blocks = 3 exact rounds @2/CU)
                gemm_ct<0, 0, 1><<<dim3(12, RC / 128), 256, 0, stream>>>(
                    Acb, tQKV[0], nullptr, QKVb, nullptr, 512, 1536);
                attn_fused_kernel<1, 1536><<<CB, 256, 0, stream>>>(
                    QKVb, maskf, c * CB, att_sum, ctxb);
                // fc + residual(n_emb bf16) -> pre-LN bf16 (512 blocks = 1 round)
                gemm_ct<3, 0, 1><<<dim3(4, RC / 128), 256, 0, stream>>>(
                    ctxb, tWfc, nullptr, BbA, Acb, 512, 512);
                ln_kernel<1><<<RC / 4, 256, 0, stream>>>(
                    BbA, mlng, mlnb, nullptr, Bb_res, RC);   // res_inter bf16
                // ffi1 relu: N=2048 (2048 blocks = 4 exact rounds)
                gemm_ct<1, 0, 1><<<dim3(16, RC / 128), 256, 0, stream>>>(
                    Bb_res, tfi1, nullptr, hid, nullptr, 512, 2048);
                // ffi2 + residual(res_inter bf16) -> pre-LN bf16 (512 blocks)
                gemm_ct<3, 0, 1><<<dim3(4, RC / 128), 256, 0, stream>>>(
                    hid, tfi2, nullptr, BbA, Bb_res, 2048, 512);
                ln_kernel<1><<<RC / 4, 256, 0, stream>>>(
                    BbA, fig, fib, nullptr, Acb, RC);        // new n_emb (bf16)
            }
        } else {
            // l=1: unchunked QK (N=1024, ldc=1024; 64 MiB = SCR): 2048 blocks
            gemm_ct<0, 0, 1><<<dim3(8, ROWS_I / 128), 256, 0, stream>>>(
                Ab, tQKV[1], nullptr, QKVb, nullptr, 512, 1024);
            attn_fused_kernel<0, 1024><<<BM, 256, 0, stream>>>(
                QKVb, maskf, 0, att_sum, nullptr);
        }

        // ---- self-attention + si + ffs (split-K; WSI partials kept live) ----
        siatt_kernel<<<N_ * H_, 256, 0, stream>>>(xemb, att_sum, attf, sib);
        // WSI partials (M=1024, N=512, K=4096): NS=8 -> 256 blocks, Kc=512
        gemm_ks<8><<<dim3(4, 8, 8), 256, 0, stream>>>(sib, tWSI[l], Pw, 4096, 512);
        // xnb = bf16(sum of WSI partials)  (xnew f32 round-trip eliminated)
        ksum_kernel<8, 0, 0, 1><<<512, 256, 0, stream>>>(
            Pw, nullptr, nullptr, xnb, 1024 * 512);
        // hid = relu(xnb @ tfs1) (M=1024, N=2048, K=512): direct gemm_ct, 128 blocks
        gemm_ct<1, 0, 1><<<dim3(16, 8), 256, 0, stream>>>(
            xnb, tfs1[l], nullptr, hid, nullptr, 512, 2048);
        // fs2 partials; then fused reduce(fs2)+reduce(WSI residual)+LN [+pred head]
        gemm_ks<8><<<dim3(4, 8, 8), 256, 0, stream>>>(hid, tfs2[l], Pk2, 2048, 512);
        if (l == 0) {
            ksln_kernel<8, 0><<<256, 256, 0, stream>>>(
                Pk2, Pw, fsg, fsb, xemb, nullptr, nullptr, nullptr, 1024);
        } else {
            ksln_kernel<8, 1><<<256, 256, 0, stream>>>(
                Pk2, Pw, fsg + D_, fsb + D_, nullptr, Wp, bp, (float*)d_out, 1024);
        }
    }
}

// Round 13
// 709.996 us; speedup vs baseline: 1.2035x; 1.0035x over previous
//
#include <hip/hip_runtime.h>
#include <math.h>

// DTYPE COMMITMENTS (evidence-backed): inputs f32, output f32 (rounds 4-14 PASS).
// WS BUDGET: <= ~210 MB decimal; this build ~168 MiB (partials alias SCR).
// r13: final launch-elimination bundle (numerics-identical): pe fused into
// wconv_all tail blocks; xemb+nbr merged (independent, both read x); att_sum
// self-zeroed in siatt (each entry read by exactly one thread -> write 0 after
// read), single pre-loop memset. GEMMs frozen (8-phase 0/4, abandoned).

#define T_ 16
#define N_ 64
#define NN_ 32
#define D_ 512
#define H_ 8
#define DK_ 64
#define DFF_ 2048
#define L_ 2
#define NPRED_ 20

typedef unsigned short u16;
typedef unsigned int u32;
typedef __attribute__((ext_vector_type(8))) short short8;
typedef __attribute__((ext_vector_type(4))) float f32x4;

__device__ __forceinline__ u16 f2bf(float f) {
    u32 u = __float_as_uint(f);
    u32 r = u + 0x7fffu + ((u >> 16) & 1u);
    return (u16)(r >> 16);
}
__device__ __forceinline__ float bfv(u16 v) {
    return __uint_as_float(((u32)v) << 16);
}
__device__ __forceinline__ float ntn(float v) {
    if (isnan(v)) return 0.0f;
    if (isinf(v)) return v > 0.0f ? 3.4028234663852886e38f : -3.4028234663852886e38f;
    return v;
}
__device__ __forceinline__ float wave_sum(float v) {
    #pragma unroll
    for (int o = 32; o > 0; o >>= 1) v += __shfl_xor(v, o, 64);
    return v;
}
// async 16B HBM->LDS: writes ldsbase + lane*16 (wave-uniform base, per-lane gptr)
__device__ __forceinline__ void gload_lds(const u16* g, u16* l) {
    __builtin_amdgcn_global_load_lds(
        (const __attribute__((address_space(1))) u32*)g,
        (__attribute__((address_space(3))) u32*)l, 16, 0, 0);
}

// ============ batched weight convert+transpose + pe tail: ONE launch ================
struct WJob { const float* src; u16* dst; int K; int N; int t0; };
struct WJobs { WJob j[14]; };
__global__ __launch_bounds__(256) void wconv_all(WJobs jobs, int ntiles, float* pe) {
    int bid = blockIdx.x;
    if (bid >= ntiles) {
        // r13: pe tail blocks (16) -- exact pe_kernel math
        int i = (bid - ntiles) * 256 + threadIdx.x;
        if (i >= T_ * 256) return;
        int t = i >> 8, j = i & 255;
        float dv = (float)pow(10000.0, (double)j / 256.0);
        float a = (float)t * dv;
        double ad = (double)a;
        pe[t * D_ + 2 * j]     = (float)sin(ad);
        pe[t * D_ + 2 * j + 1] = (float)cos(ad);
        return;
    }
    int ji = 0;
    #pragma unroll 1
    for (int i = 1; i < 14; ++i) if (bid >= jobs.j[i].t0) ji = i;
    const float* in = jobs.j[ji].src;
    u16* out = jobs.j[ji].dst;
    int K = jobs.j[ji].K, N = jobs.j[ji].N;
    int lt = bid - jobs.j[ji].t0;
    int ntx = N >> 5;
    int nb = (lt % ntx) * 32, kb = (lt / ntx) * 32;
    __shared__ float tile[32][33];
    int tx = threadIdx.x & 31, ty = threadIdx.x >> 5;
    #pragma unroll
    for (int r = ty; r < 32; r += 8)
        tile[r][tx] = in[(size_t)(kb + r) * N + nb + tx];
    __syncthreads();
    #pragma unroll
    for (int r = ty; r < 32; r += 8)
        out[(size_t)(nb + r) * K + kb + tx] = f2bf(tile[tx][r]);
}

// ============ counted-pipeline GEMM: 128x128, BK=64, 2 barriers/tile (r4 best) ======
template<int EPI, int WF32, int WBF16>
__global__ __launch_bounds__(256, 2) void gemm_ct(
    const u16* __restrict__ Ab, const u16* __restrict__ Btb,
    float* __restrict__ Cf, u16* __restrict__ Cb, const void* __restrict__ Rg,
    int K, int ldc)
{
    __shared__ __align__(16) u16 As[2][128][64];
    __shared__ __align__(16) u16 Bs[2][128][64];
    int tid = threadIdx.x;
    int lane = tid & 63, wave = tid >> 6;       // 4 waves: 2M x 2N
    int quad = lane >> 4, l16 = lane & 15;
    int wm = (wave >> 1) * 64, wn = (wave & 1) * 64;

    int gx = gridDim.x, gy = gridDim.y;
    int id = blockIdx.y * gx + blockIdx.x;
    int xcd = id & 7, slot = id >> 3;
    int bx = slot % gx;
    int by = xcd * (gy >> 3) + slot / gx;
    size_t row0 = (size_t)by * 128;
    size_t col0 = (size_t)bx * 128;

    f32x4 acc[4][4];
    #pragma unroll
    for (int i = 0; i < 4; ++i)
        #pragma unroll
        for (int j = 0; j < 4; ++j)
            acc[i][j] = (f32x4){0.f, 0.f, 0.f, 0.f};

    // staging swizzle (r9-verified): physical 16B chunk p of row r holds logical
    // chunk p ^ (r&7)
    int srow = lane >> 3;
    int c8 = (lane & 7) ^ srow;
    int h8 = l16 & 7;
    size_t aoff[4], boff[4];
    #pragma unroll
    for (int it = 0; it < 4; ++it) {
        aoff[it] = (row0 + (size_t)(wave + it * 4) * 8 + srow) * (size_t)K + c8 * 8;
        boff[it] = (col0 + (size_t)(wave + it * 4) * 8 + srow) * (size_t)K + c8 * 8;
    }

    int nt = K >> 6;
    // prologue: stage tile 0 -> buf 0 (8 loads in flight, no wait)
    #pragma unroll
    for (int it = 0; it < 4; ++it)
        gload_lds(Ab + aoff[it], &As[0][(wave + it * 4) * 8][0]);
    #pragma unroll
    for (int it = 0; it < 4; ++it)
        gload_lds(Btb + boff[it], &Bs[0][(wave + it * 4) * 8][0]);

    #pragma unroll 1
    for (int t = 0; t < nt; ++t) {
        int cur = t & 1;
        if (t + 1 < nt) {
            // stage tile t+1 into other buffer (freed by iter t-1's end barrier)
            size_t ko = (size_t)(t + 1) * 64;
            #pragma unroll
            for (int it = 0; it < 4; ++it)
                gload_lds(Ab + aoff[it] + ko, &As[cur ^ 1][(wave + it * 4) * 8][0]);
            #pragma unroll
            for (int it = 0; it < 4; ++it)
                gload_lds(Btb + boff[it] + ko, &Bs[cur ^ 1][(wave + it * 4) * 8][0]);
            __builtin_amdgcn_sched_barrier(0);
            asm volatile("s_waitcnt vmcnt(8)" ::: "memory");   // tile t landed; t+1 in flight
        } else {
            __builtin_amdgcn_sched_barrier(0);
            asm volatile("s_waitcnt vmcnt(0)" ::: "memory");   // final tile only
        }
        __builtin_amdgcn_sched_barrier(0);
        __builtin_amdgcn_s_barrier();                          // rendezvous: tile t staged
        __builtin_amdgcn_sched_barrier(0);
        __builtin_amdgcn_s_setprio(1);
        #pragma unroll
        for (int kh = 0; kh < 2; ++kh) {
            int coff = ((kh * 4 + quad) ^ h8) * 8;
            short8 af[4], bf[4];
            #pragma unroll
            for (int j = 0; j < 4; ++j)
                bf[j] = *(short8*)&Bs[cur][wn + j * 16 + l16][coff];
            #pragma unroll
            for (int i = 0; i < 4; ++i)
                af[i] = *(short8*)&As[cur][wm + i * 16 + l16][coff];
            #pragma unroll
            for (int i = 0; i < 4; ++i)
                #pragma unroll
                for (int j = 0; j < 4; ++j)
                    acc[i][j] = __builtin_amdgcn_mfma_f32_16x16x32_bf16(
                        af[i], bf[j], acc[i][j], 0, 0, 0);
        }
        __builtin_amdgcn_s_setprio(0);
        __builtin_amdgcn_sched_barrier(0);                     // reads done before barrier
        __builtin_amdgcn_s_barrier();                          // frees buf[cur] for restage
    }

    // C/D layout (on-target verified): col = lane&15, row = quad*4 + reg
    #pragma unroll
    for (int i = 0; i < 4; ++i)
        #pragma unroll
        for (int j = 0; j < 4; ++j)
            #pragma unroll
            for (int reg = 0; reg < 4; ++reg) {
                size_t row = row0 + wm + i * 16 + quad * 4 + reg;
                size_t col = col0 + wn + j * 16 + l16;
                float v = acc[i][j][reg];
                if (EPI == 2) v += ((const float*)Rg)[row * (size_t)ldc + col];
                if (EPI == 3) v += bfv(((const u16*)Rg)[row * (size_t)ldc + col]);
                if (EPI == 1) v = fmaxf(v, 0.f);
                if (WF32)  Cf[row * (size_t)ldc + col] = v;
                if (WBF16) Cb[row * (size_t)ldc + col] = f2bf(v);
            }
}

// ============ split-K GEMM for small-M (ffs chain): gemm_ct schedule + z-split ======
template<int NS>
__global__ __launch_bounds__(256, 2) void gemm_ks(
    const u16* __restrict__ Ab, const u16* __restrict__ Btb,
    float* __restrict__ Pf, int K, int ldc)
{
    __shared__ __align__(16) u16 As[2][128][64];
    __shared__ __align__(16) u16 Bs[2][128][64];
    int tid = threadIdx.x;
    int lane = tid & 63, wave = tid >> 6;
    int quad = lane >> 4, l16 = lane & 15;
    int wm = (wave >> 1) * 64, wn = (wave & 1) * 64;

    int gx = gridDim.x, gy = gridDim.y;
    int id = blockIdx.y * gx + blockIdx.x;
    int xcd = id & 7, slot = id >> 3;
    int bx = slot % gx;
    int by = xcd * (gy >> 3) + slot / gx;
    int z = blockIdx.z;
    int Kc = K / NS;
    size_t row0 = (size_t)by * 128;
    size_t col0 = (size_t)bx * 128;
    size_t M = (size_t)gy * 128;

    f32x4 acc[4][4];
    #pragma unroll
    for (int i = 0; i < 4; ++i)
        #pragma unroll
        for (int j = 0; j < 4; ++j)
            acc[i][j] = (f32x4){0.f, 0.f, 0.f, 0.f};

    int srow = lane >> 3;
    int c8 = (lane & 7) ^ srow;
    int h8 = l16 & 7;
    size_t kbase = (size_t)z * Kc;
    size_t aoff[4], boff[4];
    #pragma unroll
    for (int it = 0; it < 4; ++it) {
        aoff[it] = (row0 + (size_t)(wave + it * 4) * 8 + srow) * (size_t)K + kbase + c8 * 8;
        boff[it] = (col0 + (size_t)(wave + it * 4) * 8 + srow) * (size_t)K + kbase + c8 * 8;
    }

    int nt = Kc >> 6;
    #pragma unroll
    for (int it = 0; it < 4; ++it)
        gload_lds(Ab + aoff[it], &As[0][(wave + it * 4) * 8][0]);
    #pragma unroll
    for (int it = 0; it < 4; ++it)
        gload_lds(Btb + boff[it], &Bs[0][(wave + it * 4) * 8][0]);

    #pragma unroll 1
    for (int t = 0; t < nt; ++t) {
        int cur = t & 1;
        if (t + 1 < nt) {
            size_t ko = (size_t)(t + 1) * 64;
            #pragma unroll
            for (int it = 0; it < 4; ++it)
                gload_lds(Ab + aoff[it] + ko, &As[cur ^ 1][(wave + it * 4) * 8][0]);
            #pragma unroll
            for (int it = 0; it < 4; ++it)
                gload_lds(Btb + boff[it] + ko, &Bs[cur ^ 1][(wave + it * 4) * 8][0]);
            __builtin_amdgcn_sched_barrier(0);
            asm volatile("s_waitcnt vmcnt(8)" ::: "memory");
        } else {
            __builtin_amdgcn_sched_barrier(0);
            asm volatile("s_waitcnt vmcnt(0)" ::: "memory");
        }
        __builtin_amdgcn_sched_barrier(0);
        __builtin_amdgcn_s_barrier();
        __builtin_amdgcn_sched_barrier(0);
        __builtin_amdgcn_s_setprio(1);
        #pragma unroll
        for (int kh = 0; kh < 2; ++kh) {
            int coff = ((kh * 4 + quad) ^ h8) * 8;
            short8 af[4], bf[4];
            #pragma unroll
            for (int j = 0; j < 4; ++j)
                bf[j] = *(short8*)&Bs[cur][wn + j * 16 + l16][coff];
            #pragma unroll
            for (int i = 0; i < 4; ++i)
                af[i] = *(short8*)&As[cur][wm + i * 16 + l16][coff];
            #pragma unroll
            for (int i = 0; i < 4; ++i)
                #pragma unroll
                for (int j = 0; j < 4; ++j)
                    acc[i][j] = __builtin_amdgcn_mfma_f32_16x16x32_bf16(
                        af[i], bf[j], acc[i][j], 0, 0, 0);
        }
        __builtin_amdgcn_s_setprio(0);
        __builtin_amdgcn_sched_barrier(0);
        __builtin_amdgcn_s_barrier();
    }

    float* P = Pf + (size_t)z * M * (size_t)ldc;
    #pragma unroll
    for (int i = 0; i < 4; ++i)
        #pragma unroll
        for (int j = 0; j < 4; ++j)
            #pragma unroll
            for (int reg = 0; reg < 4; ++reg) {
                size_t row = row0 + wm + i * 16 + quad * 4 + reg;
                size_t col = col0 + wn + j * 16 + l16;
                P[row * (size_t)ldc + col] = acc[i][j][reg];
            }
}

// ---- split-K reduce + epilogue: sum NS f32 partials; EPI 1=relu 2=+res; dual out --
template<int NS, int EPI, int WF32, int WBF16>
__global__ __launch_bounds__(256) void ksum_kernel(
    const float* __restrict__ P, const float* __restrict__ res,
    float* __restrict__ outF, u16* __restrict__ outB, int total)
{
    int i = blockIdx.x * blockDim.x + threadIdx.x;
    size_t o4 = (size_t)i * 4;
    if (o4 >= (size_t)total) return;
    float4 s = *(const float4*)(P + o4);
    #pragma unroll
    for (int p = 1; p < NS; ++p) {
        float4 v = *(const float4*)(P + (size_t)p * total + o4);
        s.x += v.x; s.y += v.y; s.z += v.z; s.w += v.w;
    }
    if (EPI == 2) {
        float4 r = *(const float4*)(res + o4);
        s.x += r.x; s.y += r.y; s.z += r.z; s.w += r.w;
    }
    if (EPI == 1) {
        s.x = fmaxf(s.x, 0.f); s.y = fmaxf(s.y, 0.f);
        s.z = fmaxf(s.z, 0.f); s.w = fmaxf(s.w, 0.f);
    }
    if (WF32) *(float4*)(outF + o4) = s;
    if (WBF16) {
        uint2 w;
        w.x = (u32)f2bf(s.x) | ((u32)f2bf(s.y) << 16);
        w.y = (u32)f2bf(s.z) | ((u32)f2bf(s.w) << 16);
        *(uint2*)(outB + o4) = w;
    }
}

// ---- fused split-K reduce (fs2 + WSI partial sets) + LN [+ pred head] (r12) -------
template<int NS, int PRED>
__global__ __launch_bounds__(256) void ksln_kernel(
    const float* __restrict__ P, const float* __restrict__ Pw,
    const float* __restrict__ g, const float* __restrict__ b,
    float* __restrict__ outF, const float* __restrict__ Wp,
    const float* __restrict__ bp, float* __restrict__ out, int nrows)
{
    int row = blockIdx.x * 4 + (threadIdx.x >> 6);
    if (row >= nrows) return;
    int lane = threadIdx.x & 63;
    int d0 = lane * 8;
    size_t base = (size_t)row * D_ + d0;
    size_t total = (size_t)nrows * D_;
    float v[8];
    {
        float4 a = *(const float4*)(P + base);
        float4 c = *(const float4*)(P + base + 4);
        v[0] = a.x; v[1] = a.y; v[2] = a.z; v[3] = a.w;
        v[4] = c.x; v[5] = c.y; v[6] = c.z; v[7] = c.w;
    }
    #pragma unroll
    for (int p = 1; p < NS; ++p) {
        float4 a = *(const float4*)(P + (size_t)p * total + base);
        float4 c = *(const float4*)(P + (size_t)p * total + base + 4);
        v[0] += a.x; v[1] += a.y; v[2] += a.z; v[3] += a.w;
        v[4] += c.x; v[5] += c.y; v[6] += c.z; v[7] += c.w;
    }
    // residual = WSI partial sum (same order as the ksum that produced xnb)
    float r8[8];
    {
        float4 a = *(const float4*)(Pw + base);
        float4 c = *(const float4*)(Pw + base + 4);
        r8[0] = a.x; r8[1] = a.y; r8[2] = a.z; r8[3] = a.w;
        r8[4] = c.x; r8[5] = c.y; r8[6] = c.z; r8[7] = c.w;
    }
    #pragma unroll
    for (int p = 1; p < NS; ++p) {
        float4 a = *(const float4*)(Pw + (size_t)p * total + base);
        float4 c = *(const float4*)(Pw + (size_t)p * total + base + 4);
        r8[0] += a.x; r8[1] += a.y; r8[2] += a.z; r8[3] += a.w;
        r8[4] += c.x; r8[5] += c.y; r8[6] += c.z; r8[7] += c.w;
    }
    #pragma unroll
    for (int r = 0; r < 8; ++r) v[r] += r8[r];

    float s = 0.f;
    #pragma unroll
    for (int r = 0; r < 8; ++r) s += v[r];
    s = wave_sum(s);
    float mean = s * (1.0f / 512.0f);
    float vs = 0.f;
    #pragma unroll
    for (int r = 0; r < 8; ++r) { float d = v[r] - mean; vs += d * d; }
    vs = wave_sum(vs);
    float rstd = rsqrtf(vs * (1.0f / 512.0f) + 1e-5f);
    float4 g0 = *(const float4*)&g[d0], g1 = *(const float4*)&g[d0 + 4];
    float4 b0 = *(const float4*)&b[d0], b1 = *(const float4*)&b[d0 + 4];
    float o[8];
    o[0] = (v[0] - mean) * rstd * g0.x + b0.x;
    o[1] = (v[1] - mean) * rstd * g0.y + b0.y;
    o[2] = (v[2] - mean) * rstd * g0.z + b0.z;
    o[3] = (v[3] - mean) * rstd * g0.w + b0.w;
    o[4] = (v[4] - mean) * rstd * g1.x + b1.x;
    o[5] = (v[5] - mean) * rstd * g1.y + b1.y;
    o[6] = (v[6] - mean) * rstd * g1.z + b1.z;
    o[7] = (v[7] - mean) * rstd * g1.w + b1.w;
    if (!PRED) {
        float4 w0 = {o[0], o[1], o[2], o[3]};
        float4 w1 = {o[4], o[5], o[6], o[7]};
        *(float4*)(outF + base) = w0;
        *(float4*)(outF + base + 4) = w1;
    } else {
        // prediction head: a_c = bp[c] + sum_d o_row[d] * Wp[d][c]
        float a0 = 0.f, a1 = 0.f;
        #pragma unroll
        for (int r = 0; r < 8; ++r) {
            int d = d0 + r;
            a0 += o[r] * Wp[(size_t)d * 2];
            a1 += o[r] * Wp[(size_t)d * 2 + 1];
        }
        a0 = wave_sum(a0);
        a1 = wave_sum(a1);
        a0 += bp[0];
        a1 += bp[1];
        int n = row / T_, t = row % T_;
        if (lane < NPRED_) {
            size_t off = (((size_t)lane * T_ + t) * N_ + n) * 2;
            out[off]     = a0;
            out[off + 1] = a1;
        }
    }
}

// ============ fused attention per (b,m): all-heads phases, 3 barriers ===============
// r7: QK^T via MFMA 16x16x32 (verified layout); S stays f32. ctx phase uint2.
template<int CTX, int LD>
__global__ __launch_bounds__(256) void attn_fused_kernel(
    const u16* __restrict__ QKVb, const float* __restrict__ maskf, int bm0,
    float* __restrict__ att_sum, u16* __restrict__ ctxb)
{
    __shared__ __align__(16) u16 sQ[16][520];
    __shared__ __align__(16) u16 sK[16][520];
    __shared__ __align__(16) u16 sV[CTX ? 16 : 1][520];
    __shared__ float s_p[H_][16][17];
    __shared__ float sMask[16];
    int bm_l = blockIdx.x;
    int tid = threadIdx.x;
    int t = tid >> 4, ch = (tid & 15) * 32;
    const u16* base = QKVb + ((size_t)bm_l * T_ + t) * LD;
    #pragma unroll
    for (int c = 0; c < 4; ++c) {
        *(uint4*)&sQ[t][ch + c * 8] = *(const uint4*)(base + ch + c * 8);
        *(uint4*)&sK[t][ch + c * 8] = *(const uint4*)(base + 512 + ch + c * 8);
        if (CTX) *(uint4*)&sV[t][ch + c * 8] = *(const uint4*)(base + 1024 + ch + c * 8);
    }
    if (tid < 16) sMask[tid] = maskf[(size_t)(bm0 + bm_l) * T_ + tid];
    __syncthreads();

    int b = (bm0 + bm_l) >> 5;                  // bm = b*NN + m
    int lane = tid & 63, wid = tid >> 6;
    int l16 = lane & 15, quad = lane >> 4;

    // QK^T: per wave heads {wid, wid+4}; S[q=quad*4+reg][kt=l16] = Q[q][:] . K[kt][:]
    #pragma unroll
    for (int hh = 0; hh < 2; ++hh) {
        int h = wid + hh * 4;
        short8 aq0 = *(const short8*)&sQ[l16][h * 64 + quad * 8];
        short8 aq1 = *(const short8*)&sQ[l16][h * 64 + 32 + quad * 8];
        short8 bk0 = *(const short8*)&sK[l16][h * 64 + quad * 8];
        short8 bk1 = *(const short8*)&sK[l16][h * 64 + 32 + quad * 8];
        f32x4 acc = (f32x4){0.f, 0.f, 0.f, 0.f};
        acc = __builtin_amdgcn_mfma_f32_16x16x32_bf16(aq0, bk0, acc, 0, 0, 0);
        acc = __builtin_amdgcn_mfma_f32_16x16x32_bf16(aq1, bk1, acc, 0, 0, 0);
        #pragma unroll
        for (int reg = 0; reg < 4; ++reg) {
            int q = quad * 4 + reg;
            float v = acc[reg] * 0.125f;
            if (sMask[q] == 0.0f) v = -1e9f;
            s_p[h][q][l16] = v;
        }
    }
    __syncthreads();
    if (tid < 128) {
        int h = tid >> 4, q = tid & 15;
        float mx = -3.4e38f;
        #pragma unroll
        for (int kk = 0; kk < 16; ++kk) mx = fmaxf(mx, s_p[h][q][kk]);
        float e[16], s = 0.f;
        #pragma unroll
        for (int kk = 0; kk < 16; ++kk) { e[kk] = expf(s_p[h][q][kk] - mx); s += e[kk]; }
        float inv = 1.0f / s;
        #pragma unroll
        for (int kk = 0; kk < 16; ++kk) s_p[h][q][kk] = e[kk] * inv;
    }
    __syncthreads();
    #pragma unroll
    for (int r = 0; r < 8; ++r) {
        int h = r;
        int q = (tid >> 4) & 15, k = tid & 15;
        atomicAdd(&att_sum[(((size_t)b * H_ + h) * T_ + q) * T_ + k], s_p[h][q][k]);
    }
    if (CTX) {
        // 4 consecutive cols (2 u32) per step: uint2 sV reads, uint2 ctxb writes
        #pragma unroll
        for (int rep = 0; rep < 8; ++rep) {
            int i2 = rep * 256 + tid;           // t*128 + cu, cu = uint2 col index
            int tt = i2 >> 7, cu = i2 & 127;
            int h = cu >> 4;                    // (cu*2)>>5; pair never crosses a head
            const float* pr = &s_p[h][tt][0];
            float a0 = 0.f, a1 = 0.f, a2 = 0.f, a3 = 0.f;
            #pragma unroll
            for (int kk = 0; kk < 16; ++kk) {
                uint2 vv = *((const uint2*)&sV[kk][0] + cu);
                float p = pr[kk];
                a0 += p * bfv((u16)(vv.x & 0xffff));
                a1 += p * bfv((u16)(vv.x >> 16));
                a2 += p * bfv((u16)(vv.y & 0xffff));
                a3 += p * bfv((u16)(vv.y >> 16));
            }
            uint2 o;
            o.x = (u32)f2bf(a0) | ((u32)f2bf(a1) << 16);
            o.y = (u32)f2bf(a2) | ((u32)f2bf(a3) << 16);
            *(uint2*)((u32*)(ctxb + ((size_t)bm_l * T_ + tt) * D_) + cu * 2) = o;
        }
    }
}

// ============ fused self-attention + combine + si, one block per (n,h) ==============
// r13: att_sum self-zeroing -- each entry read by exactly one thread; write 0 after
// the read (replaces the per-layer memset; pre-loop memset handles launch start).
__global__ __launch_bounds__(256) void siatt_kernel(
    const float* __restrict__ xemb, float* __restrict__ att_sum,
    const float* __restrict__ attf, u16* __restrict__ sib)
{
    __shared__ float sX[16][516];
    __shared__ float sS[16][17];
    __shared__ float sA[16][17];
    int n = blockIdx.x >> 3, h = blockIdx.x & 7;
    int tid = threadIdx.x;
    int t = tid >> 4, ch = (tid & 15) * 32;
    const float* src = xemb + ((size_t)n * T_ + t) * D_;
    #pragma unroll
    for (int c = 0; c < 8; ++c)
        *(float4*)&sX[t][ch + c * 4] = *(const float4*)(src + ch + c * 4);
    __syncthreads();
    int q = tid >> 4, k = tid & 15;
    {
        float acc = 0.f;
        for (int d4 = 0; d4 < D_ / 4; ++d4) {
            float4 xq = *(const float4*)&sX[q][d4 * 4];
            float4 xk = *(const float4*)&sX[k][d4 * 4];
            acc += xq.x * xk.x;
            acc += xq.y * xk.y;
            acc += xq.z * xk.z;
            acc += xq.w * xk.w;
        }
        sS[q][k] = acc * 0.04419417382415922f;
    }
    __syncthreads();
    if (tid < T_) {
        float mx = -3.4e38f;
        #pragma unroll
        for (int kk = 0; kk < 16; ++kk) mx = fmaxf(mx, sS[tid][kk]);
        float e[16], s = 0.f;
        #pragma unroll
        for (int kk = 0; kk < 16; ++kk) { e[kk] = expf(sS[tid][kk] - mx); s += e[kk]; }
        float inv = 1.0f / s;
        #pragma unroll
        for (int kk = 0; kk < 16; ++kk) sS[tid][kk] = e[kk] * inv;
    }
    __syncthreads();
    float f = attf[0] * (1.0f / 32.0f);
    {
        size_t asidx = ((size_t)n * H_ + h) * 256 + q * 16 + k;
        float av = att_sum[asidx];
        sA[q][k] = sS[q][k] + f * av;
        att_sum[asidx] = 0.f;              // r13: self-zero for next layer
    }
    __syncthreads();
    #pragma unroll
    for (int rep = 0; rep < 16; ++rep) {
        int i2 = rep * 256 + tid;          // q*256 + d2
        int qq = i2 >> 8, d2 = (i2 & 255) * 2;
        const float* ar = &sA[qq][0];
        float a0 = 0.f, a1 = 0.f;
        #pragma unroll
        for (int tt = 0; tt < 16; ++tt) {
            float p = ar[tt];
            a0 += p * sX[tt][d2];
            a1 += p * sX[tt][d2 + 1];
        }
        u32 o = (u32)f2bf(a0) | ((u32)f2bf(a1) << 16);
        *((u32*)(sib + (size_t)n * T_ * 4096 + (size_t)qq * 4096 + h * 512) + (d2 >> 1)) = o;
    }
}

// ---------------- x features + embed AND neighbor features, one launch (r13) --------
// blocks 0..255: xemb rows (4/block, row-per-wave, float4 stores).
// blocks 256..383: nbr indices (256/block). Both read only x/nbr -> independent.
__global__ __launch_bounds__(256) void xnbr_kernel(
    const float* __restrict__ x, const float* __restrict__ Wx,
    const float* __restrict__ bx, const float* __restrict__ pe,
    float* __restrict__ xemb, const float* __restrict__ nbr,
    float* __restrict__ nf, float* __restrict__ maskf) {
    if (blockIdx.x < 256) {
        int row = blockIdx.x * 4 + (threadIdx.x >> 6);   // t*N + n
        if (row >= T_ * N_) return;
        int lane = threadIdx.x & 63;
        int t = row / N_, n = row % N_;
        float x0 = x[row * 6 + 0], x1 = x[row * 6 + 1];
        float x2 = x[row * 6 + 2], x3 = x[row * 6 + 3];
        float x4 = x[row * 6 + 4], x5 = x[row * 6 + 5];
        float vel = sqrtf(x2 * x2 + x3 * x3);
        float ang = atanf(x5 / x4);
        float f0 = ntn(x0), f1 = ntn(x1), f2 = ntn(vel), f3 = ntn(ang);
        int d0 = lane * 8;
        float o[8];
        #pragma unroll
        for (int r = 0; r < 8; ++r) {
            int d = d0 + r;
            o[r] = f0 * Wx[0 * D_ + d] + f1 * Wx[1 * D_ + d]
                 + f2 * Wx[2 * D_ + d] + f3 * Wx[3 * D_ + d]
                 + bx[d] + pe[t * D_ + d];
        }
        float* dst = xemb + ((size_t)n * T_ + t) * D_ + d0;
        float4 w0 = {o[0], o[1], o[2], o[3]};
        float4 w1 = {o[4], o[5], o[6], o[7]};
        *(float4*)dst = w0;
        *(float4*)(dst + 4) = w1;
        return;
    }
    int idx = (blockIdx.x - 256) * 256 + threadIdx.x;   // t*N*NN + n*NN + m
    if (idx >= T_ * N_ * NN_) return;
    int m = idx % NN_;
    int tn = idx / NN_;
    int n = tn % N_, t = tn / N_;
    float px = x[((size_t)t * N_ + n) * 6 + 0];
    float py = x[((size_t)t * N_ + n) * 6 + 1];
    float vx, vy;
    if (t == 0) {
        vx = x[((size_t)1 * N_ + n) * 6 + 2];
        vy = x[((size_t)1 * N_ + n) * 6 + 3];
    } else {
        vx = px - x[((size_t)(t - 1) * N_ + n) * 6 + 0];
        vy = py - x[((size_t)(t - 1) * N_ + n) * 6 + 1];
    }
    float nx  = nbr[(size_t)idx * 4 + 0], ny  = nbr[(size_t)idx * 4 + 1];
    float nvx = nbr[(size_t)idx * 4 + 2], nvy = nbr[(size_t)idx * 4 + 3];
    float dpx = nx - px, dpy = ny - py;
    float dvx = nvx - vx, dvy = nvy - vy;
    float dist = sqrtf(dpx * dpx + dpy * dpy);
    maskf[((size_t)n * NN_ + m) * T_ + t] = (dist <= 2.0f) ? 1.0f : 0.0f;
    float vn = sqrtf(vx * vx + vy * vy);
    float bearing = (dpx * vx + dpy * vy) / (dist * vn);
    if (isnan(bearing)) bearing = 0.0f;
    float dvn = sqrtf(dvx * dvx + dvy * dvy);
    float tau = -(dpx * dvx + dpy * dvy) / dvn;
    if (isnan(tau)) tau = 0.0f;
    tau = fminf(fmaxf(tau, 0.0f), 7.0f);
    float mx_ = dpx + tau * dvx, my_ = dpy + tau * dvy;
    float mpd = sqrtf(mx_ * mx_ + my_ * my_);
    nf[(size_t)idx * 3 + 0] = ntn(dist);
    nf[(size_t)idx * 3 + 1] = ntn(bearing);
    nf[(size_t)idx * 3 + 2] = ntn(mpd);
}

// ---------------- neighbor embed (r10: row-per-wave, short8 store) -------------------
__global__ __launch_bounds__(256) void nemb_kernel(
    const float* __restrict__ nf, const float* __restrict__ Wn,
    const float* __restrict__ bn, const float* __restrict__ pe,
    u16* __restrict__ Ab) {
    int row = blockIdx.x * 4 + (threadIdx.x >> 6);   // (b*NN+m)*T + t
    if (row >= N_ * NN_ * T_) return;
    int lane = threadIdx.x & 63;
    int t = row % T_;
    int bm = row / T_;
    int m = bm % NN_, b = bm / NN_;
    size_t nfrow = (((size_t)t * N_ + b) * NN_ + m) * 3;
    float f0 = nf[nfrow], f1 = nf[nfrow + 1], f2 = nf[nfrow + 2];
    int d0 = lane * 8;
    short8 w;
    #pragma unroll
    for (int r = 0; r < 8; ++r) {
        int d = d0 + r;
        float v = f0 * Wn[d] + f1 * Wn[D_ + d] + f2 * Wn[2 * D_ + d]
                + bn[d] + pe[t * D_ + d];
        w[r] = (short)f2bf(v);
    }
    *(short8*)(Ab + (size_t)row * D_ + d0) = w;
}

// ---------------- LayerNorm, one wave per row; input f32 or bf16; dual out -----------
template<int INBF>
__global__ __launch_bounds__(256) void ln_kernel(
    const void* X, const float* g, const float* b, float* outF, u16* outB, int nrows) {
    int row = blockIdx.x * 4 + (threadIdx.x >> 6);
    if (row >= nrows) return;
    int lane = threadIdx.x & 63;
    int d0 = lane * 8;
    float v[8];
    if (INBF) {
        short8 x8 = *(const short8*)((const u16*)X + (size_t)row * D_ + d0);
        #pragma unroll
        for (int r = 0; r < 8; ++r) v[r] = bfv((u16)x8[r]);
    } else {
        float4 a = *(const float4*)((const float*)X + (size_t)row * D_ + d0);
        float4 c = *(const float4*)((const float*)X + (size_t)row * D_ + d0 + 4);
        v[0] = a.x; v[1] = a.y; v[2] = a.z; v[3] = a.w;
        v[4] = c.x; v[5] = c.y; v[6] = c.z; v[7] = c.w;
    }
    float s = 0.f;
    #pragma unroll
    for (int r = 0; r < 8; ++r) s += v[r];
    s = wave_sum(s);
    float mean = s * (1.0f / 512.0f);
    float vs = 0.f;
    #pragma unroll
    for (int r = 0; r < 8; ++r) { float d = v[r] - mean; vs += d * d; }
    vs = wave_sum(vs);
    float rstd = rsqrtf(vs * (1.0f / 512.0f) + 1e-5f);
    float4 g0 = *(const float4*)&g[d0], g1 = *(const float4*)&g[d0 + 4];
    float4 b0 = *(const float4*)&b[d0], b1 = *(const float4*)&b[d0 + 4];
    float o[8];
    o[0] = (v[0] - mean) * rstd * g0.x + b0.x;
    o[1] = (v[1] - mean) * rstd * g0.y + b0.y;
    o[2] = (v[2] - mean) * rstd * g0.z + b0.z;
    o[3] = (v[3] - mean) * rstd * g0.w + b0.w;
    o[4] = (v[4] - mean) * rstd * g1.x + b1.x;
    o[5] = (v[5] - mean) * rstd * g1.y + b1.y;
    o[6] = (v[6] - mean) * rstd * g1.z + b1.z;
    o[7] = (v[7] - mean) * rstd * g1.w + b1.w;
    if (outF) {
        float4 w0 = {o[0], o[1], o[2], o[3]};
        float4 w1 = {o[4], o[5], o[6], o[7]};
        *(float4*)(outF + (size_t)row * D_ + d0) = w0;
        *(float4*)(outF + (size_t)row * D_ + d0 + 4) = w1;
    }
    if (outB) {
        short8 w;
        #pragma unroll
        for (int r = 0; r < 8; ++r) w[r] = (short)f2bf(o[r]);
        *(short8*)(outB + (size_t)row * D_ + d0) = w;
    }
}

extern "C" void kernel_launch(void* const* d_in, const int* in_sizes, int n_in,
                              void* d_out, int out_size, void* d_ws, size_t ws_size,
                              hipStream_t stream) {
    (void)in_sizes; (void)n_in; (void)out_size; (void)ws_size;

    const float* x    = (const float*)d_in[0];
    const float* nbr  = (const float*)d_in[1];
    const float* attf = (const float*)d_in[2];
    const float* Wx   = (const float*)d_in[3];
    const float* bx   = (const float*)d_in[4];
    const float* Wn   = (const float*)d_in[5];
    const float* bn   = (const float*)d_in[6];
    const float* Wp   = (const float*)d_in[7];
    const float* bp   = (const float*)d_in[8];
    const float* WQ   = (const float*)d_in[9];
    const float* WK   = (const float*)d_in[10];
    const float* WV   = (const float*)d_in[11];
    const float* Wfc  = (const float*)d_in[12];
    const float* mlng = (const float*)d_in[13];
    const float* mlnb = (const float*)d_in[14];
    const float* WSI  = (const float*)d_in[15];
    const float* fsw1 = (const float*)d_in[16];
    const float* fsw2 = (const float*)d_in[17];
    const float* fsg  = (const float*)d_in[18];
    const float* fsb  = (const float*)d_in[19];
    const float* fiw1 = (const float*)d_in[20];
    const float* fiw2 = (const float*)d_in[21];
    const float* fig  = (const float*)d_in[22];
    const float* fib  = (const float*)d_in[23];

    char* w = (char*)d_ws;
    size_t off = 0;
    auto alloc = [&](size_t bytes) -> void* {
        void* p = w + off;
        off = (off + bytes + 255) & ~(size_t)255;
        return p;
    };
    const size_t MiB = 1024 * 1024;

    const int BM = N_ * NN_;          // 2048 (b,m) pairs
    const int ROWS_I = BM * T_;       // 32768 neighbor rows
    const int CB = 1024;              // bm per chunk (NCH=2, l=0 only)
    const int RC = CB * T_;           // 16384 rows per chunk
    const int NCH = ROWS_I / RC;      // 2

    float* pe      = (float*)alloc((size_t)T_ * D_ * 4);
    float* xemb    = (float*)alloc((size_t)N_ * T_ * D_ * 4);
    float* nf      = (float*)alloc((size_t)T_ * N_ * NN_ * 3 * 4);
    float* maskf   = (float*)alloc((size_t)BM * T_ * 4);
    u16*   Ab      = (u16*)alloc((size_t)ROWS_I * D_ * 2);     // n_emb bf16  32 MiB
    u16* tQKV[2], *tWSI[2], *tfs1[2], *tfs2[2];
    for (int l = 0; l < 2; ++l) {
        tQKV[l] = (u16*)alloc((size_t)1536 * 512 * 2);
        tWSI[l] = (u16*)alloc((size_t)512 * 4096 * 2);
        tfs1[l] = (u16*)alloc((size_t)2048 * 512 * 2);
        tfs2[l] = (u16*)alloc((size_t)512 * 2048 * 2);
    }
    u16* tWfc = (u16*)alloc((size_t)512 * 512 * 2);
    u16* tfi1 = (u16*)alloc((size_t)2048 * 512 * 2);
    u16* tfi2 = (u16*)alloc((size_t)512 * 2048 * 2);
    // scratch union: l0 chunk: QKVb 48 + ctxb 16 | hid 64 ; l1: QK full 64 MiB
    // ffs phase: hid(ffs) 4 MiB @ SCR+0, WSI partials 16 MiB @ SCR+16MiB,
    // fs2 partials 16 MiB @ SCR+32MiB
    char* SCR  = (char*)alloc(64 * MiB);
    u16*   QKVb = (u16*)SCR;
    u16*   ctxb = (u16*)(SCR + 48 * MiB);
    u16*   hid  = (u16*)SCR;
    float* Pw   = (float*)(SCR + 16 * MiB);
    float* Pk2  = (float*)(SCR + 32 * MiB);
    u16*   BbA    = (u16*)alloc((size_t)RC * D_ * 2);  // pre-LN bf16 chunk    16 MiB
    u16*   Bb_res = (u16*)alloc((size_t)RC * D_ * 2);  // res_inter bf16       16 MiB
    float* att_sum = (float*)alloc((size_t)N_ * H_ * 256 * 4);
    u16*   sib     = (u16*)alloc((size_t)N_ * T_ * 4096 * 2);  // 8 MiB
    u16*   xnb     = (u16*)alloc((size_t)N_ * T_ * D_ * 2);
    // total ~168 MiB

    // ---- batched weight conversion + pe: 14 jobs + 16 pe blocks, one launch ----
    WJobs jobs;
    int ntiles = 0;
    auto addJob = [&](int idx, const float* src, u16* dst, int K, int N) {
        jobs.j[idx] = {src, dst, K, N, ntiles};
        ntiles += (N >> 5) * (K >> 5);
    };
    addJob(0,  WQ,                            tQKV[0],              512, 512);
    addJob(1,  WK,                            tQKV[0] + 512 * 512,  512, 512);
    addJob(2,  WV,                            tQKV[0] + 1024 * 512, 512, 512);   // dead at l=1
    addJob(3,  WQ + (size_t)512 * 512,        tQKV[1],              512, 512);
    addJob(4,  WK + (size_t)512 * 512,        tQKV[1] + 512 * 512,  512, 512);
    addJob(5,  Wfc,                           tWfc,                 512, 512);
    addJob(6,  WSI,                           tWSI[0],              4096, 512);
    addJob(7,  WSI + (size_t)4096 * 512,      tWSI[1],              4096, 512);
    addJob(8,  fsw1,                          tfs1[0],              512, 2048);
    addJob(9,  fsw1 + (size_t)512 * 2048,     tfs1[1],              512, 2048);
    addJob(10, fsw2,                          tfs2[0],              2048, 512);
    addJob(11, fsw2 + (size_t)2048 * 512,     tfs2[1],              2048, 512);
    addJob(12, fiw1,                          tfi1,                 512, 2048);
    addJob(13, fiw2,                          tfi2,                 2048, 512);
    wconv_all<<<ntiles + 16, 256, 0, stream>>>(jobs, ntiles, pe);

    // xemb + nbr fused (independent); nemb needs nf -> separate
    xnbr_kernel<<<384, 256, 0, stream>>>(x, Wx, bx, pe, xemb, nbr, nf, maskf);
    nemb_kernel<<<(BM * T_) / 4, 256, 0, stream>>>(nf, Wn, bn, pe, Ab);

    // single pre-loop zero; siatt self-zeroes per layer thereafter
    hipMemsetAsync(att_sum, 0, (size_t)N_ * H_ * 256 * 4, stream);

    for (int l = 0; l < L_; ++l) {
        if (l == 0) {
            for (int c = 0; c < NCH; ++c) {
                u16* Acb = Ab + (size_t)c * RC * D_;
                // QKV fused GEMM: N=1536 (1536 blocks = 3 exact rounds @2/CU)
                gemm_ct<0, 0, 1><<<dim3(12, RC / 128), 256, 0, stream>>>(
                    Acb, tQKV[0], nullptr, QKVb, nullptr, 512, 1536);
                attn_fused_kernel<1, 1536><<<CB, 256, 0, stream>>>(
                    QKVb, maskf, c * CB, att_sum, ctxb);
                // fc + residual(n_emb bf16) -> pre-LN bf16 (512 blocks = 1 round)
                gemm_ct<3, 0, 1><<<dim3(4, RC / 128), 256, 0, stream>>>(
                    ctxb, tWfc, nullptr, BbA, Acb, 512, 512);
                ln_kernel<1><<<RC / 4, 256, 0, stream>>>(
                    BbA, mlng, mlnb, nullptr, Bb_res, RC);   // res_inter bf16
                // ffi1 relu: N=2048 (2048 blocks = 4 exact rounds)
                gemm_ct<1, 0, 1><<<dim3(16, RC / 128), 256, 0, stream>>>(
                    Bb_res, tfi1, nullptr, hid, nullptr, 512, 2048);
                // ffi2 + residual(res_inter bf16) -> pre-LN bf16 (512 blocks)
                gemm_ct<3, 0, 1><<<dim3(4, RC / 128), 256, 0, stream>>>(
                    hid, tfi2, nullptr, BbA, Bb_res, 2048, 512);
                ln_kernel<1><<<RC / 4, 256, 0, stream>>>(
                    BbA, fig, fib, nullptr, Acb, RC);        // new n_emb (bf16)
            }
        } else {
            // l=1: unchunked QK (N=1024, ldc=1024; 64 MiB = SCR): 2048 blocks
            gemm_ct<0, 0, 1><<<dim3(8, ROWS_I / 128), 256, 0, stream>>>(
                Ab, tQKV[1], nullptr, QKVb, nullptr, 512, 1024);
            attn_fused_kernel<0, 1024><<<BM, 256, 0, stream>>>(
                QKVb, maskf, 0, att_sum, nullptr);
        }

        // ---- self-attention + si + ffs (split-K; WSI partials kept live) ----
        siatt_kernel<<<N_ * H_, 256, 0, stream>>>(xemb, att_sum, attf, sib);
        // WSI partials (M=1024, N=512, K=4096): NS=8 -> 256 blocks, Kc=512
        gemm_ks<8><<<dim3(4, 8, 8), 256, 0, stream>>>(sib, tWSI[l], Pw, 4096, 512);
        // xnb = bf16(sum of WSI partials)
        ksum_kernel<8, 0, 0, 1><<<512, 256, 0, stream>>>(
            Pw, nullptr, nullptr, xnb, 1024 * 512);
        // hid = relu(xnb @ tfs1) (M=1024, N=2048, K=512): direct gemm_ct, 128 blocks
        gemm_ct<1, 0, 1><<<dim3(16, 8), 256, 0, stream>>>(
            xnb, tfs1[l], nullptr, hid, nullptr, 512, 2048);
        // fs2 partials; then fused reduce(fs2)+reduce(WSI residual)+LN [+pred head]
        gemm_ks<8><<<dim3(4, 8, 8), 256, 0, stream>>>(hid, tfs2[l], Pk2, 2048, 512);
        if (l == 0) {
            ksln_kernel<8, 0><<<256, 256, 0, stream>>>(
                Pk2, Pw, fsg, fsb, xemb, nullptr, nullptr, nullptr, 1024);
        } else {
            ksln_kernel<8, 1><<<256, 256, 0, stream>>>(
                Pk2, Pw, fsg + D_, fsb + D_, nullptr, Wp, bp, (float*)d_out, 1024);
        }
    }
}